// Round 4
// baseline (534.445 us; speedup 1.0000x reference)
//
#include <hip/hip_runtime.h>
#include <cstddef>

#define LEAKY 0.2f
#define EPS_DEN 1e-16f

typedef short bf8_t __attribute__((ext_vector_type(8)));   // 8 bf16 in 4 VGPRs
typedef float f4_t __attribute__((ext_vector_type(4)));
typedef unsigned short us4_t __attribute__((ext_vector_type(4)));

__device__ __forceinline__ unsigned short f2bf(float f) {   // RNE
    unsigned u = __float_as_uint(f);
    unsigned r = (u + 0x7fffu + ((u >> 16) & 1u)) >> 16;
    return (unsigned short)r;
}
__device__ __forceinline__ float bf2f(unsigned short h) {
    return __uint_as_float(((unsigned)h) << 16);
}

// ---------------------------------------------------------------------------
// CSR build: histogram -> scan -> scatter
// ---------------------------------------------------------------------------
__global__ void hist_kernel(const int* __restrict__ dst, int* __restrict__ counts, int E) {
    int i = blockIdx.x * blockDim.x + threadIdx.x;
    if (i < E) atomicAdd(&counts[dst[i]], 1);
}

__global__ void scan_kernel(const int* __restrict__ counts, int* __restrict__ offs,
                            int* __restrict__ cursor, int N) {
    __shared__ int s[256];
    __shared__ int carry_s;
    int t = threadIdx.x;
    if (t == 0) carry_s = 0;
    __syncthreads();
    for (int base = 0; base < N; base += 256) {
        int i = base + t;
        int v = (i < N) ? counts[i] : 0;
        s[t] = v;
        __syncthreads();
#pragma unroll
        for (int st = 1; st < 256; st <<= 1) {
            int add = (t >= st) ? s[t - st] : 0;
            __syncthreads();
            s[t] += add;
            __syncthreads();
        }
        int carry = carry_s;
        int excl = carry + s[t] - v;
        if (i < N) { offs[i] = excl; cursor[i] = excl; }
        __syncthreads();
        if (t == 255) carry_s = carry + s[255];
        __syncthreads();
    }
    if (t == 0) offs[N] = carry_s;
}

__global__ void scatter_kernel(const int* __restrict__ src, const int* __restrict__ dst,
                               int* __restrict__ cursor, int* __restrict__ csrc, int E) {
    int i = blockIdx.x * blockDim.x + threadIdx.x;
    if (i < E) {
        int d = dst[i];
        int pos = atomicAdd(&cursor[d], 1);
        csrc[pos] = src[i];
    }
}

// ---------------------------------------------------------------------------
// split fp32 -> bf16 hi + bf16 lo (elementwise)
// ---------------------------------------------------------------------------
__global__ void split_kernel(const float* __restrict__ in, unsigned short* __restrict__ hi,
                             unsigned short* __restrict__ lo, int len) {
    int i = blockIdx.x * blockDim.x + threadIdx.x;
    if (i >= len) return;
    float v = in[i];
    unsigned short h = f2bf(v);
    hi[i] = h;
    lo[i] = f2bf(v - bf2f(h));
}

// W [K,N] fp32  ->  WT_hi/lo [N,K] bf16 (transpose + split)
__global__ void wsplit_kernel(const float* __restrict__ W, unsigned short* __restrict__ hi,
                              unsigned short* __restrict__ lo, int K, int N) {
    int idx = blockIdx.x * blockDim.x + threadIdx.x;
    if (idx >= K * N) return;
    int n = idx / K, k = idx % K;
    float v = W[(size_t)k * N + n];
    unsigned short h = f2bf(v);
    hi[idx] = h;
    lo[idx] = f2bf(v - bf2f(h));
}

// ---------------------------------------------------------------------------
// MFMA GEMM (split-bf16, 3 passes): C[M,N] = (Ahi+Alo) @ BT^T  (BT stored [N,K])
// ---------------------------------------------------------------------------
__global__ __launch_bounds__(256) void mfma_gemm_kernel(
    const unsigned short* __restrict__ Ahi, const unsigned short* __restrict__ Alo,
    const unsigned short* __restrict__ BThi, const unsigned short* __restrict__ BTlo,
    float* __restrict__ C, int M, int N, int K) {
    constexpr int BK = 32;
    __shared__ __align__(16) unsigned short sA[128 * BK];
    __shared__ __align__(16) unsigned short sB[128 * BK];
    int t = threadIdx.x;
    int w = t >> 6, lane = t & 63;
    int quad = lane >> 4, low = lane & 15;
    int m0 = blockIdx.y * 128, n0 = blockIdx.x * 128;
    int wm = (w & 1) * 64, wn = (w >> 1) * 64;

    f4_t acc[4][4];
#pragma unroll
    for (int i = 0; i < 4; i++)
#pragma unroll
        for (int j = 0; j < 4; j++) acc[i][j] = (f4_t){0.f, 0.f, 0.f, 0.f};

    int srow = lane >> 2;
    int schunk = lane & 3;

    const unsigned short* Ap[3] = {Ahi, Ahi, Alo};
    const unsigned short* Bp[3] = {BThi, BTlo, BThi};

    for (int pass = 0; pass < 3; pass++) {
        const unsigned short* A = Ap[pass];
        const unsigned short* B = Bp[pass];
        for (int k0 = 0; k0 < K; k0 += BK) {
            __syncthreads();
#pragma unroll
            for (int inst = 0; inst < 2; inst++) {
                int r = w * 32 + inst * 16 + srow;
                int gm = m0 + r;
                if (gm >= M) gm = M - 1;
                const void* g = (const void*)(A + (size_t)gm * K + k0 + schunk * 8);
                void* l = (void*)((char*)sA + (size_t)(w * 2048 + inst * 1024));
                __builtin_amdgcn_global_load_lds((const __attribute__((address_space(1))) void*)g,
                                                 (__attribute__((address_space(3))) void*)l, 16, 0, 0);
            }
#pragma unroll
            for (int inst = 0; inst < 2; inst++) {
                int r = w * 32 + inst * 16 + srow;
                int gn = n0 + r;
                const void* g = (const void*)(B + (size_t)gn * K + k0 + schunk * 8);
                void* l = (void*)((char*)sB + (size_t)(w * 2048 + inst * 1024));
                __builtin_amdgcn_global_load_lds((const __attribute__((address_space(1))) void*)g,
                                                 (__attribute__((address_space(3))) void*)l, 16, 0, 0);
            }
            __syncthreads();

            bf8_t af[4], bf[4];
#pragma unroll
            for (int i = 0; i < 4; i++) {
                int row = wm + i * 16 + low;
                af[i] = *(const bf8_t*)&sA[row * BK + quad * 8];
            }
#pragma unroll
            for (int j = 0; j < 4; j++) {
                int row = wn + j * 16 + low;
                bf[j] = *(const bf8_t*)&sB[row * BK + quad * 8];
            }
#pragma unroll
            for (int i = 0; i < 4; i++)
#pragma unroll
                for (int j = 0; j < 4; j++)
                    acc[i][j] = __builtin_amdgcn_mfma_f32_16x16x32_bf16(af[i], bf[j], acc[i][j], 0, 0, 0);
        }
    }

#pragma unroll
    for (int i = 0; i < 4; i++) {
#pragma unroll
        for (int r = 0; r < 4; r++) {
            int gm = m0 + wm + i * 16 + quad * 4 + r;
            if (gm >= M) continue;
#pragma unroll
            for (int j = 0; j < 4; j++) {
                int gn = n0 + wn + j * 16 + low;
                C[(size_t)gm * N + gn] = acc[i][j][r];
            }
        }
    }
}

// ---------------------------------------------------------------------------
// attention logits
// ---------------------------------------------------------------------------
__global__ void al_h4_kernel(const float* __restrict__ h, const float* __restrict__ a_src,
                             const float* __restrict__ a_dst, float* __restrict__ als,
                             float* __restrict__ ald, int N) {
    int wave = threadIdx.x >> 6, lane = threadIdx.x & 63;
    int n = blockIdx.x * 4 + wave;
    if (n >= N) return;
    const float* row = h + (size_t)n * 512;
    float ps[4] = {0, 0, 0, 0}, pd[4] = {0, 0, 0, 0};
#pragma unroll
    for (int k = 0; k < 8; k++) {
        int f = k * 64 + lane;
        float v = row[f];
        ps[k >> 1] += v * a_src[f];
        pd[k >> 1] += v * a_dst[f];
    }
#pragma unroll
    for (int off = 32; off; off >>= 1) {
#pragma unroll
        for (int hd = 0; hd < 4; hd++) {
            ps[hd] += __shfl_down(ps[hd], off);
            pd[hd] += __shfl_down(pd[hd], off);
        }
    }
    if (lane == 0) {
#pragma unroll
        for (int hd = 0; hd < 4; hd++) {
            als[n * 4 + hd] = ps[hd];
            ald[n * 4 + hd] = pd[hd];
        }
    }
}

__global__ void al_h1_kernel(const float* __restrict__ h, const float* __restrict__ a_src,
                             const float* __restrict__ a_dst, float* __restrict__ als,
                             float* __restrict__ ald, int N) {
    int wave = threadIdx.x >> 6, lane = threadIdx.x & 63;
    int n = blockIdx.x * 4 + wave;
    if (n >= N) return;
    const float* row = h + (size_t)n * 128;
    float v0 = row[lane], v1 = row[lane + 64];
    float ps = v0 * a_src[lane] + v1 * a_src[lane + 64];
    float pd = v0 * a_dst[lane] + v1 * a_dst[lane + 64];
#pragma unroll
    for (int off = 32; off; off >>= 1) {
        ps += __shfl_down(ps, off);
        pd += __shfl_down(pd, off);
    }
    if (lane == 0) { als[n] = ps; ald[n] = pd; }
}

// ---------------------------------------------------------------------------
// Softmax stats per dst node: compute e (leaky), segment max, denom, and write
// NORMALIZED weights p/(denom+eps) to pbuf; self weight to psf.
// One wave per node. H=4: lane = edge_slot*4 + head.
// ---------------------------------------------------------------------------
__global__ void stats_h4_kernel(const int* __restrict__ csrc, const int* __restrict__ offs,
                                const float* __restrict__ als, const float* __restrict__ ald,
                                float* __restrict__ pbuf, float* __restrict__ psf, int N) {
    int wave = threadIdx.x >> 6, lane = threadIdx.x & 63;
    int n = blockIdx.x * 4 + wave;
    if (n >= N) return;
    int hd = lane & 3, es = lane >> 2;   // head, edge slot 0..15
    float aldn = ald[n * 4 + hd];
    float selfe = als[n * 4 + hd] + aldn;
    selfe = selfe > 0.f ? selfe : LEAKY * selfe;
    int beg = offs[n], end = offs[n + 1];
    // pass 1: e + max
    float m = selfe;
    for (int base = beg; base + es < end; base += 16) {
        int idx = base + es;
        int s = csrc[idx];
        float e = als[s * 4 + hd] + aldn;
        e = e > 0.f ? e : LEAKY * e;
        pbuf[idx * 4 + hd] = e;
        m = fmaxf(m, e);
    }
#pragma unroll
    for (int off = 4; off < 64; off <<= 1) m = fmaxf(m, __shfl_xor(m, off));
    // pass 2: p + denom
    float d = 0.f;
    for (int base = beg; base + es < end; base += 16) {
        int idx = base + es;
        float p = __expf(pbuf[idx * 4 + hd] - m);
        pbuf[idx * 4 + hd] = p;
        d += p;
    }
#pragma unroll
    for (int off = 4; off < 64; off <<= 1) d += __shfl_xor(d, off);
    float pself = __expf(selfe - m);
    float r = 1.0f / (d + pself + EPS_DEN);
    if (es == 0) psf[n * 4 + hd] = pself * r;
    // pass 3: normalize
    for (int base = beg; base + es < end; base += 16) {
        int idx = base + es;
        pbuf[idx * 4 + hd] *= r;
    }
}

__global__ void stats_h1_kernel(const int* __restrict__ csrc, const int* __restrict__ offs,
                                const float* __restrict__ als, const float* __restrict__ ald,
                                float* __restrict__ pbuf, float* __restrict__ psf, int N) {
    int wave = threadIdx.x >> 6, lane = threadIdx.x & 63;
    int n = blockIdx.x * 4 + wave;
    if (n >= N) return;
    float aldn = ald[n];
    float selfe = als[n] + aldn;
    selfe = selfe > 0.f ? selfe : LEAKY * selfe;
    int beg = offs[n], end = offs[n + 1];
    float m = selfe;
    for (int base = beg; base + lane < end; base += 64) {
        int idx = base + lane;
        int s = csrc[idx];
        float e = als[s] + aldn;
        e = e > 0.f ? e : LEAKY * e;
        pbuf[idx] = e;
        m = fmaxf(m, e);
    }
#pragma unroll
    for (int off = 1; off < 64; off <<= 1) m = fmaxf(m, __shfl_xor(m, off));
    float d = 0.f;
    for (int base = beg; base + lane < end; base += 64) {
        int idx = base + lane;
        float p = __expf(pbuf[idx] - m);
        pbuf[idx] = p;
        d += p;
    }
#pragma unroll
    for (int off = 1; off < 64; off <<= 1) d += __shfl_xor(d, off);
    float pself = __expf(selfe - m);
    float r = 1.0f / (d + pself + EPS_DEN);
    if (lane == 0) psf[n] = pself * r;
    for (int base = beg; base + lane < end; base += 64) {
        int idx = base + lane;
        pbuf[idx] *= r;
    }
}

// ---------------------------------------------------------------------------
// Lean aggregate: acc[f] = psf*self[f] + sum_e p[e]*h[src_e][f]; weights prenormalized.
// NT threads, VEC consecutive floats per thread (NT*VEC == H*128).
// ---------------------------------------------------------------------------
template <int H, int NT, int VEC, bool DO_ELU, bool SPLIT>
__global__ void gat_aggregate_kernel(const float* __restrict__ h, const float* __restrict__ pbuf,
                                     const float* __restrict__ psf, const int* __restrict__ csrc,
                                     const int* __restrict__ offs, const float* __restrict__ bias,
                                     float* __restrict__ outp, unsigned short* __restrict__ ohi,
                                     unsigned short* __restrict__ olo, int N) {
    constexpr int F = H * 128;
    static_assert(NT * VEC == F, "shape");
    constexpr int CH = 128;
    __shared__ int sSrc[CH];
    __shared__ float sP[CH * H];
    int n = blockIdx.x;
    int t = threadIdx.x;
    int f0 = t * VEC;
    int head = f0 >> 7;
    const float* selfrow = h + (size_t)n * F;
    float acc[VEC];
    {
        float pself = psf[n * H + head];
#pragma unroll
        for (int j = 0; j < VEC; j++) acc[j] = pself * selfrow[f0 + j];
    }
    int beg = offs[n], end = offs[n + 1];
    for (int base = beg; base < end; base += CH) {
        int len = min(CH, end - base);
        __syncthreads();
        for (int c = t; c < len; c += NT) sSrc[c] = csrc[base + c];
        for (int c = t; c < len * H; c += NT) sP[c] = pbuf[base * H + c];
        __syncthreads();
#pragma unroll 4
        for (int c = 0; c < len; c++) {
            const float* srow = h + (size_t)sSrc[c] * F;
            float p = sP[c * H + head];
            using vec_t = float __attribute__((ext_vector_type(VEC)));
            vec_t x = *(const vec_t*)(srow + f0);
#pragma unroll
            for (int j = 0; j < VEC; j++) acc[j] += p * x[j];
        }
    }
#pragma unroll
    for (int j = 0; j < VEC; j++) {
        float o = acc[j] + bias[f0 + j];
        if (DO_ELU) o = o > 0.f ? o : (__expf(o) - 1.0f);
        acc[j] = o;
    }
    size_t idx = (size_t)n * F + f0;
    if (SPLIT) {
        us4_t hs, ls;
#pragma unroll
        for (int j = 0; j < VEC; j++) {
            unsigned short hh = f2bf(acc[j]);
            hs[j] = hh;
            ls[j] = f2bf(acc[j] - bf2f(hh));
        }
        *(us4_t*)&ohi[idx] = hs;
        *(us4_t*)&olo[idx] = ls;
    } else {
#pragma unroll
        for (int j = 0; j < VEC; j++) outp[idx + j] = acc[j];
    }
}

// ---------------------------------------------------------------------------
// classifier
// ---------------------------------------------------------------------------
__global__ void classifier_kernel(const float* __restrict__ emb, const float* __restrict__ Wc1,
                                  const float* __restrict__ bc1, const float* __restrict__ Wc2,
                                  const float* __restrict__ bc2, float* __restrict__ out, int N) {
    int wave = threadIdx.x >> 6, lane = threadIdx.x & 63;
    int n = blockIdx.x * 4 + wave;
    if (n >= N) return;
    const float* row = emb + (size_t)n * 128;
    float acc = bc1[lane];
#pragma unroll 4
    for (int k = 0; k < 128; k++) acc += row[k] * Wc1[k * 64 + lane];
    acc = fmaxf(acc, 0.f);
    float o0 = acc * Wc2[lane * 2 + 0];
    float o1 = acc * Wc2[lane * 2 + 1];
#pragma unroll
    for (int off = 32; off; off >>= 1) {
        o0 += __shfl_down(o0, off);
        o1 += __shfl_down(o1, off);
    }
    if (lane == 0) {
        out[n * 2 + 0] = o0 + bc2[0];
        out[n * 2 + 1] = o1 + bc2[1];
    }
}

// ---------------------------------------------------------------------------
extern "C" void kernel_launch(void* const* d_in, const int* in_sizes, int n_in,
                              void* d_out, int out_size, void* d_ws, size_t ws_size,
                              hipStream_t stream) {
    const float* x      = (const float*)d_in[0];
    const int*   ei     = (const int*)d_in[1];
    const float* W1     = (const float*)d_in[2];
    const float* a1s    = (const float*)d_in[3];
    const float* a1d    = (const float*)d_in[4];
    const float* b1     = (const float*)d_in[5];
    const float* W2     = (const float*)d_in[6];
    const float* a2s    = (const float*)d_in[7];
    const float* a2d    = (const float*)d_in[8];
    const float* b2     = (const float*)d_in[9];
    const float* W3     = (const float*)d_in[10];
    const float* a3s    = (const float*)d_in[11];
    const float* a3d    = (const float*)d_in[12];
    const float* b3     = (const float*)d_in[13];
    const float* Wc1    = (const float*)d_in[14];
    const float* bc1    = (const float*)d_in[15];
    const float* Wc2    = (const float*)d_in[16];
    const float* bc2    = (const float*)d_in[17];

    const int N = in_sizes[0] / 256;       // 10000
    const int E = in_sizes[1] / 2;         // 320000
    const int F = 512;

    const int* src = ei;
    const int* dst = ei + E;

    auto align = [](size_t o) { return (o + 255) & ~(size_t)255; };
    size_t o = 0;
    size_t o_G     = o; o = align(o + (size_t)N * F * 4);        // GEMM output h (fp32)
    size_t o_ahi   = o; o = align(o + (size_t)N * F * 2);
    size_t o_alo   = o; o = align(o + (size_t)N * F * 2);
    size_t o_xhi   = o; o = align(o + (size_t)N * 256 * 2);
    size_t o_xlo   = o; o = align(o + (size_t)N * 256 * 2);
    size_t o_w1h   = o; o = align(o + (size_t)512 * 256 * 2);
    size_t o_w1l   = o; o = align(o + (size_t)512 * 256 * 2);
    size_t o_w2h   = o; o = align(o + (size_t)512 * 512 * 2);
    size_t o_w2l   = o; o = align(o + (size_t)512 * 512 * 2);
    size_t o_w3h   = o; o = align(o + (size_t)128 * 512 * 2);
    size_t o_w3l   = o; o = align(o + (size_t)128 * 512 * 2);
    size_t o_als   = o; o = align(o + (size_t)N * 4 * 4);
    size_t o_ald   = o; o = align(o + (size_t)N * 4 * 4);
    size_t o_psf   = o; o = align(o + (size_t)N * 4 * 4);
    size_t o_cnt   = o; o = align(o + (size_t)N * 4);
    size_t o_off   = o; o = align(o + (size_t)(N + 1) * 4);
    size_t o_csrc  = o; o = align(o + (size_t)E * 4);
    size_t o_ebuf  = o; o = align(o + (size_t)E * 4 * 4);
    (void)ws_size;

    char* ws = (char*)d_ws;
    float* bufG  = (float*)(ws + o_G);
    unsigned short* act_hi = (unsigned short*)(ws + o_ahi);
    unsigned short* act_lo = (unsigned short*)(ws + o_alo);
    unsigned short* x_hi   = (unsigned short*)(ws + o_xhi);
    unsigned short* x_lo   = (unsigned short*)(ws + o_xlo);
    unsigned short* w1h = (unsigned short*)(ws + o_w1h);
    unsigned short* w1l = (unsigned short*)(ws + o_w1l);
    unsigned short* w2h = (unsigned short*)(ws + o_w2h);
    unsigned short* w2l = (unsigned short*)(ws + o_w2l);
    unsigned short* w3h = (unsigned short*)(ws + o_w3h);
    unsigned short* w3l = (unsigned short*)(ws + o_w3l);
    float* als  = (float*)(ws + o_als);
    float* ald  = (float*)(ws + o_ald);
    float* psf  = (float*)(ws + o_psf);
    int*   cnt  = (int*)(ws + o_cnt);
    int*   offs = (int*)(ws + o_off);
    int*   csrc = (int*)(ws + o_csrc);
    float* ebuf = (float*)(ws + o_ebuf);

    float* outp = (float*)d_out;                 // [N,2]
    float* emb  = (float*)d_out + (size_t)N * 2; // [N,128]

    // ---- CSR build ----
    hipMemsetAsync(cnt, 0, (size_t)N * 4, stream);
    int eb = (E + 255) / 256;
    hipLaunchKernelGGL(hist_kernel, dim3(eb), dim3(256), 0, stream, dst, cnt, E);
    hipLaunchKernelGGL(scan_kernel, dim3(1), dim3(256), 0, stream, cnt, offs, cnt, N);
    hipLaunchKernelGGL(scatter_kernel, dim3(eb), dim3(256), 0, stream, src, dst, cnt, csrc, E);

    // ---- splits ----
    hipLaunchKernelGGL(split_kernel, dim3((N * 256 + 255) / 256), dim3(256), 0, stream,
                       x, x_hi, x_lo, N * 256);
    hipLaunchKernelGGL(wsplit_kernel, dim3((256 * 512 + 255) / 256), dim3(256), 0, stream,
                       W1, w1h, w1l, 256, 512);
    hipLaunchKernelGGL(wsplit_kernel, dim3((512 * 512 + 255) / 256), dim3(256), 0, stream,
                       W2, w2h, w2l, 512, 512);
    hipLaunchKernelGGL(wsplit_kernel, dim3((512 * 128 + 255) / 256), dim3(256), 0, stream,
                       W3, w3h, w3l, 512, 128);

    int nb4 = (N + 3) / 4;
    int gy  = (N + 127) / 128;

    // ---- layer 1 ----
    hipLaunchKernelGGL(mfma_gemm_kernel, dim3(512 / 128, gy), dim3(256), 0, stream,
                       x_hi, x_lo, w1h, w1l, bufG, N, 512, 256);
    hipLaunchKernelGGL(al_h4_kernel, dim3(nb4), dim3(256), 0, stream, bufG, a1s, a1d, als, ald, N);
    hipLaunchKernelGGL(stats_h4_kernel, dim3(nb4), dim3(256), 0, stream,
                       csrc, offs, als, ald, ebuf, psf, N);
    hipLaunchKernelGGL((gat_aggregate_kernel<4, 128, 4, true, true>), dim3(N), dim3(128), 0, stream,
                       bufG, ebuf, psf, csrc, offs, b1, (float*)nullptr, act_hi, act_lo, N);

    // ---- layer 2 ----
    hipLaunchKernelGGL(mfma_gemm_kernel, dim3(512 / 128, gy), dim3(256), 0, stream,
                       act_hi, act_lo, w2h, w2l, bufG, N, 512, 512);
    hipLaunchKernelGGL(al_h4_kernel, dim3(nb4), dim3(256), 0, stream, bufG, a2s, a2d, als, ald, N);
    hipLaunchKernelGGL(stats_h4_kernel, dim3(nb4), dim3(256), 0, stream,
                       csrc, offs, als, ald, ebuf, psf, N);
    hipLaunchKernelGGL((gat_aggregate_kernel<4, 128, 4, true, true>), dim3(N), dim3(128), 0, stream,
                       bufG, ebuf, psf, csrc, offs, b2, (float*)nullptr, act_hi, act_lo, N);

    // ---- layer 3 (1 head, concat=False -> mean over 1 head == identity) ----
    hipLaunchKernelGGL(mfma_gemm_kernel, dim3(128 / 128, gy), dim3(256), 0, stream,
                       act_hi, act_lo, w3h, w3l, bufG, N, 128, 512);
    hipLaunchKernelGGL(al_h1_kernel, dim3(nb4), dim3(256), 0, stream, bufG, a3s, a3d, als, ald, N);
    hipLaunchKernelGGL(stats_h1_kernel, dim3(nb4), dim3(256), 0, stream,
                       csrc, offs, als, ald, ebuf, psf, N);
    hipLaunchKernelGGL((gat_aggregate_kernel<1, 64, 2, false, false>), dim3(N), dim3(64), 0, stream,
                       bufG, ebuf, psf, csrc, offs, b3, emb, (unsigned short*)nullptr,
                       (unsigned short*)nullptr, N);

    // ---- classifier ----
    hipLaunchKernelGGL(classifier_kernel, dim3(nb4), dim3(256), 0, stream,
                       emb, Wc1, bc1, Wc2, bc2, outp, N);
}

// Round 5
// 421.329 us; speedup vs baseline: 1.2685x; 1.2685x over previous
//
#include <hip/hip_runtime.h>
#include <cstddef>

#define LEAKY 0.2f
#define EPS_DEN 1e-16f

typedef short bf8_t __attribute__((ext_vector_type(8)));   // 8 bf16 in 4 VGPRs
typedef float f4_t __attribute__((ext_vector_type(4)));
typedef unsigned short us2_t __attribute__((ext_vector_type(2)));

__device__ __forceinline__ unsigned short f2bf(float f) {   // RNE
    unsigned u = __float_as_uint(f);
    unsigned r = (u + 0x7fffu + ((u >> 16) & 1u)) >> 16;
    return (unsigned short)r;
}
__device__ __forceinline__ float bf2f(unsigned short h) {
    return __uint_as_float(((unsigned)h) << 16);
}

// ---------------------------------------------------------------------------
// CSR build: histogram -> 3-phase parallel scan -> scatter
// ---------------------------------------------------------------------------
__global__ void hist_kernel(const int* __restrict__ dst, int* __restrict__ counts, int E) {
    int i = blockIdx.x * blockDim.x + threadIdx.x;
    if (i < E) atomicAdd(&counts[dst[i]], 1);
}

// phase 1: per-256-block exclusive scan IN PLACE on cnt; block sums to bsum
__global__ void scan1_kernel(int* __restrict__ cnt, int* __restrict__ bsum, int N) {
    __shared__ int s[256];
    int t = threadIdx.x;
    int i = blockIdx.x * 256 + t;
    int v = (i < N) ? cnt[i] : 0;
    s[t] = v;
    __syncthreads();
#pragma unroll
    for (int st = 1; st < 256; st <<= 1) {
        int add = (t >= st) ? s[t - st] : 0;
        __syncthreads();
        s[t] += add;
        __syncthreads();
    }
    if (i < N) cnt[i] = s[t] - v;           // exclusive within block
    if (t == 255) bsum[blockIdx.x] = s[255];
}

// phase 2: one wave scans the <=64 block sums (exclusive), writes offs[N]=total
__global__ void scan2_kernel(int* __restrict__ bsum, int* __restrict__ offs, int NB, int N) {
    int t = threadIdx.x;   // 64 threads
    int v = (t < NB) ? bsum[t] : 0;
    int inc = v;
#pragma unroll
    for (int off = 1; off < 64; off <<= 1) {
        int u = __shfl_up(inc, off);
        if (t >= off) inc += u;
    }
    if (t < NB) bsum[t] = inc - v;          // exclusive
    if (t == 63) offs[N] = inc;             // total (lane 63 has full sum)
}

// phase 3: add block offset; write offs + cursor (cursor == cnt, in place)
__global__ void scan3_kernel(int* __restrict__ cnt, const int* __restrict__ bsum,
                             int* __restrict__ offs, int N) {
    int i = blockIdx.x * 256 + threadIdx.x;
    if (i < N) {
        int o = cnt[i] + bsum[blockIdx.x];
        offs[i] = o;
        cnt[i] = o;
    }
}

__global__ void scatter_kernel(const int* __restrict__ src, const int* __restrict__ dst,
                               int* __restrict__ cursor, int* __restrict__ csrc, int E) {
    int i = blockIdx.x * blockDim.x + threadIdx.x;
    if (i < E) {
        int d = dst[i];
        int pos = atomicAdd(&cursor[d], 1);
        csrc[pos] = src[i];
    }
}

// ---------------------------------------------------------------------------
// split fp32 -> bf16 hi + bf16 lo (elementwise)
// ---------------------------------------------------------------------------
__global__ void split_kernel(const float* __restrict__ in, unsigned short* __restrict__ hi,
                             unsigned short* __restrict__ lo, int len) {
    int i = blockIdx.x * blockDim.x + threadIdx.x;
    if (i >= len) return;
    float v = in[i];
    unsigned short h = f2bf(v);
    hi[i] = h;
    lo[i] = f2bf(v - bf2f(h));
}

// W [K,N] fp32  ->  WT_hi/lo [N,K] bf16 (transpose + split)
__global__ void wsplit_kernel(const float* __restrict__ W, unsigned short* __restrict__ hi,
                              unsigned short* __restrict__ lo, int K, int N) {
    int idx = blockIdx.x * blockDim.x + threadIdx.x;
    if (idx >= K * N) return;
    int n = idx / K, k = idx % K;
    float v = W[(size_t)k * N + n];
    unsigned short h = f2bf(v);
    hi[idx] = h;
    lo[idx] = f2bf(v - bf2f(h));
}

// ---------------------------------------------------------------------------
// MFMA GEMM (split-bf16, 3 passes): C[M,N] = (Ahi+Alo) @ BT^T  (BT stored [N,K])
// ---------------------------------------------------------------------------
__global__ __launch_bounds__(256) void mfma_gemm_kernel(
    const unsigned short* __restrict__ Ahi, const unsigned short* __restrict__ Alo,
    const unsigned short* __restrict__ BThi, const unsigned short* __restrict__ BTlo,
    float* __restrict__ C, int M, int N, int K) {
    constexpr int BK = 32;
    __shared__ __align__(16) unsigned short sA[128 * BK];
    __shared__ __align__(16) unsigned short sB[128 * BK];
    int t = threadIdx.x;
    int w = t >> 6, lane = t & 63;
    int quad = lane >> 4, low = lane & 15;
    int m0 = blockIdx.y * 128, n0 = blockIdx.x * 128;
    int wm = (w & 1) * 64, wn = (w >> 1) * 64;

    f4_t acc[4][4];
#pragma unroll
    for (int i = 0; i < 4; i++)
#pragma unroll
        for (int j = 0; j < 4; j++) acc[i][j] = (f4_t){0.f, 0.f, 0.f, 0.f};

    int srow = lane >> 2;
    int schunk = lane & 3;

    const unsigned short* Ap[3] = {Ahi, Ahi, Alo};
    const unsigned short* Bp[3] = {BThi, BTlo, BThi};

    for (int pass = 0; pass < 3; pass++) {
        const unsigned short* A = Ap[pass];
        const unsigned short* B = Bp[pass];
        for (int k0 = 0; k0 < K; k0 += BK) {
            __syncthreads();
#pragma unroll
            for (int inst = 0; inst < 2; inst++) {
                int r = w * 32 + inst * 16 + srow;
                int gm = m0 + r;
                if (gm >= M) gm = M - 1;
                const void* g = (const void*)(A + (size_t)gm * K + k0 + schunk * 8);
                void* l = (void*)((char*)sA + (size_t)(w * 2048 + inst * 1024));
                __builtin_amdgcn_global_load_lds((const __attribute__((address_space(1))) void*)g,
                                                 (__attribute__((address_space(3))) void*)l, 16, 0, 0);
            }
#pragma unroll
            for (int inst = 0; inst < 2; inst++) {
                int r = w * 32 + inst * 16 + srow;
                int gn = n0 + r;
                const void* g = (const void*)(B + (size_t)gn * K + k0 + schunk * 8);
                void* l = (void*)((char*)sB + (size_t)(w * 2048 + inst * 1024));
                __builtin_amdgcn_global_load_lds((const __attribute__((address_space(1))) void*)g,
                                                 (__attribute__((address_space(3))) void*)l, 16, 0, 0);
            }
            __syncthreads();

            bf8_t af[4], bf[4];
#pragma unroll
            for (int i = 0; i < 4; i++) {
                int row = wm + i * 16 + low;
                af[i] = *(const bf8_t*)&sA[row * BK + quad * 8];
            }
#pragma unroll
            for (int j = 0; j < 4; j++) {
                int row = wn + j * 16 + low;
                bf[j] = *(const bf8_t*)&sB[row * BK + quad * 8];
            }
#pragma unroll
            for (int i = 0; i < 4; i++)
#pragma unroll
                for (int j = 0; j < 4; j++)
                    acc[i][j] = __builtin_amdgcn_mfma_f32_16x16x32_bf16(af[i], bf[j], acc[i][j], 0, 0, 0);
        }
    }

#pragma unroll
    for (int i = 0; i < 4; i++) {
#pragma unroll
        for (int r = 0; r < 4; r++) {
            int gm = m0 + wm + i * 16 + quad * 4 + r;
            if (gm >= M) continue;
#pragma unroll
            for (int j = 0; j < 4; j++) {
                int gn = n0 + wn + j * 16 + low;
                C[(size_t)gm * N + gn] = acc[i][j][r];
            }
        }
    }
}

// ---------------------------------------------------------------------------
// attention logits
// ---------------------------------------------------------------------------
__global__ void al_h4_kernel(const float* __restrict__ h, const float* __restrict__ a_src,
                             const float* __restrict__ a_dst, float* __restrict__ als,
                             float* __restrict__ ald, int N) {
    int wave = threadIdx.x >> 6, lane = threadIdx.x & 63;
    int n = blockIdx.x * 4 + wave;
    if (n >= N) return;
    const float* row = h + (size_t)n * 512;
    float ps[4] = {0, 0, 0, 0}, pd[4] = {0, 0, 0, 0};
#pragma unroll
    for (int k = 0; k < 8; k++) {
        int f = k * 64 + lane;
        float v = row[f];
        ps[k >> 1] += v * a_src[f];
        pd[k >> 1] += v * a_dst[f];
    }
#pragma unroll
    for (int off = 32; off; off >>= 1) {
#pragma unroll
        for (int hd = 0; hd < 4; hd++) {
            ps[hd] += __shfl_down(ps[hd], off);
            pd[hd] += __shfl_down(pd[hd], off);
        }
    }
    if (lane == 0) {
#pragma unroll
        for (int hd = 0; hd < 4; hd++) {
            als[n * 4 + hd] = ps[hd];
            ald[n * 4 + hd] = pd[hd];
        }
    }
}

__global__ void al_h1_kernel(const float* __restrict__ h, const float* __restrict__ a_src,
                             const float* __restrict__ a_dst, float* __restrict__ als,
                             float* __restrict__ ald, int N) {
    int wave = threadIdx.x >> 6, lane = threadIdx.x & 63;
    int n = blockIdx.x * 4 + wave;
    if (n >= N) return;
    const float* row = h + (size_t)n * 128;
    float v0 = row[lane], v1 = row[lane + 64];
    float ps = v0 * a_src[lane] + v1 * a_src[lane + 64];
    float pd = v0 * a_dst[lane] + v1 * a_dst[lane + 64];
#pragma unroll
    for (int off = 32; off; off >>= 1) {
        ps += __shfl_down(ps, off);
        pd += __shfl_down(pd, off);
    }
    if (lane == 0) { als[n] = ps; ald[n] = pd; }
}

// ---------------------------------------------------------------------------
// Softmax stats per dst node -> NORMALIZED weights.
// pbuf is HEAD-MAJOR: pbuf[hd*E + edge_slot]. One wave per node; lane=es*4+hd.
// ---------------------------------------------------------------------------
__global__ void stats_h4_kernel(const int* __restrict__ csrc, const int* __restrict__ offs,
                                const float* __restrict__ als, const float* __restrict__ ald,
                                float* __restrict__ pbuf, float* __restrict__ psf, int N, int E) {
    int wave = threadIdx.x >> 6, lane = threadIdx.x & 63;
    int n = blockIdx.x * 4 + wave;
    if (n >= N) return;
    int hd = lane & 3, es = lane >> 2;   // head, edge slot 0..15
    float aldn = ald[n * 4 + hd];
    float selfe = als[n * 4 + hd] + aldn;
    selfe = selfe > 0.f ? selfe : LEAKY * selfe;
    int beg = offs[n], end = offs[n + 1];
    float* pb = pbuf + (size_t)hd * E;
    // pass 1: e + max
    float m = selfe;
    for (int base = beg; base + es < end; base += 16) {
        int idx = base + es;
        int s = csrc[idx];
        float e = als[s * 4 + hd] + aldn;
        e = e > 0.f ? e : LEAKY * e;
        pb[idx] = e;
        m = fmaxf(m, e);
    }
#pragma unroll
    for (int off = 4; off < 64; off <<= 1) m = fmaxf(m, __shfl_xor(m, off));
    // pass 2: p + denom
    float d = 0.f;
    for (int base = beg; base + es < end; base += 16) {
        int idx = base + es;
        float p = __expf(pb[idx] - m);
        pb[idx] = p;
        d += p;
    }
#pragma unroll
    for (int off = 4; off < 64; off <<= 1) d += __shfl_xor(d, off);
    float pself = __expf(selfe - m);
    float r = 1.0f / (d + pself + EPS_DEN);
    if (es == 0) psf[n * 4 + hd] = pself * r;
    // pass 3: normalize
    for (int base = beg; base + es < end; base += 16) {
        int idx = base + es;
        pb[idx] *= r;
    }
}

__global__ void stats_h1_kernel(const int* __restrict__ csrc, const int* __restrict__ offs,
                                const float* __restrict__ als, const float* __restrict__ ald,
                                float* __restrict__ pbuf, float* __restrict__ psf, int N) {
    int wave = threadIdx.x >> 6, lane = threadIdx.x & 63;
    int n = blockIdx.x * 4 + wave;
    if (n >= N) return;
    float aldn = ald[n];
    float selfe = als[n] + aldn;
    selfe = selfe > 0.f ? selfe : LEAKY * selfe;
    int beg = offs[n], end = offs[n + 1];
    float m = selfe;
    for (int base = beg; base + lane < end; base += 64) {
        int idx = base + lane;
        int s = csrc[idx];
        float e = als[s] + aldn;
        e = e > 0.f ? e : LEAKY * e;
        pbuf[idx] = e;
        m = fmaxf(m, e);
    }
#pragma unroll
    for (int off = 1; off < 64; off <<= 1) m = fmaxf(m, __shfl_xor(m, off));
    float d = 0.f;
    for (int base = beg; base + lane < end; base += 64) {
        int idx = base + lane;
        float p = __expf(pbuf[idx] - m);
        pbuf[idx] = p;
        d += p;
    }
#pragma unroll
    for (int off = 1; off < 64; off <<= 1) d += __shfl_xor(d, off);
    float pself = __expf(selfe - m);
    float r = 1.0f / (d + pself + EPS_DEN);
    if (lane == 0) psf[n] = pself * r;
    for (int base = beg; base + lane < end; base += 64) {
        int idx = base + lane;
        pbuf[idx] *= r;
    }
}

// ---------------------------------------------------------------------------
// Head-split aggregate: one 64-thread block per (node, head). head = blockIdx%4
// so under round-robin block->XCD dispatch each XCD works a ~5.1MB head slice
// (fits ~L2). Gathers 512B per edge. Weights prenormalized; bit-identical math
// to the fused version.
// ---------------------------------------------------------------------------
template <bool DO_ELU>
__global__ __launch_bounds__(64) void gat_aggregate_h4_kernel(
    const float* __restrict__ h, const float* __restrict__ pbuf,
    const float* __restrict__ psf, const int* __restrict__ csrc,
    const int* __restrict__ offs, const float* __restrict__ bias,
    unsigned short* __restrict__ ohi, unsigned short* __restrict__ olo, int N, int E) {
    int gid = blockIdx.x;
    int head = gid & 3;
    int n = gid >> 2;
    int lane = threadIdx.x;
    int f0 = head * 128 + lane * 2;
    const float* selfrow = h + (size_t)n * 512;
    const float* pb = pbuf + (size_t)head * E;
    float a0, a1;
    {
        float pself = psf[n * 4 + head];
        a0 = pself * selfrow[f0];
        a1 = pself * selfrow[f0 + 1];
    }
    __shared__ int sSrc[64];
    __shared__ float sP[64];
    int beg = offs[n], end = offs[n + 1];
    for (int base = beg; base < end; base += 64) {
        int len = min(64, end - base);
        __syncthreads();
        if (lane < len) {
            sSrc[lane] = csrc[base + lane];
            sP[lane] = pb[base + lane];
        }
        __syncthreads();
#pragma unroll 4
        for (int c = 0; c < len; c++) {
            const float* srow = h + (size_t)sSrc[c] * 512;
            float p = sP[c];
            float2 x = *(const float2*)(srow + f0);
            a0 += p * x.x;
            a1 += p * x.y;
        }
    }
    a0 += bias[f0];
    a1 += bias[f0 + 1];
    if (DO_ELU) {
        a0 = a0 > 0.f ? a0 : (__expf(a0) - 1.0f);
        a1 = a1 > 0.f ? a1 : (__expf(a1) - 1.0f);
    }
    size_t idx = (size_t)n * 512 + f0;
    us2_t hs, ls;
    unsigned short h0 = f2bf(a0), h1 = f2bf(a1);
    hs[0] = h0; hs[1] = h1;
    ls[0] = f2bf(a0 - bf2f(h0)); ls[1] = f2bf(a1 - bf2f(h1));
    *(us2_t*)&ohi[idx] = hs;
    *(us2_t*)&olo[idx] = ls;
}

// Generic lean aggregate (used for layer 3, H=1): NT*VEC == 128
template <int NT, int VEC>
__global__ void gat_aggregate_h1_kernel(const float* __restrict__ h, const float* __restrict__ pbuf,
                                        const float* __restrict__ psf, const int* __restrict__ csrc,
                                        const int* __restrict__ offs, const float* __restrict__ bias,
                                        float* __restrict__ outp, int N) {
    constexpr int F = 128;
    constexpr int CH = 64;
    __shared__ int sSrc[CH];
    __shared__ float sP[CH];
    int n = blockIdx.x;
    int t = threadIdx.x;
    int f0 = t * VEC;
    const float* selfrow = h + (size_t)n * F;
    float acc[VEC];
    {
        float pself = psf[n];
#pragma unroll
        for (int j = 0; j < VEC; j++) acc[j] = pself * selfrow[f0 + j];
    }
    int beg = offs[n], end = offs[n + 1];
    for (int base = beg; base < end; base += CH) {
        int len = min(CH, end - base);
        __syncthreads();
        for (int c = t; c < len; c += NT) {
            sSrc[c] = csrc[base + c];
            sP[c] = pbuf[base + c];
        }
        __syncthreads();
#pragma unroll 4
        for (int c = 0; c < len; c++) {
            const float* srow = h + (size_t)sSrc[c] * F;
            float p = sP[c];
            using vec_t = float __attribute__((ext_vector_type(VEC)));
            vec_t x = *(const vec_t*)(srow + f0);
#pragma unroll
            for (int j = 0; j < VEC; j++) acc[j] += p * x[j];
        }
    }
#pragma unroll
    for (int j = 0; j < VEC; j++) outp[(size_t)n * F + f0 + j] = acc[j] + bias[f0 + j];
}

// ---------------------------------------------------------------------------
// classifier
// ---------------------------------------------------------------------------
__global__ void classifier_kernel(const float* __restrict__ emb, const float* __restrict__ Wc1,
                                  const float* __restrict__ bc1, const float* __restrict__ Wc2,
                                  const float* __restrict__ bc2, float* __restrict__ out, int N) {
    int wave = threadIdx.x >> 6, lane = threadIdx.x & 63;
    int n = blockIdx.x * 4 + wave;
    if (n >= N) return;
    const float* row = emb + (size_t)n * 128;
    float acc = bc1[lane];
#pragma unroll 4
    for (int k = 0; k < 128; k++) acc += row[k] * Wc1[k * 64 + lane];
    acc = fmaxf(acc, 0.f);
    float o0 = acc * Wc2[lane * 2 + 0];
    float o1 = acc * Wc2[lane * 2 + 1];
#pragma unroll
    for (int off = 32; off; off >>= 1) {
        o0 += __shfl_down(o0, off);
        o1 += __shfl_down(o1, off);
    }
    if (lane == 0) {
        out[n * 2 + 0] = o0 + bc2[0];
        out[n * 2 + 1] = o1 + bc2[1];
    }
}

// ---------------------------------------------------------------------------
extern "C" void kernel_launch(void* const* d_in, const int* in_sizes, int n_in,
                              void* d_out, int out_size, void* d_ws, size_t ws_size,
                              hipStream_t stream) {
    const float* x      = (const float*)d_in[0];
    const int*   ei     = (const int*)d_in[1];
    const float* W1     = (const float*)d_in[2];
    const float* a1s    = (const float*)d_in[3];
    const float* a1d    = (const float*)d_in[4];
    const float* b1     = (const float*)d_in[5];
    const float* W2     = (const float*)d_in[6];
    const float* a2s    = (const float*)d_in[7];
    const float* a2d    = (const float*)d_in[8];
    const float* b2     = (const float*)d_in[9];
    const float* W3     = (const float*)d_in[10];
    const float* a3s    = (const float*)d_in[11];
    const float* a3d    = (const float*)d_in[12];
    const float* b3     = (const float*)d_in[13];
    const float* Wc1    = (const float*)d_in[14];
    const float* bc1    = (const float*)d_in[15];
    const float* Wc2    = (const float*)d_in[16];
    const float* bc2    = (const float*)d_in[17];

    const int N = in_sizes[0] / 256;       // 10000
    const int E = in_sizes[1] / 2;         // 320000
    const int F = 512;

    const int* src = ei;
    const int* dst = ei + E;

    auto align = [](size_t o) { return (o + 255) & ~(size_t)255; };
    size_t o = 0;
    size_t o_G     = o; o = align(o + (size_t)N * F * 4);        // GEMM output h (fp32)
    size_t o_ahi   = o; o = align(o + (size_t)N * F * 2);
    size_t o_alo   = o; o = align(o + (size_t)N * F * 2);
    size_t o_xhi   = o; o = align(o + (size_t)N * 256 * 2);
    size_t o_xlo   = o; o = align(o + (size_t)N * 256 * 2);
    size_t o_w1h   = o; o = align(o + (size_t)512 * 256 * 2);
    size_t o_w1l   = o; o = align(o + (size_t)512 * 256 * 2);
    size_t o_w2h   = o; o = align(o + (size_t)512 * 512 * 2);
    size_t o_w2l   = o; o = align(o + (size_t)512 * 512 * 2);
    size_t o_w3h   = o; o = align(o + (size_t)128 * 512 * 2);
    size_t o_w3l   = o; o = align(o + (size_t)128 * 512 * 2);
    size_t o_als   = o; o = align(o + (size_t)N * 4 * 4);
    size_t o_ald   = o; o = align(o + (size_t)N * 4 * 4);
    size_t o_psf   = o; o = align(o + (size_t)N * 4 * 4);
    size_t o_cnt   = o; o = align(o + (size_t)N * 4);
    size_t o_off   = o; o = align(o + (size_t)(N + 1) * 4);
    size_t o_bsum  = o; o = align(o + (size_t)64 * 4);
    size_t o_csrc  = o; o = align(o + (size_t)E * 4);
    size_t o_ebuf  = o; o = align(o + (size_t)E * 4 * 4);
    (void)ws_size;

    char* ws = (char*)d_ws;
    float* bufG  = (float*)(ws + o_G);
    unsigned short* act_hi = (unsigned short*)(ws + o_ahi);
    unsigned short* act_lo = (unsigned short*)(ws + o_alo);
    unsigned short* x_hi   = (unsigned short*)(ws + o_xhi);
    unsigned short* x_lo   = (unsigned short*)(ws + o_xlo);
    unsigned short* w1h = (unsigned short*)(ws + o_w1h);
    unsigned short* w1l = (unsigned short*)(ws + o_w1l);
    unsigned short* w2h = (unsigned short*)(ws + o_w2h);
    unsigned short* w2l = (unsigned short*)(ws + o_w2l);
    unsigned short* w3h = (unsigned short*)(ws + o_w3h);
    unsigned short* w3l = (unsigned short*)(ws + o_w3l);
    float* als  = (float*)(ws + o_als);
    float* ald  = (float*)(ws + o_ald);
    float* psf  = (float*)(ws + o_psf);
    int*   cnt  = (int*)(ws + o_cnt);
    int*   offs = (int*)(ws + o_off);
    int*   bsum = (int*)(ws + o_bsum);
    int*   csrc = (int*)(ws + o_csrc);
    float* ebuf = (float*)(ws + o_ebuf);

    float* outp = (float*)d_out;                 // [N,2]
    float* emb  = (float*)d_out + (size_t)N * 2; // [N,128]

    // ---- CSR build ----
    hipMemsetAsync(cnt, 0, (size_t)N * 4, stream);
    int eb = (E + 255) / 256;
    int nbs = (N + 255) / 256;   // 40
    hipLaunchKernelGGL(hist_kernel, dim3(eb), dim3(256), 0, stream, dst, cnt, E);
    hipLaunchKernelGGL(scan1_kernel, dim3(nbs), dim3(256), 0, stream, cnt, bsum, N);
    hipLaunchKernelGGL(scan2_kernel, dim3(1), dim3(64), 0, stream, bsum, offs, nbs, N);
    hipLaunchKernelGGL(scan3_kernel, dim3(nbs), dim3(256), 0, stream, cnt, bsum, offs, N);
    hipLaunchKernelGGL(scatter_kernel, dim3(eb), dim3(256), 0, stream, src, dst, cnt, csrc, E);

    // ---- splits ----
    hipLaunchKernelGGL(split_kernel, dim3((N * 256 + 255) / 256), dim3(256), 0, stream,
                       x, x_hi, x_lo, N * 256);
    hipLaunchKernelGGL(wsplit_kernel, dim3((256 * 512 + 255) / 256), dim3(256), 0, stream,
                       W1, w1h, w1l, 256, 512);
    hipLaunchKernelGGL(wsplit_kernel, dim3((512 * 512 + 255) / 256), dim3(256), 0, stream,
                       W2, w2h, w2l, 512, 512);
    hipLaunchKernelGGL(wsplit_kernel, dim3((512 * 128 + 255) / 256), dim3(256), 0, stream,
                       W3, w3h, w3l, 512, 128);

    int nb4 = (N + 3) / 4;
    int gy  = (N + 127) / 128;

    // ---- layer 1 ----
    hipLaunchKernelGGL(mfma_gemm_kernel, dim3(512 / 128, gy), dim3(256), 0, stream,
                       x_hi, x_lo, w1h, w1l, bufG, N, 512, 256);
    hipLaunchKernelGGL(al_h4_kernel, dim3(nb4), dim3(256), 0, stream, bufG, a1s, a1d, als, ald, N);
    hipLaunchKernelGGL(stats_h4_kernel, dim3(nb4), dim3(256), 0, stream,
                       csrc, offs, als, ald, ebuf, psf, N, E);
    hipLaunchKernelGGL((gat_aggregate_h4_kernel<true>), dim3(N * 4), dim3(64), 0, stream,
                       bufG, ebuf, psf, csrc, offs, b1, act_hi, act_lo, N, E);

    // ---- layer 2 ----
    hipLaunchKernelGGL(mfma_gemm_kernel, dim3(512 / 128, gy), dim3(256), 0, stream,
                       act_hi, act_lo, w2h, w2l, bufG, N, 512, 512);
    hipLaunchKernelGGL(al_h4_kernel, dim3(nb4), dim3(256), 0, stream, bufG, a2s, a2d, als, ald, N);
    hipLaunchKernelGGL(stats_h4_kernel, dim3(nb4), dim3(256), 0, stream,
                       csrc, offs, als, ald, ebuf, psf, N, E);
    hipLaunchKernelGGL((gat_aggregate_h4_kernel<true>), dim3(N * 4), dim3(64), 0, stream,
                       bufG, ebuf, psf, csrc, offs, b2, act_hi, act_lo, N, E);

    // ---- layer 3 (1 head, concat=False -> mean over 1 head == identity) ----
    hipLaunchKernelGGL(mfma_gemm_kernel, dim3(128 / 128, gy), dim3(256), 0, stream,
                       act_hi, act_lo, w3h, w3l, bufG, N, 128, 512);
    hipLaunchKernelGGL(al_h1_kernel, dim3(nb4), dim3(256), 0, stream, bufG, a3s, a3d, als, ald, N);
    hipLaunchKernelGGL(stats_h1_kernel, dim3(nb4), dim3(256), 0, stream,
                       csrc, offs, als, ald, ebuf, psf, N);
    hipLaunchKernelGGL((gat_aggregate_h1_kernel<64, 2>), dim3(N), dim3(64), 0, stream,
                       bufG, ebuf, psf, csrc, offs, b3, emb, N);

    // ---- classifier ----
    hipLaunchKernelGGL(classifier_kernel, dim3(nb4), dim3(256), 0, stream,
                       emb, Wc1, bc1, Wc2, bc2, outp, N);
}

// Round 6
// 397.441 us; speedup vs baseline: 1.3447x; 1.0601x over previous
//
#include <hip/hip_runtime.h>
#include <cstddef>

#define LEAKY 0.2f
#define EPS_DEN 1e-16f

typedef short bf8_t __attribute__((ext_vector_type(8)));   // 8 bf16 in 4 VGPRs
typedef float f4_t __attribute__((ext_vector_type(4)));
typedef unsigned short us4_t __attribute__((ext_vector_type(4)));

__device__ __forceinline__ unsigned short f2bf(float f) {   // RNE
    unsigned u = __float_as_uint(f);
    unsigned r = (u + 0x7fffu + ((u >> 16) & 1u)) >> 16;
    return (unsigned short)r;
}
__device__ __forceinline__ float bf2f(unsigned short h) {
    return __uint_as_float(((unsigned)h) << 16);
}

// ---------------------------------------------------------------------------
// CSR build: histogram -> 3-phase parallel scan -> scatter
// ---------------------------------------------------------------------------
__global__ void hist_kernel(const int* __restrict__ dst, int* __restrict__ counts, int E) {
    int i = blockIdx.x * blockDim.x + threadIdx.x;
    if (i < E) atomicAdd(&counts[dst[i]], 1);
}

__global__ void scan1_kernel(int* __restrict__ cnt, int* __restrict__ bsum, int N) {
    __shared__ int s[256];
    int t = threadIdx.x;
    int i = blockIdx.x * 256 + t;
    int v = (i < N) ? cnt[i] : 0;
    s[t] = v;
    __syncthreads();
#pragma unroll
    for (int st = 1; st < 256; st <<= 1) {
        int add = (t >= st) ? s[t - st] : 0;
        __syncthreads();
        s[t] += add;
        __syncthreads();
    }
    if (i < N) cnt[i] = s[t] - v;           // exclusive within block
    if (t == 255) bsum[blockIdx.x] = s[255];
}

__global__ void scan2_kernel(int* __restrict__ bsum, int* __restrict__ offs, int NB, int N) {
    int t = threadIdx.x;   // 64 threads
    int v = (t < NB) ? bsum[t] : 0;
    int inc = v;
#pragma unroll
    for (int off = 1; off < 64; off <<= 1) {
        int u = __shfl_up(inc, off);
        if (t >= off) inc += u;
    }
    if (t < NB) bsum[t] = inc - v;          // exclusive
    if (t == 63) offs[N] = inc;             // total
}

__global__ void scan3_kernel(int* __restrict__ cnt, const int* __restrict__ bsum,
                             int* __restrict__ offs, int N) {
    int i = blockIdx.x * 256 + threadIdx.x;
    if (i < N) {
        int o = cnt[i] + bsum[blockIdx.x];
        offs[i] = o;
        cnt[i] = o;
    }
}

__global__ void scatter_kernel(const int* __restrict__ src, const int* __restrict__ dst,
                               int* __restrict__ cursor, int* __restrict__ csrc, int E) {
    int i = blockIdx.x * blockDim.x + threadIdx.x;
    if (i < E) {
        int d = dst[i];
        int pos = atomicAdd(&cursor[d], 1);
        csrc[pos] = src[i];
    }
}

// ---------------------------------------------------------------------------
// split fp32 -> bf16 hi + bf16 lo
// ---------------------------------------------------------------------------
__global__ void split_kernel(const float* __restrict__ in, unsigned short* __restrict__ hi,
                             unsigned short* __restrict__ lo, int len) {
    int i = blockIdx.x * blockDim.x + threadIdx.x;
    if (i >= len) return;
    float v = in[i];
    unsigned short h = f2bf(v);
    hi[i] = h;
    lo[i] = f2bf(v - bf2f(h));
}

// W [K,N] fp32  ->  WT_hi/lo [N,K] bf16 (transpose + split)
__global__ void wsplit_kernel(const float* __restrict__ W, unsigned short* __restrict__ hi,
                              unsigned short* __restrict__ lo, int K, int N) {
    int idx = blockIdx.x * blockDim.x + threadIdx.x;
    if (idx >= K * N) return;
    int n = idx / K, k = idx % K;
    float v = W[(size_t)k * N + n];
    unsigned short h = f2bf(v);
    hi[idx] = h;
    lo[idx] = f2bf(v - bf2f(h));
}

// ---------------------------------------------------------------------------
// MFMA GEMM (split-bf16, 3 passes): C[M,N] = (Ahi+Alo) @ BT^T  (BT stored [N,K])
// 64x128 tile, BK=32, 4 waves, 2x4 16x16 tiles/wave -> 2x block count vs 128x128
// for better occupancy at skinny M-grid shapes (M=10000 -> 157 M-blocks).
// ---------------------------------------------------------------------------
__global__ __launch_bounds__(256) void mfma_gemm_kernel(
    const unsigned short* __restrict__ Ahi, const unsigned short* __restrict__ Alo,
    const unsigned short* __restrict__ BThi, const unsigned short* __restrict__ BTlo,
    float* __restrict__ C, int M, int N, int K) {
    constexpr int BK = 32;
    __shared__ __align__(16) unsigned short sA[64 * BK];    // 4 KB
    __shared__ __align__(16) unsigned short sB[128 * BK];   // 8 KB
    int t = threadIdx.x;
    int w = t >> 6, lane = t & 63;
    int quad = lane >> 4, low = lane & 15;
    int m0 = blockIdx.y * 64, n0 = blockIdx.x * 128;
    int wm = (w & 1) * 32, wn = (w >> 1) * 64;

    f4_t acc[2][4];
#pragma unroll
    for (int i = 0; i < 2; i++)
#pragma unroll
        for (int j = 0; j < 4; j++) acc[i][j] = (f4_t){0.f, 0.f, 0.f, 0.f};

    int srow = lane >> 2;     // 0..15
    int schunk = lane & 3;    // 0..3 (16B chunk within 64B k-row)

    const unsigned short* Ap[3] = {Ahi, Ahi, Alo};
    const unsigned short* Bp[3] = {BThi, BTlo, BThi};

    for (int pass = 0; pass < 3; pass++) {
        const unsigned short* A = Ap[pass];
        const unsigned short* B = Bp[pass];
        for (int k0 = 0; k0 < K; k0 += BK) {
            __syncthreads();
            {   // sA: 64 rows, wave w stages rows w*16 .. w*16+15
                int gm = m0 + w * 16 + srow;
                if (gm >= M) gm = M - 1;
                const void* g = (const void*)(A + (size_t)gm * K + k0 + schunk * 8);
                void* l = (void*)((char*)sA + (size_t)(w * 1024));
                __builtin_amdgcn_global_load_lds((const __attribute__((address_space(1))) void*)g,
                                                 (__attribute__((address_space(3))) void*)l, 16, 0, 0);
            }
#pragma unroll
            for (int inst = 0; inst < 2; inst++) {   // sB: 128 rows
                int gn = n0 + w * 32 + inst * 16 + srow;
                const void* g = (const void*)(B + (size_t)gn * K + k0 + schunk * 8);
                void* l = (void*)((char*)sB + (size_t)(w * 2048 + inst * 1024));
                __builtin_amdgcn_global_load_lds((const __attribute__((address_space(1))) void*)g,
                                                 (__attribute__((address_space(3))) void*)l, 16, 0, 0);
            }
            __syncthreads();

            bf8_t af[2], bf[4];
#pragma unroll
            for (int i = 0; i < 2; i++) {
                int row = wm + i * 16 + low;
                af[i] = *(const bf8_t*)&sA[row * BK + quad * 8];
            }
#pragma unroll
            for (int j = 0; j < 4; j++) {
                int row = wn + j * 16 + low;
                bf[j] = *(const bf8_t*)&sB[row * BK + quad * 8];
            }
#pragma unroll
            for (int i = 0; i < 2; i++)
#pragma unroll
                for (int j = 0; j < 4; j++)
                    acc[i][j] = __builtin_amdgcn_mfma_f32_16x16x32_bf16(af[i], bf[j], acc[i][j], 0, 0, 0);
        }
    }

    // C/D layout: col = lane&15, row = quad*4 + reg
#pragma unroll
    for (int i = 0; i < 2; i++) {
#pragma unroll
        for (int r = 0; r < 4; r++) {
            int gm = m0 + wm + i * 16 + quad * 4 + r;
            if (gm >= M) continue;
#pragma unroll
            for (int j = 0; j < 4; j++) {
                int gn = n0 + wn + j * 16 + low;
                C[(size_t)gm * N + gn] = acc[i][j][r];
            }
        }
    }
}

// ---------------------------------------------------------------------------
// attention logits
// ---------------------------------------------------------------------------
__global__ void al_h4_kernel(const float* __restrict__ h, const float* __restrict__ a_src,
                             const float* __restrict__ a_dst, float* __restrict__ als,
                             float* __restrict__ ald, int N) {
    int wave = threadIdx.x >> 6, lane = threadIdx.x & 63;
    int n = blockIdx.x * 4 + wave;
    if (n >= N) return;
    const float* row = h + (size_t)n * 512;
    float ps[4] = {0, 0, 0, 0}, pd[4] = {0, 0, 0, 0};
#pragma unroll
    for (int k = 0; k < 8; k++) {
        int f = k * 64 + lane;
        float v = row[f];
        ps[k >> 1] += v * a_src[f];
        pd[k >> 1] += v * a_dst[f];
    }
#pragma unroll
    for (int off = 32; off; off >>= 1) {
#pragma unroll
        for (int hd = 0; hd < 4; hd++) {
            ps[hd] += __shfl_down(ps[hd], off);
            pd[hd] += __shfl_down(pd[hd], off);
        }
    }
    if (lane == 0) {
#pragma unroll
        for (int hd = 0; hd < 4; hd++) {
            als[n * 4 + hd] = ps[hd];
            ald[n * 4 + hd] = pd[hd];
        }
    }
}

__global__ void al_h1_kernel(const float* __restrict__ h, const float* __restrict__ a_src,
                             const float* __restrict__ a_dst, float* __restrict__ als,
                             float* __restrict__ ald, int N) {
    int wave = threadIdx.x >> 6, lane = threadIdx.x & 63;
    int n = blockIdx.x * 4 + wave;
    if (n >= N) return;
    const float* row = h + (size_t)n * 128;
    float v0 = row[lane], v1 = row[lane + 64];
    float ps = v0 * a_src[lane] + v1 * a_src[lane + 64];
    float pd = v0 * a_dst[lane] + v1 * a_dst[lane + 64];
#pragma unroll
    for (int off = 32; off; off >>= 1) {
        ps += __shfl_down(ps, off);
        pd += __shfl_down(pd, off);
    }
    if (lane == 0) { als[n] = ps; ald[n] = pd; }
}

// ---------------------------------------------------------------------------
// Softmax stats per dst node -> UNNORMALIZED weights p = exp(e - max) in pbuf
// (head-major pbuf[hd*E+slot]); psf = unnormalized self weight; rden = 1/(sum+eps).
// Aggregate multiplies by rden in its epilogue (pass-3 normalize eliminated).
// ---------------------------------------------------------------------------
__global__ void stats_h4_kernel(const int* __restrict__ csrc, const int* __restrict__ offs,
                                const float* __restrict__ als, const float* __restrict__ ald,
                                float* __restrict__ pbuf, float* __restrict__ psf,
                                float* __restrict__ rden, int N, int E) {
    int wave = threadIdx.x >> 6, lane = threadIdx.x & 63;
    int n = blockIdx.x * 4 + wave;
    if (n >= N) return;
    int hd = lane & 3, es = lane >> 2;   // head, edge slot 0..15
    float aldn = ald[n * 4 + hd];
    float selfe = als[n * 4 + hd] + aldn;
    selfe = selfe > 0.f ? selfe : LEAKY * selfe;
    int beg = offs[n], end = offs[n + 1];
    float* pb = pbuf + (size_t)hd * E;
    // pass 1: e + max
    float m = selfe;
    for (int base = beg; base + es < end; base += 16) {
        int idx = base + es;
        int s = csrc[idx];
        float e = als[s * 4 + hd] + aldn;
        e = e > 0.f ? e : LEAKY * e;
        pb[idx] = e;
        m = fmaxf(m, e);
    }
#pragma unroll
    for (int off = 4; off < 64; off <<= 1) m = fmaxf(m, __shfl_xor(m, off));
    // pass 2: p + denom
    float d = 0.f;
    for (int base = beg; base + es < end; base += 16) {
        int idx = base + es;
        float p = __expf(pb[idx] - m);
        pb[idx] = p;
        d += p;
    }
#pragma unroll
    for (int off = 4; off < 64; off <<= 1) d += __shfl_xor(d, off);
    float pself = __expf(selfe - m);
    float r = 1.0f / (d + pself + EPS_DEN);
    if (es == 0) {
        psf[n * 4 + hd] = pself;
        rden[n * 4 + hd] = r;
    }
}

__global__ void stats_h1_kernel(const int* __restrict__ csrc, const int* __restrict__ offs,
                                const float* __restrict__ als, const float* __restrict__ ald,
                                float* __restrict__ pbuf, float* __restrict__ psf,
                                float* __restrict__ rden, int N) {
    int wave = threadIdx.x >> 6, lane = threadIdx.x & 63;
    int n = blockIdx.x * 4 + wave;
    if (n >= N) return;
    float aldn = ald[n];
    float selfe = als[n] + aldn;
    selfe = selfe > 0.f ? selfe : LEAKY * selfe;
    int beg = offs[n], end = offs[n + 1];
    float m = selfe;
    for (int base = beg; base + lane < end; base += 64) {
        int idx = base + lane;
        int s = csrc[idx];
        float e = als[s] + aldn;
        e = e > 0.f ? e : LEAKY * e;
        pbuf[idx] = e;
        m = fmaxf(m, e);
    }
#pragma unroll
    for (int off = 1; off < 64; off <<= 1) m = fmaxf(m, __shfl_xor(m, off));
    float d = 0.f;
    for (int base = beg; base + lane < end; base += 64) {
        int idx = base + lane;
        float p = __expf(pbuf[idx] - m);
        pbuf[idx] = p;
        d += p;
    }
#pragma unroll
    for (int off = 1; off < 64; off <<= 1) d += __shfl_xor(d, off);
    float pself = __expf(selfe - m);
    float r = 1.0f / (d + pself + EPS_DEN);
    if (lane == 0) { psf[n] = pself; rden[n] = r; }
}

// ---------------------------------------------------------------------------
// Head-split aggregate, 2-edges-per-iteration float4 form (MLP x4):
// lanes 0-31 take even edges, 32-63 odd; each lane loads float4 of features.
// Halves combined with one shfl_xor(32). Weights unnormalized; *rden at end.
// ---------------------------------------------------------------------------
template <bool DO_ELU>
__global__ __launch_bounds__(64) void gat_aggregate_h4_kernel(
    const float* __restrict__ h, const float* __restrict__ pbuf,
    const float* __restrict__ psf, const float* __restrict__ rden,
    const int* __restrict__ csrc, const int* __restrict__ offs,
    const float* __restrict__ bias, unsigned short* __restrict__ ohi,
    unsigned short* __restrict__ olo, int N, int E) {
    int gid = blockIdx.x;
    int head = gid & 3;
    int n = gid >> 2;
    int lane = threadIdx.x;
    int half = lane >> 5;             // edge parity
    int fl = (lane & 31) * 4;         // feature offset within head
    int f0 = head * 128 + fl;
    const float* pb = pbuf + (size_t)head * E;
    f4_t acc;
    {
        float pself = (half == 0) ? psf[n * 4 + head] : 0.f;  // self only in half 0
        f4_t x = *(const f4_t*)(h + (size_t)n * 512 + f0);
        acc = pself * x;
    }
    __shared__ int sSrc[64];
    __shared__ float sP[64];
    int beg = offs[n], end = offs[n + 1];
    for (int base = beg; base < end; base += 64) {
        int len = min(64, end - base);
        __syncthreads();
        if (lane < len) {
            sSrc[lane] = csrc[base + lane];
            sP[lane] = pb[base + lane];
        }
        __syncthreads();
#pragma unroll 8
        for (int c = half; c < len; c += 2) {
            const float* srow = h + (size_t)sSrc[c] * 512;
            float p = sP[c];
            f4_t x = *(const f4_t*)(srow + f0);
            acc += p * x;
        }
    }
    // combine the two halves
#pragma unroll
    for (int j = 0; j < 4; j++) acc[j] += __shfl_xor(acc[j], 32);
    float r = rden[n * 4 + head];
    f4_t b = *(const f4_t*)(bias + f0);
    us4_t hs, ls;
#pragma unroll
    for (int j = 0; j < 4; j++) {
        float o = acc[j] * r + b[j];
        if (DO_ELU) o = o > 0.f ? o : (__expf(o) - 1.0f);
        unsigned short hh = f2bf(o);
        hs[j] = hh;
        ls[j] = f2bf(o - bf2f(hh));
    }
    if (half == 0) {
        size_t idx = (size_t)n * 512 + f0;
        *(us4_t*)&ohi[idx] = hs;
        *(us4_t*)&olo[idx] = ls;
    }
}

// Layer-3 aggregate (H=1, F=128), same 2-edge float4 structure, fp32 out.
__global__ __launch_bounds__(64) void gat_aggregate_h1_kernel(
    const float* __restrict__ h, const float* __restrict__ pbuf,
    const float* __restrict__ psf, const float* __restrict__ rden,
    const int* __restrict__ csrc, const int* __restrict__ offs,
    const float* __restrict__ bias, float* __restrict__ outp, int N) {
    int n = blockIdx.x;
    int lane = threadIdx.x;
    int half = lane >> 5;
    int f0 = (lane & 31) * 4;
    f4_t acc;
    {
        float pself = (half == 0) ? psf[n] : 0.f;
        f4_t x = *(const f4_t*)(h + (size_t)n * 128 + f0);
        acc = pself * x;
    }
    __shared__ int sSrc[64];
    __shared__ float sP[64];
    int beg = offs[n], end = offs[n + 1];
    for (int base = beg; base < end; base += 64) {
        int len = min(64, end - base);
        __syncthreads();
        if (lane < len) {
            sSrc[lane] = csrc[base + lane];
            sP[lane] = pbuf[base + lane];
        }
        __syncthreads();
#pragma unroll 8
        for (int c = half; c < len; c += 2) {
            const float* srow = h + (size_t)sSrc[c] * 128;
            float p = sP[c];
            f4_t x = *(const f4_t*)(srow + f0);
            acc += p * x;
        }
    }
#pragma unroll
    for (int j = 0; j < 4; j++) acc[j] += __shfl_xor(acc[j], 32);
    if (half == 0) {
        float r = rden[n];
        f4_t b = *(const f4_t*)(bias + f0);
        f4_t o;
#pragma unroll
        for (int j = 0; j < 4; j++) o[j] = acc[j] * r + b[j];
        *(f4_t*)&outp[(size_t)n * 128 + f0] = o;
    }
}

// ---------------------------------------------------------------------------
// classifier
// ---------------------------------------------------------------------------
__global__ void classifier_kernel(const float* __restrict__ emb, const float* __restrict__ Wc1,
                                  const float* __restrict__ bc1, const float* __restrict__ Wc2,
                                  const float* __restrict__ bc2, float* __restrict__ out, int N) {
    int wave = threadIdx.x >> 6, lane = threadIdx.x & 63;
    int n = blockIdx.x * 4 + wave;
    if (n >= N) return;
    const float* row = emb + (size_t)n * 128;
    float acc = bc1[lane];
#pragma unroll 4
    for (int k = 0; k < 128; k++) acc += row[k] * Wc1[k * 64 + lane];
    acc = fmaxf(acc, 0.f);
    float o0 = acc * Wc2[lane * 2 + 0];
    float o1 = acc * Wc2[lane * 2 + 1];
#pragma unroll
    for (int off = 32; off; off >>= 1) {
        o0 += __shfl_down(o0, off);
        o1 += __shfl_down(o1, off);
    }
    if (lane == 0) {
        out[n * 2 + 0] = o0 + bc2[0];
        out[n * 2 + 1] = o1 + bc2[1];
    }
}

// ---------------------------------------------------------------------------
extern "C" void kernel_launch(void* const* d_in, const int* in_sizes, int n_in,
                              void* d_out, int out_size, void* d_ws, size_t ws_size,
                              hipStream_t stream) {
    const float* x      = (const float*)d_in[0];
    const int*   ei     = (const int*)d_in[1];
    const float* W1     = (const float*)d_in[2];
    const float* a1s    = (const float*)d_in[3];
    const float* a1d    = (const float*)d_in[4];
    const float* b1     = (const float*)d_in[5];
    const float* W2     = (const float*)d_in[6];
    const float* a2s    = (const float*)d_in[7];
    const float* a2d    = (const float*)d_in[8];
    const float* b2     = (const float*)d_in[9];
    const float* W3     = (const float*)d_in[10];
    const float* a3s    = (const float*)d_in[11];
    const float* a3d    = (const float*)d_in[12];
    const float* b3     = (const float*)d_in[13];
    const float* Wc1    = (const float*)d_in[14];
    const float* bc1    = (const float*)d_in[15];
    const float* Wc2    = (const float*)d_in[16];
    const float* bc2    = (const float*)d_in[17];

    const int N = in_sizes[0] / 256;       // 10000
    const int E = in_sizes[1] / 2;         // 320000
    const int F = 512;

    const int* src = ei;
    const int* dst = ei + E;

    auto align = [](size_t o) { return (o + 255) & ~(size_t)255; };
    size_t o = 0;
    size_t o_G     = o; o = align(o + (size_t)N * F * 4);        // GEMM output h (fp32)
    size_t o_ahi   = o; o = align(o + (size_t)N * F * 2);
    size_t o_alo   = o; o = align(o + (size_t)N * F * 2);
    size_t o_xhi   = o; o = align(o + (size_t)N * 256 * 2);
    size_t o_xlo   = o; o = align(o + (size_t)N * 256 * 2);
    size_t o_w1h   = o; o = align(o + (size_t)512 * 256 * 2);
    size_t o_w1l   = o; o = align(o + (size_t)512 * 256 * 2);
    size_t o_w2h   = o; o = align(o + (size_t)512 * 512 * 2);
    size_t o_w2l   = o; o = align(o + (size_t)512 * 512 * 2);
    size_t o_w3h   = o; o = align(o + (size_t)128 * 512 * 2);
    size_t o_w3l   = o; o = align(o + (size_t)128 * 512 * 2);
    size_t o_als   = o; o = align(o + (size_t)N * 4 * 4);
    size_t o_ald   = o; o = align(o + (size_t)N * 4 * 4);
    size_t o_psf   = o; o = align(o + (size_t)N * 4 * 4);
    size_t o_rden  = o; o = align(o + (size_t)N * 4 * 4);
    size_t o_cnt   = o; o = align(o + (size_t)N * 4);
    size_t o_off   = o; o = align(o + (size_t)(N + 1) * 4);
    size_t o_bsum  = o; o = align(o + (size_t)64 * 4);
    size_t o_csrc  = o; o = align(o + (size_t)E * 4);
    size_t o_ebuf  = o; o = align(o + (size_t)E * 4 * 4);
    (void)ws_size;

    char* ws = (char*)d_ws;
    float* bufG  = (float*)(ws + o_G);
    unsigned short* act_hi = (unsigned short*)(ws + o_ahi);
    unsigned short* act_lo = (unsigned short*)(ws + o_alo);
    unsigned short* x_hi   = (unsigned short*)(ws + o_xhi);
    unsigned short* x_lo   = (unsigned short*)(ws + o_xlo);
    unsigned short* w1h = (unsigned short*)(ws + o_w1h);
    unsigned short* w1l = (unsigned short*)(ws + o_w1l);
    unsigned short* w2h = (unsigned short*)(ws + o_w2h);
    unsigned short* w2l = (unsigned short*)(ws + o_w2l);
    unsigned short* w3h = (unsigned short*)(ws + o_w3h);
    unsigned short* w3l = (unsigned short*)(ws + o_w3l);
    float* als  = (float*)(ws + o_als);
    float* ald  = (float*)(ws + o_ald);
    float* psf  = (float*)(ws + o_psf);
    float* rden = (float*)(ws + o_rden);
    int*   cnt  = (int*)(ws + o_cnt);
    int*   offs = (int*)(ws + o_off);
    int*   bsum = (int*)(ws + o_bsum);
    int*   csrc = (int*)(ws + o_csrc);
    float* ebuf = (float*)(ws + o_ebuf);

    float* outp = (float*)d_out;                 // [N,2]
    float* emb  = (float*)d_out + (size_t)N * 2; // [N,128]

    // ---- CSR build ----
    hipMemsetAsync(cnt, 0, (size_t)N * 4, stream);
    int eb = (E + 255) / 256;
    int nbs = (N + 255) / 256;   // 40
    hipLaunchKernelGGL(hist_kernel, dim3(eb), dim3(256), 0, stream, dst, cnt, E);
    hipLaunchKernelGGL(scan1_kernel, dim3(nbs), dim3(256), 0, stream, cnt, bsum, N);
    hipLaunchKernelGGL(scan2_kernel, dim3(1), dim3(64), 0, stream, bsum, offs, nbs, N);
    hipLaunchKernelGGL(scan3_kernel, dim3(nbs), dim3(256), 0, stream, cnt, bsum, offs, N);
    hipLaunchKernelGGL(scatter_kernel, dim3(eb), dim3(256), 0, stream, src, dst, cnt, csrc, E);

    // ---- splits ----
    hipLaunchKernelGGL(split_kernel, dim3((N * 256 + 255) / 256), dim3(256), 0, stream,
                       x, x_hi, x_lo, N * 256);
    hipLaunchKernelGGL(wsplit_kernel, dim3((256 * 512 + 255) / 256), dim3(256), 0, stream,
                       W1, w1h, w1l, 256, 512);
    hipLaunchKernelGGL(wsplit_kernel, dim3((512 * 512 + 255) / 256), dim3(256), 0, stream,
                       W2, w2h, w2l, 512, 512);
    hipLaunchKernelGGL(wsplit_kernel, dim3((512 * 128 + 255) / 256), dim3(256), 0, stream,
                       W3, w3h, w3l, 512, 128);

    int nb4 = (N + 3) / 4;
    int gy  = (N + 63) / 64;     // 64-row M tiles -> 157

    // ---- layer 1 ----
    hipLaunchKernelGGL(mfma_gemm_kernel, dim3(512 / 128, gy), dim3(256), 0, stream,
                       x_hi, x_lo, w1h, w1l, bufG, N, 512, 256);
    hipLaunchKernelGGL(al_h4_kernel, dim3(nb4), dim3(256), 0, stream, bufG, a1s, a1d, als, ald, N);
    hipLaunchKernelGGL(stats_h4_kernel, dim3(nb4), dim3(256), 0, stream,
                       csrc, offs, als, ald, ebuf, psf, rden, N, E);
    hipLaunchKernelGGL((gat_aggregate_h4_kernel<true>), dim3(N * 4), dim3(64), 0, stream,
                       bufG, ebuf, psf, rden, csrc, offs, b1, act_hi, act_lo, N, E);

    // ---- layer 2 ----
    hipLaunchKernelGGL(mfma_gemm_kernel, dim3(512 / 128, gy), dim3(256), 0, stream,
                       act_hi, act_lo, w2h, w2l, bufG, N, 512, 512);
    hipLaunchKernelGGL(al_h4_kernel, dim3(nb4), dim3(256), 0, stream, bufG, a2s, a2d, als, ald, N);
    hipLaunchKernelGGL(stats_h4_kernel, dim3(nb4), dim3(256), 0, stream,
                       csrc, offs, als, ald, ebuf, psf, rden, N, E);
    hipLaunchKernelGGL((gat_aggregate_h4_kernel<true>), dim3(N * 4), dim3(64), 0, stream,
                       bufG, ebuf, psf, rden, csrc, offs, b2, act_hi, act_lo, N, E);

    // ---- layer 3 (1 head, concat=False -> mean over 1 head == identity) ----
    hipLaunchKernelGGL(mfma_gemm_kernel, dim3(128 / 128, gy), dim3(256), 0, stream,
                       act_hi, act_lo, w3h, w3l, bufG, N, 128, 512);
    hipLaunchKernelGGL(al_h1_kernel, dim3(nb4), dim3(256), 0, stream, bufG, a3s, a3d, als, ald, N);
    hipLaunchKernelGGL(stats_h1_kernel, dim3(nb4), dim3(256), 0, stream,
                       csrc, offs, als, ald, ebuf, psf, rden, N);
    hipLaunchKernelGGL(gat_aggregate_h1_kernel, dim3(N), dim3(64), 0, stream,
                       bufG, ebuf, psf, rden, csrc, offs, b3, emb, N);

    // ---- classifier ----
    hipLaunchKernelGGL(classifier_kernel, dim3(nb4), dim3(256), 0, stream,
                       emb, Wc1, bc1, Wc2, bc2, outp, N);
}

// Round 7
// 396.315 us; speedup vs baseline: 1.3485x; 1.0028x over previous
//
#include <hip/hip_runtime.h>
#include <cstddef>

#define LEAKY 0.2f
#define EPS_DEN 1e-16f

typedef short bf8_t __attribute__((ext_vector_type(8)));   // 8 bf16 in 4 VGPRs
typedef float f4_t __attribute__((ext_vector_type(4)));
typedef unsigned short us4_t __attribute__((ext_vector_type(4)));

__device__ __forceinline__ unsigned short f2bf(float f) {   // RNE
    unsigned u = __float_as_uint(f);
    unsigned r = (u + 0x7fffu + ((u >> 16) & 1u)) >> 16;
    return (unsigned short)r;
}
__device__ __forceinline__ float bf2f(unsigned short h) {
    return __uint_as_float(((unsigned)h) << 16);
}

// ---------------------------------------------------------------------------
// CSR build: histogram -> 3-phase parallel scan -> scatter
// ---------------------------------------------------------------------------
__global__ void hist_kernel(const int* __restrict__ dst, int* __restrict__ counts, int E) {
    int i = blockIdx.x * blockDim.x + threadIdx.x;
    if (i < E) atomicAdd(&counts[dst[i]], 1);
}

__global__ void scan1_kernel(int* __restrict__ cnt, int* __restrict__ bsum, int N) {
    __shared__ int s[256];
    int t = threadIdx.x;
    int i = blockIdx.x * 256 + t;
    int v = (i < N) ? cnt[i] : 0;
    s[t] = v;
    __syncthreads();
#pragma unroll
    for (int st = 1; st < 256; st <<= 1) {
        int add = (t >= st) ? s[t - st] : 0;
        __syncthreads();
        s[t] += add;
        __syncthreads();
    }
    if (i < N) cnt[i] = s[t] - v;           // exclusive within block
    if (t == 255) bsum[blockIdx.x] = s[255];
}

__global__ void scan2_kernel(int* __restrict__ bsum, int* __restrict__ offs, int NB, int N) {
    int t = threadIdx.x;   // 64 threads
    int v = (t < NB) ? bsum[t] : 0;
    int inc = v;
#pragma unroll
    for (int off = 1; off < 64; off <<= 1) {
        int u = __shfl_up(inc, off);
        if (t >= off) inc += u;
    }
    if (t < NB) bsum[t] = inc - v;          // exclusive
    if (t == 63) offs[N] = inc;             // total
}

__global__ void scan3_kernel(int* __restrict__ cnt, const int* __restrict__ bsum,
                             int* __restrict__ offs, int N) {
    int i = blockIdx.x * 256 + threadIdx.x;
    if (i < N) {
        int o = cnt[i] + bsum[blockIdx.x];
        offs[i] = o;
        cnt[i] = o;
    }
}

__global__ void scatter_kernel(const int* __restrict__ src, const int* __restrict__ dst,
                               int* __restrict__ cursor, int* __restrict__ csrc, int E) {
    int i = blockIdx.x * blockDim.x + threadIdx.x;
    if (i < E) {
        int d = dst[i];
        int pos = atomicAdd(&cursor[d], 1);
        csrc[pos] = src[i];
    }
}

// ---------------------------------------------------------------------------
// split fp32 -> bf16 hi + bf16 lo
// ---------------------------------------------------------------------------
__global__ void split_kernel(const float* __restrict__ in, unsigned short* __restrict__ hi,
                             unsigned short* __restrict__ lo, int len) {
    int i = blockIdx.x * blockDim.x + threadIdx.x;
    if (i >= len) return;
    float v = in[i];
    unsigned short h = f2bf(v);
    hi[i] = h;
    lo[i] = f2bf(v - bf2f(h));
}

// W [K,N] fp32  ->  WT_hi/lo [N,K] bf16 (transpose + split)
__global__ void wsplit_kernel(const float* __restrict__ W, unsigned short* __restrict__ hi,
                              unsigned short* __restrict__ lo, int K, int N) {
    int idx = blockIdx.x * blockDim.x + threadIdx.x;
    if (idx >= K * N) return;
    int n = idx / K, k = idx % K;
    float v = W[(size_t)k * N + n];
    unsigned short h = f2bf(v);
    hi[idx] = h;
    lo[idx] = f2bf(v - bf2f(h));
}

// ---------------------------------------------------------------------------
// MFMA GEMM (split-bf16, 3 passes), 128x128 tile (verified R5 structure).
// ---------------------------------------------------------------------------
__global__ __launch_bounds__(256) void mfma_gemm128_kernel(
    const unsigned short* __restrict__ Ahi, const unsigned short* __restrict__ Alo,
    const unsigned short* __restrict__ BThi, const unsigned short* __restrict__ BTlo,
    float* __restrict__ C, int M, int N, int K) {
    constexpr int BK = 32;
    __shared__ __align__(16) unsigned short sA[128 * BK];
    __shared__ __align__(16) unsigned short sB[128 * BK];
    int t = threadIdx.x;
    int w = t >> 6, lane = t & 63;
    int quad = lane >> 4, low = lane & 15;
    int m0 = blockIdx.y * 128, n0 = blockIdx.x * 128;
    int wm = (w & 1) * 64, wn = (w >> 1) * 64;

    f4_t acc[4][4];
#pragma unroll
    for (int i = 0; i < 4; i++)
#pragma unroll
        for (int j = 0; j < 4; j++) acc[i][j] = (f4_t){0.f, 0.f, 0.f, 0.f};

    int srow = lane >> 2;
    int schunk = lane & 3;

    const unsigned short* Ap[3] = {Ahi, Ahi, Alo};
    const unsigned short* Bp[3] = {BThi, BTlo, BThi};

    for (int pass = 0; pass < 3; pass++) {
        const unsigned short* A = Ap[pass];
        const unsigned short* B = Bp[pass];
        for (int k0 = 0; k0 < K; k0 += BK) {
            __syncthreads();
#pragma unroll
            for (int inst = 0; inst < 2; inst++) {
                int r = w * 32 + inst * 16 + srow;
                int gm = m0 + r;
                if (gm >= M) gm = M - 1;
                const void* g = (const void*)(A + (size_t)gm * K + k0 + schunk * 8);
                void* l = (void*)((char*)sA + (size_t)(w * 2048 + inst * 1024));
                __builtin_amdgcn_global_load_lds((const __attribute__((address_space(1))) void*)g,
                                                 (__attribute__((address_space(3))) void*)l, 16, 0, 0);
            }
#pragma unroll
            for (int inst = 0; inst < 2; inst++) {
                int r = w * 32 + inst * 16 + srow;
                int gn = n0 + r;
                const void* g = (const void*)(B + (size_t)gn * K + k0 + schunk * 8);
                void* l = (void*)((char*)sB + (size_t)(w * 2048 + inst * 1024));
                __builtin_amdgcn_global_load_lds((const __attribute__((address_space(1))) void*)g,
                                                 (__attribute__((address_space(3))) void*)l, 16, 0, 0);
            }
            __syncthreads();

            bf8_t af[4], bf[4];
#pragma unroll
            for (int i = 0; i < 4; i++) {
                int row = wm + i * 16 + low;
                af[i] = *(const bf8_t*)&sA[row * BK + quad * 8];
            }
#pragma unroll
            for (int j = 0; j < 4; j++) {
                int row = wn + j * 16 + low;
                bf[j] = *(const bf8_t*)&sB[row * BK + quad * 8];
            }
#pragma unroll
            for (int i = 0; i < 4; i++)
#pragma unroll
                for (int j = 0; j < 4; j++)
                    acc[i][j] = __builtin_amdgcn_mfma_f32_16x16x32_bf16(af[i], bf[j], acc[i][j], 0, 0, 0);
        }
    }

#pragma unroll
    for (int i = 0; i < 4; i++) {
#pragma unroll
        for (int r = 0; r < 4; r++) {
            int gm = m0 + wm + i * 16 + quad * 4 + r;
            if (gm >= M) continue;
#pragma unroll
            for (int j = 0; j < 4; j++) {
                int gn = n0 + wn + j * 16 + low;
                C[(size_t)gm * N + gn] = acc[i][j][r];
            }
        }
    }
}

// 64x128 tile variant: only for layer 3 (N=128 -> 157 blocks vs 79).
__global__ __launch_bounds__(256) void mfma_gemm64_kernel(
    const unsigned short* __restrict__ Ahi, const unsigned short* __restrict__ Alo,
    const unsigned short* __restrict__ BThi, const unsigned short* __restrict__ BTlo,
    float* __restrict__ C, int M, int N, int K) {
    constexpr int BK = 32;
    __shared__ __align__(16) unsigned short sA[64 * BK];
    __shared__ __align__(16) unsigned short sB[128 * BK];
    int t = threadIdx.x;
    int w = t >> 6, lane = t & 63;
    int quad = lane >> 4, low = lane & 15;
    int m0 = blockIdx.y * 64, n0 = blockIdx.x * 128;
    int wm = (w & 1) * 32, wn = (w >> 1) * 64;

    f4_t acc[2][4];
#pragma unroll
    for (int i = 0; i < 2; i++)
#pragma unroll
        for (int j = 0; j < 4; j++) acc[i][j] = (f4_t){0.f, 0.f, 0.f, 0.f};

    int srow = lane >> 2;
    int schunk = lane & 3;

    const unsigned short* Ap[3] = {Ahi, Ahi, Alo};
    const unsigned short* Bp[3] = {BThi, BTlo, BThi};

    for (int pass = 0; pass < 3; pass++) {
        const unsigned short* A = Ap[pass];
        const unsigned short* B = Bp[pass];
        for (int k0 = 0; k0 < K; k0 += BK) {
            __syncthreads();
            {
                int gm = m0 + w * 16 + srow;
                if (gm >= M) gm = M - 1;
                const void* g = (const void*)(A + (size_t)gm * K + k0 + schunk * 8);
                void* l = (void*)((char*)sA + (size_t)(w * 1024));
                __builtin_amdgcn_global_load_lds((const __attribute__((address_space(1))) void*)g,
                                                 (__attribute__((address_space(3))) void*)l, 16, 0, 0);
            }
#pragma unroll
            for (int inst = 0; inst < 2; inst++) {
                int gn = n0 + w * 32 + inst * 16 + srow;
                const void* g = (const void*)(B + (size_t)gn * K + k0 + schunk * 8);
                void* l = (void*)((char*)sB + (size_t)(w * 2048 + inst * 1024));
                __builtin_amdgcn_global_load_lds((const __attribute__((address_space(1))) void*)g,
                                                 (__attribute__((address_space(3))) void*)l, 16, 0, 0);
            }
            __syncthreads();

            bf8_t af[2], bf[4];
#pragma unroll
            for (int i = 0; i < 2; i++) {
                int row = wm + i * 16 + low;
                af[i] = *(const bf8_t*)&sA[row * BK + quad * 8];
            }
#pragma unroll
            for (int j = 0; j < 4; j++) {
                int row = wn + j * 16 + low;
                bf[j] = *(const bf8_t*)&sB[row * BK + quad * 8];
            }
#pragma unroll
            for (int i = 0; i < 2; i++)
#pragma unroll
                for (int j = 0; j < 4; j++)
                    acc[i][j] = __builtin_amdgcn_mfma_f32_16x16x32_bf16(af[i], bf[j], acc[i][j], 0, 0, 0);
        }
    }

#pragma unroll
    for (int i = 0; i < 2; i++) {
#pragma unroll
        for (int r = 0; r < 4; r++) {
            int gm = m0 + wm + i * 16 + quad * 4 + r;
            if (gm >= M) continue;
#pragma unroll
            for (int j = 0; j < 4; j++) {
                int gn = n0 + wn + j * 16 + low;
                C[(size_t)gm * N + gn] = acc[i][j][r];
            }
        }
    }
}

// ---------------------------------------------------------------------------
// attention logits
// ---------------------------------------------------------------------------
__global__ void al_h4_kernel(const float* __restrict__ h, const float* __restrict__ a_src,
                             const float* __restrict__ a_dst, float* __restrict__ als,
                             float* __restrict__ ald, int N) {
    int wave = threadIdx.x >> 6, lane = threadIdx.x & 63;
    int n = blockIdx.x * 4 + wave;
    if (n >= N) return;
    const float* row = h + (size_t)n * 512;
    float ps[4] = {0, 0, 0, 0}, pd[4] = {0, 0, 0, 0};
#pragma unroll
    for (int k = 0; k < 8; k++) {
        int f = k * 64 + lane;
        float v = row[f];
        ps[k >> 1] += v * a_src[f];
        pd[k >> 1] += v * a_dst[f];
    }
#pragma unroll
    for (int off = 32; off; off >>= 1) {
#pragma unroll
        for (int hd = 0; hd < 4; hd++) {
            ps[hd] += __shfl_down(ps[hd], off);
            pd[hd] += __shfl_down(pd[hd], off);
        }
    }
    if (lane == 0) {
#pragma unroll
        for (int hd = 0; hd < 4; hd++) {
            als[n * 4 + hd] = ps[hd];
            ald[n * 4 + hd] = pd[hd];
        }
    }
}

__global__ void al_h1_kernel(const float* __restrict__ h, const float* __restrict__ a_src,
                             const float* __restrict__ a_dst, float* __restrict__ als,
                             float* __restrict__ ald, int N) {
    int wave = threadIdx.x >> 6, lane = threadIdx.x & 63;
    int n = blockIdx.x * 4 + wave;
    if (n >= N) return;
    const float* row = h + (size_t)n * 128;
    float v0 = row[lane], v1 = row[lane + 64];
    float ps = v0 * a_src[lane] + v1 * a_src[lane + 64];
    float pd = v0 * a_dst[lane] + v1 * a_dst[lane + 64];
#pragma unroll
    for (int off = 32; off; off >>= 1) {
        ps += __shfl_down(ps, off);
        pd += __shfl_down(pd, off);
    }
    if (lane == 0) { als[n] = ps; ald[n] = pd; }
}

// ---------------------------------------------------------------------------
// FUSED stats+aggregate, head-split: one 64-thread block per (node, head).
// Inline softmax: gather als[src] (160KB L2-hot table), max/exp/denom in-block;
// p kept in LDS -- no pbuf global traffic, no stats dispatch.
// Aggregation: lanes 0-31 even edges, 32-63 odd, float4 features/lane.
// ---------------------------------------------------------------------------
template <bool DO_ELU>
__global__ __launch_bounds__(64) void gat_agg_h4_fused_kernel(
    const float* __restrict__ h, const float* __restrict__ als,
    const float* __restrict__ ald, const int* __restrict__ csrc,
    const int* __restrict__ offs, const float* __restrict__ bias,
    unsigned short* __restrict__ ohi, unsigned short* __restrict__ olo, int N) {
    int gid = blockIdx.x;
    int head = gid & 3;
    int n = gid >> 2;
    int lane = threadIdx.x;
    int half = lane >> 5;
    int fl = (lane & 31) * 4;
    int f0 = head * 128 + fl;

    float aldn = ald[n * 4 + head];
    float selfe = als[n * 4 + head] + aldn;
    selfe = selfe > 0.f ? selfe : LEAKY * selfe;

    __shared__ int sSrc[64];
    __shared__ float sP[64];
    int beg = offs[n], end = offs[n + 1];
    int deg = end - beg;

    f4_t acc = (f4_t){0.f, 0.f, 0.f, 0.f};
    float dpart = 0.f;
    float m = selfe;

    if (deg <= 64) {
        // single-chunk fast path: one gather, e kept in register
        int s = 0; float e = selfe;
        if (lane < deg) {
            s = csrc[beg + lane];
            e = als[s * 4 + head] + aldn;
            e = e > 0.f ? e : LEAKY * e;
            sSrc[lane] = s;
            m = e > m ? e : m;
        }
#pragma unroll
        for (int off = 1; off < 64; off <<= 1) m = fmaxf(m, __shfl_xor(m, off));
        if (lane < deg) {
            float p = __expf(e - m);
            sP[lane] = p;
            dpart = p;
        }
        __syncthreads();
        for (int c = half; c < deg; c += 2) {
            const float* srow = h + (size_t)sSrc[c] * 512;
            float p = sP[c];
            f4_t x = *(const f4_t*)(srow + f0);
            acc += p * x;
        }
    } else {
        // pass 1: max (streaming gather)
        for (int i = beg + lane; i < end; i += 64) {
            int s = csrc[i];
            float e = als[s * 4 + head] + aldn;
            e = e > 0.f ? e : LEAKY * e;
            m = e > m ? e : m;
        }
#pragma unroll
        for (int off = 1; off < 64; off <<= 1) m = fmaxf(m, __shfl_xor(m, off));
        // pass 2: chunked p + aggregate
        for (int base = beg; base < end; base += 64) {
            int len = min(64, end - base);
            __syncthreads();
            if (lane < len) {
                int s = csrc[base + lane];
                float e = als[s * 4 + head] + aldn;
                e = e > 0.f ? e : LEAKY * e;
                float p = __expf(e - m);
                sSrc[lane] = s;
                sP[lane] = p;
                dpart += p;
            }
            __syncthreads();
#pragma unroll 8
            for (int c = half; c < len; c += 2) {
                const float* srow = h + (size_t)sSrc[c] * 512;
                float p = sP[c];
                f4_t x = *(const f4_t*)(srow + f0);
                acc += p * x;
            }
        }
    }

    // self contribution (half 0 only), then combine halves + denom reduce
    float pself = __expf(selfe - m);
    if (half == 0) {
        f4_t x = *(const f4_t*)(h + (size_t)n * 512 + f0);
        acc += pself * x;
    }
#pragma unroll
    for (int j = 0; j < 4; j++) acc[j] += __shfl_xor(acc[j], 32);
#pragma unroll
    for (int off = 1; off < 64; off <<= 1) dpart += __shfl_xor(dpart, off);
    float r = 1.0f / (dpart + pself + EPS_DEN);

    f4_t b = *(const f4_t*)(bias + f0);
    us4_t hs, ls;
#pragma unroll
    for (int j = 0; j < 4; j++) {
        float o = acc[j] * r + b[j];
        if (DO_ELU) o = o > 0.f ? o : (__expf(o) - 1.0f);
        unsigned short hh = f2bf(o);
        hs[j] = hh;
        ls[j] = f2bf(o - bf2f(hh));
    }
    if (half == 0) {
        size_t idx = (size_t)n * 512 + f0;
        *(us4_t*)&ohi[idx] = hs;
        *(us4_t*)&olo[idx] = ls;
    }
}

// Layer-3: fused stats + aggregate + CLASSIFIER. One block per node.
__global__ __launch_bounds__(64) void gat_agg_h1_fused_kernel(
    const float* __restrict__ h, const float* __restrict__ als,
    const float* __restrict__ ald, const int* __restrict__ csrc,
    const int* __restrict__ offs, const float* __restrict__ bias,
    const float* __restrict__ Wc1, const float* __restrict__ bc1,
    const float* __restrict__ Wc2, const float* __restrict__ bc2,
    float* __restrict__ emb, float* __restrict__ outp, int N) {
    int n = blockIdx.x;
    int lane = threadIdx.x;
    int half = lane >> 5;
    int f0 = (lane & 31) * 4;

    float aldn = ald[n];
    float selfe = als[n] + aldn;
    selfe = selfe > 0.f ? selfe : LEAKY * selfe;

    __shared__ int sSrc[64];
    __shared__ float sP[64];
    __shared__ float semb[128];
    int beg = offs[n], end = offs[n + 1];
    int deg = end - beg;

    f4_t acc = (f4_t){0.f, 0.f, 0.f, 0.f};
    float dpart = 0.f;
    float m = selfe;

    if (deg <= 64) {
        int s = 0; float e = selfe;
        if (lane < deg) {
            s = csrc[beg + lane];
            e = als[s] + aldn;
            e = e > 0.f ? e : LEAKY * e;
            sSrc[lane] = s;
            m = e > m ? e : m;
        }
#pragma unroll
        for (int off = 1; off < 64; off <<= 1) m = fmaxf(m, __shfl_xor(m, off));
        if (lane < deg) {
            float p = __expf(e - m);
            sP[lane] = p;
            dpart = p;
        }
        __syncthreads();
        for (int c = half; c < deg; c += 2) {
            const float* srow = h + (size_t)sSrc[c] * 128;
            float p = sP[c];
            f4_t x = *(const f4_t*)(srow + f0);
            acc += p * x;
        }
    } else {
        for (int i = beg + lane; i < end; i += 64) {
            int s = csrc[i];
            float e = als[s] + aldn;
            e = e > 0.f ? e : LEAKY * e;
            m = e > m ? e : m;
        }
#pragma unroll
        for (int off = 1; off < 64; off <<= 1) m = fmaxf(m, __shfl_xor(m, off));
        for (int base = beg; base < end; base += 64) {
            int len = min(64, end - base);
            __syncthreads();
            if (lane < len) {
                int s = csrc[base + lane];
                float e = als[s] + aldn;
                e = e > 0.f ? e : LEAKY * e;
                float p = __expf(e - m);
                sSrc[lane] = s;
                sP[lane] = p;
                dpart += p;
            }
            __syncthreads();
#pragma unroll 8
            for (int c = half; c < len; c += 2) {
                const float* srow = h + (size_t)sSrc[c] * 128;
                float p = sP[c];
                f4_t x = *(const f4_t*)(srow + f0);
                acc += p * x;
            }
        }
    }

    float pself = __expf(selfe - m);
    if (half == 0) {
        f4_t x = *(const f4_t*)(h + (size_t)n * 128 + f0);
        acc += pself * x;
    }
#pragma unroll
    for (int j = 0; j < 4; j++) acc[j] += __shfl_xor(acc[j], 32);
#pragma unroll
    for (int off = 1; off < 64; off <<= 1) dpart += __shfl_xor(dpart, off);
    float r = 1.0f / (dpart + pself + EPS_DEN);

    __syncthreads();   // sP/sSrc done; about to reuse LDS phase
    if (half == 0) {
        f4_t b = *(const f4_t*)(bias + f0);
        f4_t o;
#pragma unroll
        for (int j = 0; j < 4; j++) o[j] = acc[j] * r + b[j];
        *(f4_t*)&semb[f0] = o;
        *(f4_t*)&emb[(size_t)n * 128 + f0] = o;
    }
    __syncthreads();

    // classifier: hidden[lane] = relu(bc1[lane] + sum_k semb[k]*Wc1[k*64+lane])
    float cacc = bc1[lane];
#pragma unroll 4
    for (int k = 0; k < 128; k++) cacc += semb[k] * Wc1[k * 64 + lane];
    cacc = fmaxf(cacc, 0.f);
    float o0 = cacc * Wc2[lane * 2 + 0];
    float o1 = cacc * Wc2[lane * 2 + 1];
#pragma unroll
    for (int off = 32; off; off >>= 1) {
        o0 += __shfl_down(o0, off);
        o1 += __shfl_down(o1, off);
    }
    if (lane == 0) {
        outp[n * 2 + 0] = o0 + bc2[0];
        outp[n * 2 + 1] = o1 + bc2[1];
    }
}

// ---------------------------------------------------------------------------
extern "C" void kernel_launch(void* const* d_in, const int* in_sizes, int n_in,
                              void* d_out, int out_size, void* d_ws, size_t ws_size,
                              hipStream_t stream) {
    const float* x      = (const float*)d_in[0];
    const int*   ei     = (const int*)d_in[1];
    const float* W1     = (const float*)d_in[2];
    const float* a1s    = (const float*)d_in[3];
    const float* a1d    = (const float*)d_in[4];
    const float* b1     = (const float*)d_in[5];
    const float* W2     = (const float*)d_in[6];
    const float* a2s    = (const float*)d_in[7];
    const float* a2d    = (const float*)d_in[8];
    const float* b2     = (const float*)d_in[9];
    const float* W3     = (const float*)d_in[10];
    const float* a3s    = (const float*)d_in[11];
    const float* a3d    = (const float*)d_in[12];
    const float* b3     = (const float*)d_in[13];
    const float* Wc1    = (const float*)d_in[14];
    const float* bc1    = (const float*)d_in[15];
    const float* Wc2    = (const float*)d_in[16];
    const float* bc2    = (const float*)d_in[17];

    const int N = in_sizes[0] / 256;       // 10000
    const int E = in_sizes[1] / 2;         // 320000
    const int F = 512;

    const int* src = ei;
    const int* dst = ei + E;

    auto align = [](size_t o) { return (o + 255) & ~(size_t)255; };
    size_t o = 0;
    size_t o_G     = o; o = align(o + (size_t)N * F * 4);        // GEMM output h (fp32)
    size_t o_ahi   = o; o = align(o + (size_t)N * F * 2);
    size_t o_alo   = o; o = align(o + (size_t)N * F * 2);
    size_t o_xhi   = o; o = align(o + (size_t)N * 256 * 2);
    size_t o_xlo   = o; o = align(o + (size_t)N * 256 * 2);
    size_t o_w1h   = o; o = align(o + (size_t)512 * 256 * 2);
    size_t o_w1l   = o; o = align(o + (size_t)512 * 256 * 2);
    size_t o_w2h   = o; o = align(o + (size_t)512 * 512 * 2);
    size_t o_w2l   = o; o = align(o + (size_t)512 * 512 * 2);
    size_t o_w3h   = o; o = align(o + (size_t)128 * 512 * 2);
    size_t o_w3l   = o; o = align(o + (size_t)128 * 512 * 2);
    size_t o_als   = o; o = align(o + (size_t)N * 4 * 4);
    size_t o_ald   = o; o = align(o + (size_t)N * 4 * 4);
    size_t o_cnt   = o; o = align(o + (size_t)N * 4);
    size_t o_off   = o; o = align(o + (size_t)(N + 1) * 4);
    size_t o_bsum  = o; o = align(o + (size_t)64 * 4);
    size_t o_csrc  = o; o = align(o + (size_t)E * 4);
    (void)ws_size;

    char* ws = (char*)d_ws;
    float* bufG  = (float*)(ws + o_G);
    unsigned short* act_hi = (unsigned short*)(ws + o_ahi);
    unsigned short* act_lo = (unsigned short*)(ws + o_alo);
    unsigned short* x_hi   = (unsigned short*)(ws + o_xhi);
    unsigned short* x_lo   = (unsigned short*)(ws + o_xlo);
    unsigned short* w1h = (unsigned short*)(ws + o_w1h);
    unsigned short* w1l = (unsigned short*)(ws + o_w1l);
    unsigned short* w2h = (unsigned short*)(ws + o_w2h);
    unsigned short* w2l = (unsigned short*)(ws + o_w2l);
    unsigned short* w3h = (unsigned short*)(ws + o_w3h);
    unsigned short* w3l = (unsigned short*)(ws + o_w3l);
    float* als  = (float*)(ws + o_als);
    float* ald  = (float*)(ws + o_ald);
    int*   cnt  = (int*)(ws + o_cnt);
    int*   offs = (int*)(ws + o_off);
    int*   bsum = (int*)(ws + o_bsum);
    int*   csrc = (int*)(ws + o_csrc);

    float* outp = (float*)d_out;                 // [N,2]
    float* emb  = (float*)d_out + (size_t)N * 2; // [N,128]

    // ---- CSR build ----
    hipMemsetAsync(cnt, 0, (size_t)N * 4, stream);
    int eb = (E + 255) / 256;
    int nbs = (N + 255) / 256;   // 40
    hipLaunchKernelGGL(hist_kernel, dim3(eb), dim3(256), 0, stream, dst, cnt, E);
    hipLaunchKernelGGL(scan1_kernel, dim3(nbs), dim3(256), 0, stream, cnt, bsum, N);
    hipLaunchKernelGGL(scan2_kernel, dim3(1), dim3(64), 0, stream, bsum, offs, nbs, N);
    hipLaunchKernelGGL(scan3_kernel, dim3(nbs), dim3(256), 0, stream, cnt, bsum, offs, N);
    hipLaunchKernelGGL(scatter_kernel, dim3(eb), dim3(256), 0, stream, src, dst, cnt, csrc, E);

    // ---- splits ----
    hipLaunchKernelGGL(split_kernel, dim3((N * 256 + 255) / 256), dim3(256), 0, stream,
                       x, x_hi, x_lo, N * 256);
    hipLaunchKernelGGL(wsplit_kernel, dim3((256 * 512 + 255) / 256), dim3(256), 0, stream,
                       W1, w1h, w1l, 256, 512);
    hipLaunchKernelGGL(wsplit_kernel, dim3((512 * 512 + 255) / 256), dim3(256), 0, stream,
                       W2, w2h, w2l, 512, 512);
    hipLaunchKernelGGL(wsplit_kernel, dim3((512 * 128 + 255) / 256), dim3(256), 0, stream,
                       W3, w3h, w3l, 512, 128);

    int nb4 = (N + 3) / 4;
    int gy128 = (N + 127) / 128;  // 79
    int gy64  = (N + 63) / 64;    // 157

    // ---- layer 1 ----
    hipLaunchKernelGGL(mfma_gemm128_kernel, dim3(512 / 128, gy128), dim3(256), 0, stream,
                       x_hi, x_lo, w1h, w1l, bufG, N, 512, 256);
    hipLaunchKernelGGL(al_h4_kernel, dim3(nb4), dim3(256), 0, stream, bufG, a1s, a1d, als, ald, N);
    hipLaunchKernelGGL((gat_agg_h4_fused_kernel<true>), dim3(N * 4), dim3(64), 0, stream,
                       bufG, als, ald, csrc, offs, b1, act_hi, act_lo, N);

    // ---- layer 2 ----
    hipLaunchKernelGGL(mfma_gemm128_kernel, dim3(512 / 128, gy128), dim3(256), 0, stream,
                       act_hi, act_lo, w2h, w2l, bufG, N, 512, 512);
    hipLaunchKernelGGL(al_h4_kernel, dim3(nb4), dim3(256), 0, stream, bufG, a2s, a2d, als, ald, N);
    hipLaunchKernelGGL((gat_agg_h4_fused_kernel<true>), dim3(N * 4), dim3(64), 0, stream,
                       bufG, als, ald, csrc, offs, b2, act_hi, act_lo, N);

    // ---- layer 3 + classifier ----
    hipLaunchKernelGGL(mfma_gemm64_kernel, dim3(128 / 128, gy64), dim3(256), 0, stream,
                       act_hi, act_lo, w3h, w3l, bufG, N, 128, 512);
    hipLaunchKernelGGL(al_h1_kernel, dim3(nb4), dim3(256), 0, stream, bufG, a3s, a3d, als, ald, N);
    hipLaunchKernelGGL(gat_agg_h1_fused_kernel, dim3(N), dim3(64), 0, stream,
                       bufG, als, ald, csrc, offs, b3, Wc1, bc1, Wc2, bc2, emb, outp, N);
}

// Round 8
// 391.661 us; speedup vs baseline: 1.3646x; 1.0119x over previous
//
#include <hip/hip_runtime.h>
#include <cstddef>

#define LEAKY 0.2f
#define EPS_DEN 1e-16f

typedef short bf8_t __attribute__((ext_vector_type(8)));   // 8 bf16 in 4 VGPRs
typedef float f4_t __attribute__((ext_vector_type(4)));
typedef unsigned short us4_t __attribute__((ext_vector_type(4)));

__device__ __forceinline__ unsigned short f2bf(float f) {   // RNE
    unsigned u = __float_as_uint(f);
    unsigned r = (u + 0x7fffu + ((u >> 16) & 1u)) >> 16;
    return (unsigned short)r;
}
__device__ __forceinline__ float bf2f(unsigned short h) {
    return __uint_as_float(((unsigned)h) << 16);
}

// ---------------------------------------------------------------------------
// CSR build: histogram -> 3-phase parallel scan -> scatter
// ---------------------------------------------------------------------------
__global__ void hist_kernel(const int* __restrict__ dst, int* __restrict__ counts, int E) {
    int i = blockIdx.x * blockDim.x + threadIdx.x;
    if (i < E) atomicAdd(&counts[dst[i]], 1);
}

__global__ void scan1_kernel(int* __restrict__ cnt, int* __restrict__ bsum, int N) {
    __shared__ int s[256];
    int t = threadIdx.x;
    int i = blockIdx.x * 256 + t;
    int v = (i < N) ? cnt[i] : 0;
    s[t] = v;
    __syncthreads();
#pragma unroll
    for (int st = 1; st < 256; st <<= 1) {
        int add = (t >= st) ? s[t - st] : 0;
        __syncthreads();
        s[t] += add;
        __syncthreads();
    }
    if (i < N) cnt[i] = s[t] - v;           // exclusive within block
    if (t == 255) bsum[blockIdx.x] = s[255];
}

__global__ void scan2_kernel(int* __restrict__ bsum, int* __restrict__ offs, int NB, int N) {
    int t = threadIdx.x;   // 64 threads
    int v = (t < NB) ? bsum[t] : 0;
    int inc = v;
#pragma unroll
    for (int off = 1; off < 64; off <<= 1) {
        int u = __shfl_up(inc, off);
        if (t >= off) inc += u;
    }
    if (t < NB) bsum[t] = inc - v;          // exclusive
    if (t == 63) offs[N] = inc;             // total
}

__global__ void scan3_kernel(int* __restrict__ cnt, const int* __restrict__ bsum,
                             int* __restrict__ offs, int N) {
    int i = blockIdx.x * 256 + threadIdx.x;
    if (i < N) {
        int o = cnt[i] + bsum[blockIdx.x];
        offs[i] = o;
        cnt[i] = o;
    }
}

__global__ void scatter_kernel(const int* __restrict__ src, const int* __restrict__ dst,
                               int* __restrict__ cursor, int* __restrict__ csrc, int E) {
    int i = blockIdx.x * blockDim.x + threadIdx.x;
    if (i < E) {
        int d = dst[i];
        int pos = atomicAdd(&cursor[d], 1);
        csrc[pos] = src[i];
    }
}

// ---------------------------------------------------------------------------
// split fp32 -> bf16 hi + bf16 lo
// ---------------------------------------------------------------------------
__global__ void split_kernel(const float* __restrict__ in, unsigned short* __restrict__ hi,
                             unsigned short* __restrict__ lo, int len) {
    int i = blockIdx.x * blockDim.x + threadIdx.x;
    if (i >= len) return;
    float v = in[i];
    unsigned short h = f2bf(v);
    hi[i] = h;
    lo[i] = f2bf(v - bf2f(h));
}

// W [K,N] fp32  ->  WT_hi/lo [N,K] bf16 (transpose + split)
__global__ void wsplit_kernel(const float* __restrict__ W, unsigned short* __restrict__ hi,
                              unsigned short* __restrict__ lo, int K, int N) {
    int idx = blockIdx.x * blockDim.x + threadIdx.x;
    if (idx >= K * N) return;
    int n = idx / K, k = idx % K;
    float v = W[(size_t)k * N + n];
    unsigned short h = f2bf(v);
    hi[idx] = h;
    lo[idx] = f2bf(v - bf2f(h));
}

// ---------------------------------------------------------------------------
// MFMA GEMM (split-bf16, 3 passes), 128x128 tile (verified structure).
// ---------------------------------------------------------------------------
__global__ __launch_bounds__(256) void mfma_gemm128_kernel(
    const unsigned short* __restrict__ Ahi, const unsigned short* __restrict__ Alo,
    const unsigned short* __restrict__ BThi, const unsigned short* __restrict__ BTlo,
    float* __restrict__ C, int M, int N, int K) {
    constexpr int BK = 32;
    __shared__ __align__(16) unsigned short sA[128 * BK];
    __shared__ __align__(16) unsigned short sB[128 * BK];
    int t = threadIdx.x;
    int w = t >> 6, lane = t & 63;
    int quad = lane >> 4, low = lane & 15;
    int m0 = blockIdx.y * 128, n0 = blockIdx.x * 128;
    int wm = (w & 1) * 64, wn = (w >> 1) * 64;

    f4_t acc[4][4];
#pragma unroll
    for (int i = 0; i < 4; i++)
#pragma unroll
        for (int j = 0; j < 4; j++) acc[i][j] = (f4_t){0.f, 0.f, 0.f, 0.f};

    int srow = lane >> 2;
    int schunk = lane & 3;

    const unsigned short* Ap[3] = {Ahi, Ahi, Alo};
    const unsigned short* Bp[3] = {BThi, BTlo, BThi};

    for (int pass = 0; pass < 3; pass++) {
        const unsigned short* A = Ap[pass];
        const unsigned short* B = Bp[pass];
        for (int k0 = 0; k0 < K; k0 += BK) {
            __syncthreads();
#pragma unroll
            for (int inst = 0; inst < 2; inst++) {
                int r = w * 32 + inst * 16 + srow;
                int gm = m0 + r;
                if (gm >= M) gm = M - 1;
                const void* g = (const void*)(A + (size_t)gm * K + k0 + schunk * 8);
                void* l = (void*)((char*)sA + (size_t)(w * 2048 + inst * 1024));
                __builtin_amdgcn_global_load_lds((const __attribute__((address_space(1))) void*)g,
                                                 (__attribute__((address_space(3))) void*)l, 16, 0, 0);
            }
#pragma unroll
            for (int inst = 0; inst < 2; inst++) {
                int r = w * 32 + inst * 16 + srow;
                int gn = n0 + r;
                const void* g = (const void*)(B + (size_t)gn * K + k0 + schunk * 8);
                void* l = (void*)((char*)sB + (size_t)(w * 2048 + inst * 1024));
                __builtin_amdgcn_global_load_lds((const __attribute__((address_space(1))) void*)g,
                                                 (__attribute__((address_space(3))) void*)l, 16, 0, 0);
            }
            __syncthreads();

            bf8_t af[4], bf[4];
#pragma unroll
            for (int i = 0; i < 4; i++) {
                int row = wm + i * 16 + low;
                af[i] = *(const bf8_t*)&sA[row * BK + quad * 8];
            }
#pragma unroll
            for (int j = 0; j < 4; j++) {
                int row = wn + j * 16 + low;
                bf[j] = *(const bf8_t*)&sB[row * BK + quad * 8];
            }
#pragma unroll
            for (int i = 0; i < 4; i++)
#pragma unroll
                for (int j = 0; j < 4; j++)
                    acc[i][j] = __builtin_amdgcn_mfma_f32_16x16x32_bf16(af[i], bf[j], acc[i][j], 0, 0, 0);
        }
    }

#pragma unroll
    for (int i = 0; i < 4; i++) {
#pragma unroll
        for (int r = 0; r < 4; r++) {
            int gm = m0 + wm + i * 16 + quad * 4 + r;
            if (gm >= M) continue;
#pragma unroll
            for (int j = 0; j < 4; j++) {
                int gn = n0 + wn + j * 16 + low;
                C[(size_t)gm * N + gn] = acc[i][j][r];
            }
        }
    }
}

// 64x128 tile variant: only for layer 3 (N=128 -> 157 blocks vs 79).
__global__ __launch_bounds__(256) void mfma_gemm64_kernel(
    const unsigned short* __restrict__ Ahi, const unsigned short* __restrict__ Alo,
    const unsigned short* __restrict__ BThi, const unsigned short* __restrict__ BTlo,
    float* __restrict__ C, int M, int N, int K) {
    constexpr int BK = 32;
    __shared__ __align__(16) unsigned short sA[64 * BK];
    __shared__ __align__(16) unsigned short sB[128 * BK];
    int t = threadIdx.x;
    int w = t >> 6, lane = t & 63;
    int quad = lane >> 4, low = lane & 15;
    int m0 = blockIdx.y * 64, n0 = blockIdx.x * 128;
    int wm = (w & 1) * 32, wn = (w >> 1) * 64;

    f4_t acc[2][4];
#pragma unroll
    for (int i = 0; i < 2; i++)
#pragma unroll
        for (int j = 0; j < 4; j++) acc[i][j] = (f4_t){0.f, 0.f, 0.f, 0.f};

    int srow = lane >> 2;
    int schunk = lane & 3;

    const unsigned short* Ap[3] = {Ahi, Ahi, Alo};
    const unsigned short* Bp[3] = {BThi, BTlo, BThi};

    for (int pass = 0; pass < 3; pass++) {
        const unsigned short* A = Ap[pass];
        const unsigned short* B = Bp[pass];
        for (int k0 = 0; k0 < K; k0 += BK) {
            __syncthreads();
            {
                int gm = m0 + w * 16 + srow;
                if (gm >= M) gm = M - 1;
                const void* g = (const void*)(A + (size_t)gm * K + k0 + schunk * 8);
                void* l = (void*)((char*)sA + (size_t)(w * 1024));
                __builtin_amdgcn_global_load_lds((const __attribute__((address_space(1))) void*)g,
                                                 (__attribute__((address_space(3))) void*)l, 16, 0, 0);
            }
#pragma unroll
            for (int inst = 0; inst < 2; inst++) {
                int gn = n0 + w * 32 + inst * 16 + srow;
                const void* g = (const void*)(B + (size_t)gn * K + k0 + schunk * 8);
                void* l = (void*)((char*)sB + (size_t)(w * 2048 + inst * 1024));
                __builtin_amdgcn_global_load_lds((const __attribute__((address_space(1))) void*)g,
                                                 (__attribute__((address_space(3))) void*)l, 16, 0, 0);
            }
            __syncthreads();

            bf8_t af[2], bf[4];
#pragma unroll
            for (int i = 0; i < 2; i++) {
                int row = wm + i * 16 + low;
                af[i] = *(const bf8_t*)&sA[row * BK + quad * 8];
            }
#pragma unroll
            for (int j = 0; j < 4; j++) {
                int row = wn + j * 16 + low;
                bf[j] = *(const bf8_t*)&sB[row * BK + quad * 8];
            }
#pragma unroll
            for (int i = 0; i < 2; i++)
#pragma unroll
                for (int j = 0; j < 4; j++)
                    acc[i][j] = __builtin_amdgcn_mfma_f32_16x16x32_bf16(af[i], bf[j], acc[i][j], 0, 0, 0);
        }
    }

#pragma unroll
    for (int i = 0; i < 2; i++) {
#pragma unroll
        for (int r = 0; r < 4; r++) {
            int gm = m0 + wm + i * 16 + quad * 4 + r;
            if (gm >= M) continue;
#pragma unroll
            for (int j = 0; j < 4; j++) {
                int gn = n0 + wn + j * 16 + low;
                C[(size_t)gm * N + gn] = acc[i][j][r];
            }
        }
    }
}

// ---------------------------------------------------------------------------
// attention logits
// ---------------------------------------------------------------------------
__global__ void al_h4_kernel(const float* __restrict__ h, const float* __restrict__ a_src,
                             const float* __restrict__ a_dst, float* __restrict__ als,
                             float* __restrict__ ald, int N) {
    int wave = threadIdx.x >> 6, lane = threadIdx.x & 63;
    int n = blockIdx.x * 4 + wave;
    if (n >= N) return;
    const float* row = h + (size_t)n * 512;
    float ps[4] = {0, 0, 0, 0}, pd[4] = {0, 0, 0, 0};
#pragma unroll
    for (int k = 0; k < 8; k++) {
        int f = k * 64 + lane;
        float v = row[f];
        ps[k >> 1] += v * a_src[f];
        pd[k >> 1] += v * a_dst[f];
    }
#pragma unroll
    for (int off = 32; off; off >>= 1) {
#pragma unroll
        for (int hd = 0; hd < 4; hd++) {
            ps[hd] += __shfl_down(ps[hd], off);
            pd[hd] += __shfl_down(pd[hd], off);
        }
    }
    if (lane == 0) {
#pragma unroll
        for (int hd = 0; hd < 4; hd++) {
            als[n * 4 + hd] = ps[hd];
            ald[n * 4 + hd] = pd[hd];
        }
    }
}

__global__ void al_h1_kernel(const float* __restrict__ h, const float* __restrict__ a_src,
                             const float* __restrict__ a_dst, float* __restrict__ als,
                             float* __restrict__ ald, int N) {
    int wave = threadIdx.x >> 6, lane = threadIdx.x & 63;
    int n = blockIdx.x * 4 + wave;
    if (n >= N) return;
    const float* row = h + (size_t)n * 128;
    float v0 = row[lane], v1 = row[lane + 64];
    float ps = v0 * a_src[lane] + v1 * a_src[lane + 64];
    float pd = v0 * a_dst[lane] + v1 * a_dst[lane + 64];
#pragma unroll
    for (int off = 32; off; off >>= 1) {
        ps += __shfl_down(ps, off);
        pd += __shfl_down(pd, off);
    }
    if (lane == 0) { als[n] = ps; ald[n] = pd; }
}

// ---------------------------------------------------------------------------
// Softmax stats per dst node -> UNNORMALIZED p = exp(e-max) in head-major
// pbuf[hd*E+slot]; psf = unnorm self weight; rden = 1/(sum+eps).
// Coalesced: lane = edge_slot*4 + head -> 16B/edge als gathers.
// ---------------------------------------------------------------------------
__global__ void stats_h4_kernel(const int* __restrict__ csrc, const int* __restrict__ offs,
                                const float* __restrict__ als, const float* __restrict__ ald,
                                float* __restrict__ pbuf, float* __restrict__ psf,
                                float* __restrict__ rden, int N, int E) {
    int wave = threadIdx.x >> 6, lane = threadIdx.x & 63;
    int n = blockIdx.x * 4 + wave;
    if (n >= N) return;
    int hd = lane & 3, es = lane >> 2;   // head, edge slot 0..15
    float aldn = ald[n * 4 + hd];
    float selfe = als[n * 4 + hd] + aldn;
    selfe = selfe > 0.f ? selfe : LEAKY * selfe;
    int beg = offs[n], end = offs[n + 1];
    float* pb = pbuf + (size_t)hd * E;
    float m = selfe;
    for (int base = beg; base + es < end; base += 16) {
        int idx = base + es;
        int s = csrc[idx];
        float e = als[s * 4 + hd] + aldn;
        e = e > 0.f ? e : LEAKY * e;
        pb[idx] = e;
        m = fmaxf(m, e);
    }
#pragma unroll
    for (int off = 4; off < 64; off <<= 1) m = fmaxf(m, __shfl_xor(m, off));
    float d = 0.f;
    for (int base = beg; base + es < end; base += 16) {
        int idx = base + es;
        float p = __expf(pb[idx] - m);
        pb[idx] = p;
        d += p;
    }
#pragma unroll
    for (int off = 4; off < 64; off <<= 1) d += __shfl_xor(d, off);
    float pself = __expf(selfe - m);
    float r = 1.0f / (d + pself + EPS_DEN);
    if (es == 0) {
        psf[n * 4 + hd] = pself;
        rden[n * 4 + hd] = r;
    }
}

__global__ void stats_h1_kernel(const int* __restrict__ csrc, const int* __restrict__ offs,
                                const float* __restrict__ als, const float* __restrict__ ald,
                                float* __restrict__ pbuf, float* __restrict__ psf,
                                float* __restrict__ rden, int N) {
    int wave = threadIdx.x >> 6, lane = threadIdx.x & 63;
    int n = blockIdx.x * 4 + wave;
    if (n >= N) return;
    float aldn = ald[n];
    float selfe = als[n] + aldn;
    selfe = selfe > 0.f ? selfe : LEAKY * selfe;
    int beg = offs[n], end = offs[n + 1];
    float m = selfe;
    for (int base = beg; base + lane < end; base += 64) {
        int idx = base + lane;
        int s = csrc[idx];
        float e = als[s] + aldn;
        e = e > 0.f ? e : LEAKY * e;
        pbuf[idx] = e;
        m = fmaxf(m, e);
    }
#pragma unroll
    for (int off = 1; off < 64; off <<= 1) m = fmaxf(m, __shfl_xor(m, off));
    float d = 0.f;
    for (int base = beg; base + lane < end; base += 64) {
        int idx = base + lane;
        float p = __expf(pbuf[idx] - m);
        pbuf[idx] = p;
        d += p;
    }
#pragma unroll
    for (int off = 1; off < 64; off <<= 1) d += __shfl_xor(d, off);
    float pself = __expf(selfe - m);
    float r = 1.0f / (d + pself + EPS_DEN);
    if (lane == 0) { psf[n] = pself; rden[n] = r; }
}

// ---------------------------------------------------------------------------
// HALF-HEAD aggregate: one 64-thread block per (node, half-head).
// hh = blockIdx&7 -> each XCD (round-robin %8) works one 2.6MB slice (fits L2).
// 16 lanes x float4 per edge, 4 edges in flight; shfl_xor(16/32) combine.
// Weights prenormalized upstream is NOT needed: p unnorm, *rden at end.
// ---------------------------------------------------------------------------
template <bool DO_ELU>
__global__ __launch_bounds__(64) void gat_agg_hh_kernel(
    const float* __restrict__ h, const float* __restrict__ pbuf,
    const float* __restrict__ psf, const float* __restrict__ rden,
    const int* __restrict__ csrc, const int* __restrict__ offs,
    const float* __restrict__ bias, unsigned short* __restrict__ ohi,
    unsigned short* __restrict__ olo, int N, int E) {
    int gid = blockIdx.x;
    int hh = gid & 7;           // half-head 0..7
    int n = gid >> 3;
    int head = hh >> 1;
    int lane = threadIdx.x;
    int eg = lane >> 4;         // edge group 0..3
    int f0 = hh * 64 + (lane & 15) * 4;
    const float* pb = pbuf + (size_t)head * E;

    f4_t acc = (f4_t){0.f, 0.f, 0.f, 0.f};
    __shared__ int sSrc[64];
    __shared__ float sP[64];
    int beg = offs[n], end = offs[n + 1];
    for (int base = beg; base < end; base += 64) {
        int len = min(64, end - base);
        __syncthreads();
        if (lane < len) {
            sSrc[lane] = csrc[base + lane];
            sP[lane] = pb[base + lane];
        }
        __syncthreads();
#pragma unroll 8
        for (int c = eg; c < len; c += 4) {
            const float* srow = h + (size_t)sSrc[c] * 512;
            f4_t x = *(const f4_t*)(srow + f0);
            acc += sP[c] * x;
        }
    }
    if (eg == 0) {
        f4_t x = *(const f4_t*)(h + (size_t)n * 512 + f0);
        acc += psf[n * 4 + head] * x;
    }
#pragma unroll
    for (int j = 0; j < 4; j++) {
        acc[j] += __shfl_xor(acc[j], 16);
        acc[j] += __shfl_xor(acc[j], 32);
    }
    if (lane < 16) {
        float r = rden[n * 4 + head];
        f4_t b = *(const f4_t*)(bias + f0);
        us4_t hs, ls;
#pragma unroll
        for (int j = 0; j < 4; j++) {
            float o = acc[j] * r + b[j];
            if (DO_ELU) o = o > 0.f ? o : (__expf(o) - 1.0f);
            unsigned short hhh = f2bf(o);
            hs[j] = hhh;
            ls[j] = f2bf(o - bf2f(hhh));
        }
        size_t idx = (size_t)n * 512 + f0;
        *(us4_t*)&ohi[idx] = hs;
        *(us4_t*)&olo[idx] = ls;
    }
}

// Layer-3: aggregate (pbuf inputs) + classifier fused. One block per node.
__global__ __launch_bounds__(64) void gat_agg_h1_cls_kernel(
    const float* __restrict__ h, const float* __restrict__ pbuf,
    const float* __restrict__ psf, const float* __restrict__ rden,
    const int* __restrict__ csrc, const int* __restrict__ offs,
    const float* __restrict__ bias, const float* __restrict__ Wc1,
    const float* __restrict__ bc1, const float* __restrict__ Wc2,
    const float* __restrict__ bc2, float* __restrict__ emb,
    float* __restrict__ outp, int N) {
    int n = blockIdx.x;
    int lane = threadIdx.x;
    int half = lane >> 5;
    int f0 = (lane & 31) * 4;

    f4_t acc = (f4_t){0.f, 0.f, 0.f, 0.f};
    __shared__ int sSrc[64];
    __shared__ float sP[64];
    __shared__ float semb[128];
    int beg = offs[n], end = offs[n + 1];
    for (int base = beg; base < end; base += 64) {
        int len = min(64, end - base);
        __syncthreads();
        if (lane < len) {
            sSrc[lane] = csrc[base + lane];
            sP[lane] = pbuf[base + lane];
        }
        __syncthreads();
#pragma unroll 8
        for (int c = half; c < len; c += 2) {
            const float* srow = h + (size_t)sSrc[c] * 128;
            f4_t x = *(const f4_t*)(srow + f0);
            acc += sP[c] * x;
        }
    }
    if (half == 0) {
        f4_t x = *(const f4_t*)(h + (size_t)n * 128 + f0);
        acc += psf[n] * x;
    }
#pragma unroll
    for (int j = 0; j < 4; j++) acc[j] += __shfl_xor(acc[j], 32);

    __syncthreads();
    if (half == 0) {
        float r = rden[n];
        f4_t b = *(const f4_t*)(bias + f0);
        f4_t o;
#pragma unroll
        for (int j = 0; j < 4; j++) o[j] = acc[j] * r + b[j];
        *(f4_t*)&semb[f0] = o;
        *(f4_t*)&emb[(size_t)n * 128 + f0] = o;
    }
    __syncthreads();

    // classifier: hidden[lane] = relu(bc1[lane] + sum_k semb[k]*Wc1[k*64+lane])
    float cacc = bc1[lane];
#pragma unroll 4
    for (int k = 0; k < 128; k++) cacc += semb[k] * Wc1[k * 64 + lane];
    cacc = fmaxf(cacc, 0.f);
    float o0 = cacc * Wc2[lane * 2 + 0];
    float o1 = cacc * Wc2[lane * 2 + 1];
#pragma unroll
    for (int off = 32; off; off >>= 1) {
        o0 += __shfl_down(o0, off);
        o1 += __shfl_down(o1, off);
    }
    if (lane == 0) {
        outp[n * 2 + 0] = o0 + bc2[0];
        outp[n * 2 + 1] = o1 + bc2[1];
    }
}

// ---------------------------------------------------------------------------
extern "C" void kernel_launch(void* const* d_in, const int* in_sizes, int n_in,
                              void* d_out, int out_size, void* d_ws, size_t ws_size,
                              hipStream_t stream) {
    const float* x      = (const float*)d_in[0];
    const int*   ei     = (const int*)d_in[1];
    const float* W1     = (const float*)d_in[2];
    const float* a1s    = (const float*)d_in[3];
    const float* a1d    = (const float*)d_in[4];
    const float* b1     = (const float*)d_in[5];
    const float* W2     = (const float*)d_in[6];
    const float* a2s    = (const float*)d_in[7];
    const float* a2d    = (const float*)d_in[8];
    const float* b2     = (const float*)d_in[9];
    const float* W3     = (const float*)d_in[10];
    const float* a3s    = (const float*)d_in[11];
    const float* a3d    = (const float*)d_in[12];
    const float* b3     = (const float*)d_in[13];
    const float* Wc1    = (const float*)d_in[14];
    const float* bc1    = (const float*)d_in[15];
    const float* Wc2    = (const float*)d_in[16];
    const float* bc2    = (const float*)d_in[17];

    const int N = in_sizes[0] / 256;       // 10000
    const int E = in_sizes[1] / 2;         // 320000
    const int F = 512;

    const int* src = ei;
    const int* dst = ei + E;

    auto align = [](size_t o) { return (o + 255) & ~(size_t)255; };
    size_t o = 0;
    size_t o_G     = o; o = align(o + (size_t)N * F * 4);        // GEMM output h (fp32)
    size_t o_ahi   = o; o = align(o + (size_t)N * F * 2);
    size_t o_alo   = o; o = align(o + (size_t)N * F * 2);
    size_t o_xhi   = o; o = align(o + (size_t)N * 256 * 2);
    size_t o_xlo   = o; o = align(o + (size_t)N * 256 * 2);
    size_t o_w1h   = o; o = align(o + (size_t)512 * 256 * 2);
    size_t o_w1l   = o; o = align(o + (size_t)512 * 256 * 2);
    size_t o_w2h   = o; o = align(o + (size_t)512 * 512 * 2);
    size_t o_w2l   = o; o = align(o + (size_t)512 * 512 * 2);
    size_t o_w3h   = o; o = align(o + (size_t)128 * 512 * 2);
    size_t o_w3l   = o; o = align(o + (size_t)128 * 512 * 2);
    size_t o_als   = o; o = align(o + (size_t)N * 4 * 4);
    size_t o_ald   = o; o = align(o + (size_t)N * 4 * 4);
    size_t o_psf   = o; o = align(o + (size_t)N * 4 * 4);
    size_t o_rden  = o; o = align(o + (size_t)N * 4 * 4);
    size_t o_cnt   = o; o = align(o + (size_t)N * 4);
    size_t o_off   = o; o = align(o + (size_t)(N + 1) * 4);
    size_t o_bsum  = o; o = align(o + (size_t)64 * 4);
    size_t o_csrc  = o; o = align(o + (size_t)E * 4);
    size_t o_ebuf  = o; o = align(o + (size_t)E * 4 * 4);
    (void)ws_size;

    char* ws = (char*)d_ws;
    float* bufG  = (float*)(ws + o_G);
    unsigned short* act_hi = (unsigned short*)(ws + o_ahi);
    unsigned short* act_lo = (unsigned short*)(ws + o_alo);
    unsigned short* x_hi   = (unsigned short*)(ws + o_xhi);
    unsigned short* x_lo   = (unsigned short*)(ws + o_xlo);
    unsigned short* w1h = (unsigned short*)(ws + o_w1h);
    unsigned short* w1l = (unsigned short*)(ws + o_w1l);
    unsigned short* w2h = (unsigned short*)(ws + o_w2h);
    unsigned short* w2l = (unsigned short*)(ws + o_w2l);
    unsigned short* w3h = (unsigned short*)(ws + o_w3h);
    unsigned short* w3l = (unsigned short*)(ws + o_w3l);
    float* als  = (float*)(ws + o_als);
    float* ald  = (float*)(ws + o_ald);
    float* psf  = (float*)(ws + o_psf);
    float* rden = (float*)(ws + o_rden);
    int*   cnt  = (int*)(ws + o_cnt);
    int*   offs = (int*)(ws + o_off);
    int*   bsum = (int*)(ws + o_bsum);
    int*   csrc = (int*)(ws + o_csrc);
    float* ebuf = (float*)(ws + o_ebuf);

    float* outp = (float*)d_out;                 // [N,2]
    float* emb  = (float*)d_out + (size_t)N * 2; // [N,128]

    // ---- CSR build ----
    hipMemsetAsync(cnt, 0, (size_t)N * 4, stream);
    int eb = (E + 255) / 256;
    int nbs = (N + 255) / 256;   // 40
    hipLaunchKernelGGL(hist_kernel, dim3(eb), dim3(256), 0, stream, dst, cnt, E);
    hipLaunchKernelGGL(scan1_kernel, dim3(nbs), dim3(256), 0, stream, cnt, bsum, N);
    hipLaunchKernelGGL(scan2_kernel, dim3(1), dim3(64), 0, stream, bsum, offs, nbs, N);
    hipLaunchKernelGGL(scan3_kernel, dim3(nbs), dim3(256), 0, stream, cnt, bsum, offs, N);
    hipLaunchKernelGGL(scatter_kernel, dim3(eb), dim3(256), 0, stream, src, dst, cnt, csrc, E);

    // ---- splits ----
    hipLaunchKernelGGL(split_kernel, dim3((N * 256 + 255) / 256), dim3(256), 0, stream,
                       x, x_hi, x_lo, N * 256);
    hipLaunchKernelGGL(wsplit_kernel, dim3((256 * 512 + 255) / 256), dim3(256), 0, stream,
                       W1, w1h, w1l, 256, 512);
    hipLaunchKernelGGL(wsplit_kernel, dim3((512 * 512 + 255) / 256), dim3(256), 0, stream,
                       W2, w2h, w2l, 512, 512);
    hipLaunchKernelGGL(wsplit_kernel, dim3((512 * 128 + 255) / 256), dim3(256), 0, stream,
                       W3, w3h, w3l, 512, 128);

    int nb4 = (N + 3) / 4;
    int gy128 = (N + 127) / 128;  // 79
    int gy64  = (N + 63) / 64;    // 157

    // ---- layer 1 ----
    hipLaunchKernelGGL(mfma_gemm128_kernel, dim3(512 / 128, gy128), dim3(256), 0, stream,
                       x_hi, x_lo, w1h, w1l, bufG, N, 512, 256);
    hipLaunchKernelGGL(al_h4_kernel, dim3(nb4), dim3(256), 0, stream, bufG, a1s, a1d, als, ald, N);
    hipLaunchKernelGGL(stats_h4_kernel, dim3(nb4), dim3(256), 0, stream,
                       csrc, offs, als, ald, ebuf, psf, rden, N, E);
    hipLaunchKernelGGL((gat_agg_hh_kernel<true>), dim3(N * 8), dim3(64), 0, stream,
                       bufG, ebuf, psf, rden, csrc, offs, b1, act_hi, act_lo, N, E);

    // ---- layer 2 ----
    hipLaunchKernelGGL(mfma_gemm128_kernel, dim3(512 / 128, gy128), dim3(256), 0, stream,
                       act_hi, act_lo, w2h, w2l, bufG, N, 512, 512);
    hipLaunchKernelGGL(al_h4_kernel, dim3(nb4), dim3(256), 0, stream, bufG, a2s, a2d, als, ald, N);
    hipLaunchKernelGGL(stats_h4_kernel, dim3(nb4), dim3(256), 0, stream,
                       csrc, offs, als, ald, ebuf, psf, rden, N, E);
    hipLaunchKernelGGL((gat_agg_hh_kernel<true>), dim3(N * 8), dim3(64), 0, stream,
                       bufG, ebuf, psf, rden, csrc, offs, b2, act_hi, act_lo, N, E);

    // ---- layer 3 + classifier ----
    hipLaunchKernelGGL(mfma_gemm64_kernel, dim3(128 / 128, gy64), dim3(256), 0, stream,
                       act_hi, act_lo, w3h, w3l, bufG, N, 128, 512);
    hipLaunchKernelGGL(al_h1_kernel, dim3(nb4), dim3(256), 0, stream, bufG, a3s, a3d, als, ald, N);
    hipLaunchKernelGGL(stats_h1_kernel, dim3(nb4), dim3(256), 0, stream,
                       csrc, offs, als, ald, ebuf, psf, rden, N);
    hipLaunchKernelGGL(gat_agg_h1_cls_kernel, dim3(N), dim3(64), 0, stream,
                       bufG, ebuf, psf, rden, csrc, offs, b3, Wc1, bc1, Wc2, bc2, emb, outp, N);
}

// Round 9
// 383.516 us; speedup vs baseline: 1.3935x; 1.0212x over previous
//
#include <hip/hip_runtime.h>
#include <cstddef>

#define LEAKY 0.2f
#define EPS_DEN 1e-16f

typedef short bf8_t __attribute__((ext_vector_type(8)));   // 8 bf16 in 4 VGPRs
typedef float f4_t __attribute__((ext_vector_type(4)));
typedef unsigned short us4_t __attribute__((ext_vector_type(4)));
typedef unsigned short us8_t __attribute__((ext_vector_type(8)));

__device__ __forceinline__ unsigned short f2bf(float f) {   // RNE
    unsigned u = __float_as_uint(f);
    unsigned r = (u + 0x7fffu + ((u >> 16) & 1u)) >> 16;
    return (unsigned short)r;
}
__device__ __forceinline__ float bf2f(unsigned short h) {
    return __uint_as_float(((unsigned)h) << 16);
}

// ---------------------------------------------------------------------------
// CSR build: histogram -> 3-phase parallel scan -> scatter
// ---------------------------------------------------------------------------
__global__ void hist_kernel(const int* __restrict__ dst, int* __restrict__ counts, int E) {
    int i = blockIdx.x * blockDim.x + threadIdx.x;
    if (i < E) atomicAdd(&counts[dst[i]], 1);
}

__global__ void scan1_kernel(int* __restrict__ cnt, int* __restrict__ bsum, int N) {
    __shared__ int s[256];
    int t = threadIdx.x;
    int i = blockIdx.x * 256 + t;
    int v = (i < N) ? cnt[i] : 0;
    s[t] = v;
    __syncthreads();
#pragma unroll
    for (int st = 1; st < 256; st <<= 1) {
        int add = (t >= st) ? s[t - st] : 0;
        __syncthreads();
        s[t] += add;
        __syncthreads();
    }
    if (i < N) cnt[i] = s[t] - v;           // exclusive within block
    if (t == 255) bsum[blockIdx.x] = s[255];
}

__global__ void scan2_kernel(int* __restrict__ bsum, int* __restrict__ offs, int NB, int N) {
    int t = threadIdx.x;   // 64 threads
    int v = (t < NB) ? bsum[t] : 0;
    int inc = v;
#pragma unroll
    for (int off = 1; off < 64; off <<= 1) {
        int u = __shfl_up(inc, off);
        if (t >= off) inc += u;
    }
    if (t < NB) bsum[t] = inc - v;          // exclusive
    if (t == 63) offs[N] = inc;             // total
}

__global__ void scan3_kernel(int* __restrict__ cnt, const int* __restrict__ bsum,
                             int* __restrict__ offs, int N) {
    int i = blockIdx.x * 256 + threadIdx.x;
    if (i < N) {
        int o = cnt[i] + bsum[blockIdx.x];
        offs[i] = o;
        cnt[i] = o;
    }
}

__global__ void scatter_kernel(const int* __restrict__ src, const int* __restrict__ dst,
                               int* __restrict__ cursor, int* __restrict__ csrc, int E) {
    int i = blockIdx.x * blockDim.x + threadIdx.x;
    if (i < E) {
        int d = dst[i];
        int pos = atomicAdd(&cursor[d], 1);
        csrc[pos] = src[i];
    }
}

// ---------------------------------------------------------------------------
// split fp32 -> bf16 hi + bf16 lo
// ---------------------------------------------------------------------------
__global__ void split_kernel(const float* __restrict__ in, unsigned short* __restrict__ hi,
                             unsigned short* __restrict__ lo, int len) {
    int i = blockIdx.x * blockDim.x + threadIdx.x;
    if (i >= len) return;
    float v = in[i];
    unsigned short h = f2bf(v);
    hi[i] = h;
    lo[i] = f2bf(v - bf2f(h));
}

// W [K,N] fp32  ->  WT_hi/lo [N,K] bf16 (transpose + split)
__global__ void wsplit_kernel(const float* __restrict__ W, unsigned short* __restrict__ hi,
                              unsigned short* __restrict__ lo, int K, int N) {
    int idx = blockIdx.x * blockDim.x + threadIdx.x;
    if (idx >= K * N) return;
    int n = idx / K, k = idx % K;
    float v = W[(size_t)k * N + n];
    unsigned short h = f2bf(v);
    hi[idx] = h;
    lo[idx] = f2bf(v - bf2f(h));
}

// ---------------------------------------------------------------------------
// MFMA GEMM (split-bf16): C = Ahi*Bhi + Ahi*Blo + Alo*Bhi, SINGLE staging per
// k0: all four tiles staged once, 48 MFMAs between 2 barriers (vs 16 between
// 6 in the 3-pass form). 128x128 tile, BK=32.
// ---------------------------------------------------------------------------
__global__ __launch_bounds__(256) void mfma_gemm128_kernel(
    const unsigned short* __restrict__ Ahi, const unsigned short* __restrict__ Alo,
    const unsigned short* __restrict__ BThi, const unsigned short* __restrict__ BTlo,
    float* __restrict__ C, int M, int N, int K) {
    constexpr int BK = 32;
    __shared__ __align__(16) unsigned short sAh[128 * BK];
    __shared__ __align__(16) unsigned short sAl[128 * BK];
    __shared__ __align__(16) unsigned short sBh[128 * BK];
    __shared__ __align__(16) unsigned short sBl[128 * BK];
    int t = threadIdx.x;
    int w = t >> 6, lane = t & 63;
    int quad = lane >> 4, low = lane & 15;
    int m0 = blockIdx.y * 128, n0 = blockIdx.x * 128;
    int wm = (w & 1) * 64, wn = (w >> 1) * 64;

    f4_t acc[4][4];
#pragma unroll
    for (int i = 0; i < 4; i++)
#pragma unroll
        for (int j = 0; j < 4; j++) acc[i][j] = (f4_t){0.f, 0.f, 0.f, 0.f};

    int srow = lane >> 2;
    int schunk = lane & 3;

    for (int k0 = 0; k0 < K; k0 += BK) {
        __syncthreads();
#pragma unroll
        for (int inst = 0; inst < 2; inst++) {
            int r = w * 32 + inst * 16 + srow;
            int gm = m0 + r;
            if (gm >= M) gm = M - 1;
            size_t goff = (size_t)gm * K + k0 + schunk * 8;
            size_t loff = (size_t)(w * 2048 + inst * 1024);
            __builtin_amdgcn_global_load_lds(
                (const __attribute__((address_space(1))) void*)(Ahi + goff),
                (__attribute__((address_space(3))) void*)((char*)sAh + loff), 16, 0, 0);
            __builtin_amdgcn_global_load_lds(
                (const __attribute__((address_space(1))) void*)(Alo + goff),
                (__attribute__((address_space(3))) void*)((char*)sAl + loff), 16, 0, 0);
        }
#pragma unroll
        for (int inst = 0; inst < 2; inst++) {
            int r = w * 32 + inst * 16 + srow;
            int gn = n0 + r;
            size_t goff = (size_t)gn * K + k0 + schunk * 8;
            size_t loff = (size_t)(w * 2048 + inst * 1024);
            __builtin_amdgcn_global_load_lds(
                (const __attribute__((address_space(1))) void*)(BThi + goff),
                (__attribute__((address_space(3))) void*)((char*)sBh + loff), 16, 0, 0);
            __builtin_amdgcn_global_load_lds(
                (const __attribute__((address_space(1))) void*)(BTlo + goff),
                (__attribute__((address_space(3))) void*)((char*)sBl + loff), 16, 0, 0);
        }
        __syncthreads();

        bf8_t afh[4], bfh[4], x[4];
#pragma unroll
        for (int i = 0; i < 4; i++) {
            int row = wm + i * 16 + low;
            afh[i] = *(const bf8_t*)&sAh[row * BK + quad * 8];
        }
#pragma unroll
        for (int j = 0; j < 4; j++) {
            int row = wn + j * 16 + low;
            bfh[j] = *(const bf8_t*)&sBh[row * BK + quad * 8];
        }
#pragma unroll
        for (int i = 0; i < 4; i++)
#pragma unroll
            for (int j = 0; j < 4; j++)
                acc[i][j] = __builtin_amdgcn_mfma_f32_16x16x32_bf16(afh[i], bfh[j], acc[i][j], 0, 0, 0);
        // x = Blo
#pragma unroll
        for (int j = 0; j < 4; j++) {
            int row = wn + j * 16 + low;
            x[j] = *(const bf8_t*)&sBl[row * BK + quad * 8];
        }
#pragma unroll
        for (int i = 0; i < 4; i++)
#pragma unroll
            for (int j = 0; j < 4; j++)
                acc[i][j] = __builtin_amdgcn_mfma_f32_16x16x32_bf16(afh[i], x[j], acc[i][j], 0, 0, 0);
        // x = Alo
#pragma unroll
        for (int i = 0; i < 4; i++) {
            int row = wm + i * 16 + low;
            x[i] = *(const bf8_t*)&sAl[row * BK + quad * 8];
        }
#pragma unroll
        for (int i = 0; i < 4; i++)
#pragma unroll
            for (int j = 0; j < 4; j++)
                acc[i][j] = __builtin_amdgcn_mfma_f32_16x16x32_bf16(x[i], bfh[j], acc[i][j], 0, 0, 0);
    }

#pragma unroll
    for (int i = 0; i < 4; i++) {
#pragma unroll
        for (int r = 0; r < 4; r++) {
            int gm = m0 + wm + i * 16 + quad * 4 + r;
            if (gm >= M) continue;
#pragma unroll
            for (int j = 0; j < 4; j++) {
                int gn = n0 + wn + j * 16 + low;
                C[(size_t)gm * N + gn] = acc[i][j][r];
            }
        }
    }
}

// 64x128 tile variant (layer 3: N=128 -> 157 blocks), same single-staging.
__global__ __launch_bounds__(256) void mfma_gemm64_kernel(
    const unsigned short* __restrict__ Ahi, const unsigned short* __restrict__ Alo,
    const unsigned short* __restrict__ BThi, const unsigned short* __restrict__ BTlo,
    float* __restrict__ C, int M, int N, int K) {
    constexpr int BK = 32;
    __shared__ __align__(16) unsigned short sAh[64 * BK];
    __shared__ __align__(16) unsigned short sAl[64 * BK];
    __shared__ __align__(16) unsigned short sBh[128 * BK];
    __shared__ __align__(16) unsigned short sBl[128 * BK];
    int t = threadIdx.x;
    int w = t >> 6, lane = t & 63;
    int quad = lane >> 4, low = lane & 15;
    int m0 = blockIdx.y * 64, n0 = blockIdx.x * 128;
    int wm = (w & 1) * 32, wn = (w >> 1) * 64;

    f4_t acc[2][4];
#pragma unroll
    for (int i = 0; i < 2; i++)
#pragma unroll
        for (int j = 0; j < 4; j++) acc[i][j] = (f4_t){0.f, 0.f, 0.f, 0.f};

    int srow = lane >> 2;
    int schunk = lane & 3;

    for (int k0 = 0; k0 < K; k0 += BK) {
        __syncthreads();
        {
            int gm = m0 + w * 16 + srow;
            if (gm >= M) gm = M - 1;
            size_t goff = (size_t)gm * K + k0 + schunk * 8;
            size_t loff = (size_t)(w * 1024);
            __builtin_amdgcn_global_load_lds(
                (const __attribute__((address_space(1))) void*)(Ahi + goff),
                (__attribute__((address_space(3))) void*)((char*)sAh + loff), 16, 0, 0);
            __builtin_amdgcn_global_load_lds(
                (const __attribute__((address_space(1))) void*)(Alo + goff),
                (__attribute__((address_space(3))) void*)((char*)sAl + loff), 16, 0, 0);
        }
#pragma unroll
        for (int inst = 0; inst < 2; inst++) {
            int gn = n0 + w * 32 + inst * 16 + srow;
            size_t goff = (size_t)gn * K + k0 + schunk * 8;
            size_t loff = (size_t)(w * 2048 + inst * 1024);
            __builtin_amdgcn_global_load_lds(
                (const __attribute__((address_space(1))) void*)(BThi + goff),
                (__attribute__((address_space(3))) void*)((char*)sBh + loff), 16, 0, 0);
            __builtin_amdgcn_global_load_lds(
                (const __attribute__((address_space(1))) void*)(BTlo + goff),
                (__attribute__((address_space(3))) void*)((char*)sBl + loff), 16, 0, 0);
        }
        __syncthreads();

        bf8_t afh[2], bfh[4], x[4];
#pragma unroll
        for (int i = 0; i < 2; i++) {
            int row = wm + i * 16 + low;
            afh[i] = *(const bf8_t*)&sAh[row * BK + quad * 8];
        }
#pragma unroll
        for (int j = 0; j < 4; j++) {
            int row = wn + j * 16 + low;
            bfh[j] = *(const bf8_t*)&sBh[row * BK + quad * 8];
        }
#pragma unroll
        for (int i = 0; i < 2; i++)
#pragma unroll
            for (int j = 0; j < 4; j++)
                acc[i][j] = __builtin_amdgcn_mfma_f32_16x16x32_bf16(afh[i], bfh[j], acc[i][j], 0, 0, 0);
#pragma unroll
        for (int j = 0; j < 4; j++) {
            int row = wn + j * 16 + low;
            x[j] = *(const bf8_t*)&sBl[row * BK + quad * 8];
        }
#pragma unroll
        for (int i = 0; i < 2; i++)
#pragma unroll
            for (int j = 0; j < 4; j++)
                acc[i][j] = __builtin_amdgcn_mfma_f32_16x16x32_bf16(afh[i], x[j], acc[i][j], 0, 0, 0);
#pragma unroll
        for (int i = 0; i < 2; i++) {
            int row = wm + i * 16 + low;
            x[i] = *(const bf8_t*)&sAl[row * BK + quad * 8];
        }
#pragma unroll
        for (int i = 0; i < 2; i++)
#pragma unroll
            for (int j = 0; j < 4; j++)
                acc[i][j] = __builtin_amdgcn_mfma_f32_16x16x32_bf16(x[i], bfh[j], acc[i][j], 0, 0, 0);
    }

#pragma unroll
    for (int i = 0; i < 2; i++) {
#pragma unroll
        for (int r = 0; r < 4; r++) {
            int gm = m0 + wm + i * 16 + quad * 4 + r;
            if (gm >= M) continue;
#pragma unroll
            for (int j = 0; j < 4; j++) {
                int gn = n0 + wn + j * 16 + low;
                C[(size_t)gm * N + gn] = acc[i][j][r];
            }
        }
    }
}

// ---------------------------------------------------------------------------
// attention logits
// ---------------------------------------------------------------------------
__global__ void al_h4_kernel(const float* __restrict__ h, const float* __restrict__ a_src,
                             const float* __restrict__ a_dst, float* __restrict__ als,
                             float* __restrict__ ald, int N) {
    int wave = threadIdx.x >> 6, lane = threadIdx.x & 63;
    int n = blockIdx.x * 4 + wave;
    if (n >= N) return;
    const float* row = h + (size_t)n * 512;
    float ps[4] = {0, 0, 0, 0}, pd[4] = {0, 0, 0, 0};
#pragma unroll
    for (int k = 0; k < 8; k++) {
        int f = k * 64 + lane;
        float v = row[f];
        ps[k >> 1] += v * a_src[f];
        pd[k >> 1] += v * a_dst[f];
    }
#pragma unroll
    for (int off = 32; off; off >>= 1) {
#pragma unroll
        for (int hd = 0; hd < 4; hd++) {
            ps[hd] += __shfl_down(ps[hd], off);
            pd[hd] += __shfl_down(pd[hd], off);
        }
    }
    if (lane == 0) {
#pragma unroll
        for (int hd = 0; hd < 4; hd++) {
            als[n * 4 + hd] = ps[hd];
            ald[n * 4 + hd] = pd[hd];
        }
    }
}

__global__ void al_h1_kernel(const float* __restrict__ h, const float* __restrict__ a_src,
                             const float* __restrict__ a_dst, float* __restrict__ als,
                             float* __restrict__ ald, int N) {
    int wave = threadIdx.x >> 6, lane = threadIdx.x & 63;
    int n = blockIdx.x * 4 + wave;
    if (n >= N) return;
    const float* row = h + (size_t)n * 128;
    float v0 = row[lane], v1 = row[lane + 64];
    float ps = v0 * a_src[lane] + v1 * a_src[lane + 64];
    float pd = v0 * a_dst[lane] + v1 * a_dst[lane + 64];
#pragma unroll
    for (int off = 32; off; off >>= 1) {
        ps += __shfl_down(ps, off);
        pd += __shfl_down(pd, off);
    }
    if (lane == 0) { als[n] = ps; ald[n] = pd; }
}

// ---------------------------------------------------------------------------
// Softmax stats per dst node -> UNNORMALIZED p in head-major pbuf[hd*E+slot];
// psf = unnorm self weight; rden = 1/(sum+eps).
// ---------------------------------------------------------------------------
__global__ void stats_h4_kernel(const int* __restrict__ csrc, const int* __restrict__ offs,
                                const float* __restrict__ als, const float* __restrict__ ald,
                                float* __restrict__ pbuf, float* __restrict__ psf,
                                float* __restrict__ rden, int N, int E) {
    int wave = threadIdx.x >> 6, lane = threadIdx.x & 63;
    int n = blockIdx.x * 4 + wave;
    if (n >= N) return;
    int hd = lane & 3, es = lane >> 2;   // head, edge slot 0..15
    float aldn = ald[n * 4 + hd];
    float selfe = als[n * 4 + hd] + aldn;
    selfe = selfe > 0.f ? selfe : LEAKY * selfe;
    int beg = offs[n], end = offs[n + 1];
    float* pb = pbuf + (size_t)hd * E;
    float m = selfe;
    for (int base = beg; base + es < end; base += 16) {
        int idx = base + es;
        int s = csrc[idx];
        float e = als[s * 4 + hd] + aldn;
        e = e > 0.f ? e : LEAKY * e;
        pb[idx] = e;
        m = fmaxf(m, e);
    }
#pragma unroll
    for (int off = 4; off < 64; off <<= 1) m = fmaxf(m, __shfl_xor(m, off));
    float d = 0.f;
    for (int base = beg; base + es < end; base += 16) {
        int idx = base + es;
        float p = __expf(pb[idx] - m);
        pb[idx] = p;
        d += p;
    }
#pragma unroll
    for (int off = 4; off < 64; off <<= 1) d += __shfl_xor(d, off);
    float pself = __expf(selfe - m);
    float r = 1.0f / (d + pself + EPS_DEN);
    if (es == 0) {
        psf[n * 4 + hd] = pself;
        rden[n * 4 + hd] = r;
    }
}

__global__ void stats_h1_kernel(const int* __restrict__ csrc, const int* __restrict__ offs,
                                const float* __restrict__ als, const float* __restrict__ ald,
                                float* __restrict__ pbuf, float* __restrict__ psf,
                                float* __restrict__ rden, int N) {
    int wave = threadIdx.x >> 6, lane = threadIdx.x & 63;
    int n = blockIdx.x * 4 + wave;
    if (n >= N) return;
    float aldn = ald[n];
    float selfe = als[n] + aldn;
    selfe = selfe > 0.f ? selfe : LEAKY * selfe;
    int beg = offs[n], end = offs[n + 1];
    float m = selfe;
    for (int base = beg; base + lane < end; base += 64) {
        int idx = base + lane;
        int s = csrc[idx];
        float e = als[s] + aldn;
        e = e > 0.f ? e : LEAKY * e;
        pbuf[idx] = e;
        m = fmaxf(m, e);
    }
#pragma unroll
    for (int off = 1; off < 64; off <<= 1) m = fmaxf(m, __shfl_xor(m, off));
    float d = 0.f;
    for (int base = beg; base + lane < end; base += 64) {
        int idx = base + lane;
        float p = __expf(pbuf[idx] - m);
        pbuf[idx] = p;
        d += p;
    }
#pragma unroll
    for (int off = 1; off < 64; off <<= 1) d += __shfl_xor(d, off);
    float pself = __expf(selfe - m);
    float r = 1.0f / (d + pself + EPS_DEN);
    if (lane == 0) { psf[n] = pself; rden[n] = r; }
}

// ---------------------------------------------------------------------------
// HALF-HEAD aggregate, BARRIER-FREE: one 64-thread block per (node, half-head).
// hh = blockIdx&7 keeps each XCD on one 2.6MB L2-resident slice. 8 groups of
// 8 lanes; each group takes every-8th edge, 8 floats/lane (2x f4); csrc/pb
// read directly from L2 (no LDS staging, no __syncthreads).
// ---------------------------------------------------------------------------
template <bool DO_ELU>
__global__ __launch_bounds__(64) void gat_agg_hh_kernel(
    const float* __restrict__ h, const float* __restrict__ pbuf,
    const float* __restrict__ psf, const float* __restrict__ rden,
    const int* __restrict__ csrc, const int* __restrict__ offs,
    const float* __restrict__ bias, unsigned short* __restrict__ ohi,
    unsigned short* __restrict__ olo, int N, int E) {
    int gid = blockIdx.x;
    int hh = gid & 7;
    int n = gid >> 3;
    int head = hh >> 1;
    int lane = threadIdx.x;
    int eg = lane >> 3;                 // 0..7 edge group
    int fl = (lane & 7) * 8;            // 8 floats per lane
    int f0 = hh * 64 + fl;
    const float* pb = pbuf + (size_t)head * E;
    int beg = offs[n], end = offs[n + 1];

    f4_t a0 = (f4_t){0.f, 0.f, 0.f, 0.f};
    f4_t a1 = (f4_t){0.f, 0.f, 0.f, 0.f};
#pragma unroll 2
    for (int c = beg + eg; c < end; c += 8) {
        int s = csrc[c];
        float p = pb[c];
        const float* srow = h + (size_t)s * 512 + f0;
        f4_t x0 = *(const f4_t*)(srow);
        f4_t x1 = *(const f4_t*)(srow + 4);
        a0 += p * x0;
        a1 += p * x1;
    }
    if (eg == 0) {
        float p = psf[n * 4 + head];
        const float* srow = h + (size_t)n * 512 + f0;
        a0 += p * *(const f4_t*)(srow);
        a1 += p * *(const f4_t*)(srow + 4);
    }
    // reduce across the 8 edge groups (lane bits 3,4,5)
#pragma unroll
    for (int j = 0; j < 4; j++) {
        a0[j] += __shfl_xor(a0[j], 8);
        a0[j] += __shfl_xor(a0[j], 16);
        a0[j] += __shfl_xor(a0[j], 32);
        a1[j] += __shfl_xor(a1[j], 8);
        a1[j] += __shfl_xor(a1[j], 16);
        a1[j] += __shfl_xor(a1[j], 32);
    }
    if (lane < 8) {
        int fo = hh * 64 + lane * 8;
        float r = rden[n * 4 + head];
        f4_t b0 = *(const f4_t*)(bias + fo);
        f4_t b1 = *(const f4_t*)(bias + fo + 4);
        us8_t hs, ls;
#pragma unroll
        for (int j = 0; j < 4; j++) {
            float o = a0[j] * r + b0[j];
            if (DO_ELU) o = o > 0.f ? o : (__expf(o) - 1.0f);
            unsigned short hv = f2bf(o);
            hs[j] = hv;
            ls[j] = f2bf(o - bf2f(hv));
        }
#pragma unroll
        for (int j = 0; j < 4; j++) {
            float o = a1[j] * r + b1[j];
            if (DO_ELU) o = o > 0.f ? o : (__expf(o) - 1.0f);
            unsigned short hv = f2bf(o);
            hs[4 + j] = hv;
            ls[4 + j] = f2bf(o - bf2f(hv));
        }
        size_t idx = (size_t)n * 512 + fo;
        *(us8_t*)&ohi[idx] = hs;
        *(us8_t*)&olo[idx] = ls;
    }
}

// Layer-3: barrier-free aggregate + classifier fused. One block per node.
// 4 groups of 16 lanes, 8 floats/lane (F=128).
__global__ __launch_bounds__(64) void gat_agg_h1_cls_kernel(
    const float* __restrict__ h, const float* __restrict__ pbuf,
    const float* __restrict__ psf, const float* __restrict__ rden,
    const int* __restrict__ csrc, const int* __restrict__ offs,
    const float* __restrict__ bias, const float* __restrict__ Wc1,
    const float* __restrict__ bc1, const float* __restrict__ Wc2,
    const float* __restrict__ bc2, float* __restrict__ emb,
    float* __restrict__ outp, int N) {
    int n = blockIdx.x;
    int lane = threadIdx.x;
    int eg = lane >> 4;                 // 0..3
    int fl = (lane & 15) * 8;           // 8 floats per lane
    __shared__ float semb[128];
    int beg = offs[n], end = offs[n + 1];

    f4_t a0 = (f4_t){0.f, 0.f, 0.f, 0.f};
    f4_t a1 = (f4_t){0.f, 0.f, 0.f, 0.f};
#pragma unroll 2
    for (int c = beg + eg; c < end; c += 4) {
        int s = csrc[c];
        float p = pbuf[c];
        const float* srow = h + (size_t)s * 128 + fl;
        a0 += p * *(const f4_t*)(srow);
        a1 += p * *(const f4_t*)(srow + 4);
    }
    if (eg == 0) {
        float p = psf[n];
        const float* srow = h + (size_t)n * 128 + fl;
        a0 += p * *(const f4_t*)(srow);
        a1 += p * *(const f4_t*)(srow + 4);
    }
#pragma unroll
    for (int j = 0; j < 4; j++) {
        a0[j] += __shfl_xor(a0[j], 16);
        a0[j] += __shfl_xor(a0[j], 32);
        a1[j] += __shfl_xor(a1[j], 16);
        a1[j] += __shfl_xor(a1[j], 32);
    }
    if (lane < 16) {
        int fo = lane * 8;
        float r = rden[n];
        f4_t b0 = *(const f4_t*)(bias + fo);
        f4_t b1 = *(const f4_t*)(bias + fo + 4);
        f4_t o0, o1;
#pragma unroll
        for (int j = 0; j < 4; j++) {
            o0[j] = a0[j] * r + b0[j];
            o1[j] = a1[j] * r + b1[j];
        }
        *(f4_t*)&semb[fo] = o0;
        *(f4_t*)&semb[fo + 4] = o1;
        *(f4_t*)&emb[(size_t)n * 128 + fo] = o0;
        *(f4_t*)&emb[(size_t)n * 128 + fo + 4] = o1;
    }
    __syncthreads();

    // classifier: hidden[lane] = relu(bc1[lane] + sum_k semb[k]*Wc1[k*64+lane])
    float cacc = bc1[lane];
#pragma unroll 4
    for (int k = 0; k < 128; k++) cacc += semb[k] * Wc1[k * 64 + lane];
    cacc = fmaxf(cacc, 0.f);
    float o0 = cacc * Wc2[lane * 2 + 0];
    float o1 = cacc * Wc2[lane * 2 + 1];
#pragma unroll
    for (int off = 32; off; off >>= 1) {
        o0 += __shfl_down(o0, off);
        o1 += __shfl_down(o1, off);
    }
    if (lane == 0) {
        outp[n * 2 + 0] = o0 + bc2[0];
        outp[n * 2 + 1] = o1 + bc2[1];
    }
}

// ---------------------------------------------------------------------------
extern "C" void kernel_launch(void* const* d_in, const int* in_sizes, int n_in,
                              void* d_out, int out_size, void* d_ws, size_t ws_size,
                              hipStream_t stream) {
    const float* x      = (const float*)d_in[0];
    const int*   ei     = (const int*)d_in[1];
    const float* W1     = (const float*)d_in[2];
    const float* a1s    = (const float*)d_in[3];
    const float* a1d    = (const float*)d_in[4];
    const float* b1     = (const float*)d_in[5];
    const float* W2     = (const float*)d_in[6];
    const float* a2s    = (const float*)d_in[7];
    const float* a2d    = (const float*)d_in[8];
    const float* b2     = (const float*)d_in[9];
    const float* W3     = (const float*)d_in[10];
    const float* a3s    = (const float*)d_in[11];
    const float* a3d    = (const float*)d_in[12];
    const float* b3     = (const float*)d_in[13];
    const float* Wc1    = (const float*)d_in[14];
    const float* bc1    = (const float*)d_in[15];
    const float* Wc2    = (const float*)d_in[16];
    const float* bc2    = (const float*)d_in[17];

    const int N = in_sizes[0] / 256;       // 10000
    const int E = in_sizes[1] / 2;         // 320000
    const int F = 512;

    const int* src = ei;
    const int* dst = ei + E;

    auto align = [](size_t o) { return (o + 255) & ~(size_t)255; };
    size_t o = 0;
    size_t o_G     = o; o = align(o + (size_t)N * F * 4);        // GEMM output h (fp32)
    size_t o_ahi   = o; o = align(o + (size_t)N * F * 2);
    size_t o_alo   = o; o = align(o + (size_t)N * F * 2);
    size_t o_xhi   = o; o = align(o + (size_t)N * 256 * 2);
    size_t o_xlo   = o; o = align(o + (size_t)N * 256 * 2);
    size_t o_w1h   = o; o = align(o + (size_t)512 * 256 * 2);
    size_t o_w1l   = o; o = align(o + (size_t)512 * 256 * 2);
    size_t o_w2h   = o; o = align(o + (size_t)512 * 512 * 2);
    size_t o_w2l   = o; o = align(o + (size_t)512 * 512 * 2);
    size_t o_w3h   = o; o = align(o + (size_t)128 * 512 * 2);
    size_t o_w3l   = o; o = align(o + (size_t)128 * 512 * 2);
    size_t o_als   = o; o = align(o + (size_t)N * 4 * 4);
    size_t o_ald   = o; o = align(o + (size_t)N * 4 * 4);
    size_t o_psf   = o; o = align(o + (size_t)N * 4 * 4);
    size_t o_rden  = o; o = align(o + (size_t)N * 4 * 4);
    size_t o_cnt   = o; o = align(o + (size_t)N * 4);
    size_t o_off   = o; o = align(o + (size_t)(N + 1) * 4);
    size_t o_bsum  = o; o = align(o + (size_t)64 * 4);
    size_t o_csrc  = o; o = align(o + (size_t)E * 4);
    size_t o_ebuf  = o; o = align(o + (size_t)E * 4 * 4);
    (void)ws_size;

    char* ws = (char*)d_ws;
    float* bufG  = (float*)(ws + o_G);
    unsigned short* act_hi = (unsigned short*)(ws + o_ahi);
    unsigned short* act_lo = (unsigned short*)(ws + o_alo);
    unsigned short* x_hi   = (unsigned short*)(ws + o_xhi);
    unsigned short* x_lo   = (unsigned short*)(ws + o_xlo);
    unsigned short* w1h = (unsigned short*)(ws + o_w1h);
    unsigned short* w1l = (unsigned short*)(ws + o_w1l);
    unsigned short* w2h = (unsigned short*)(ws + o_w2h);
    unsigned short* w2l = (unsigned short*)(ws + o_w2l);
    unsigned short* w3h = (unsigned short*)(ws + o_w3h);
    unsigned short* w3l = (unsigned short*)(ws + o_w3l);
    float* als  = (float*)(ws + o_als);
    float* ald  = (float*)(ws + o_ald);
    float* psf  = (float*)(ws + o_psf);
    float* rden = (float*)(ws + o_rden);
    int*   cnt  = (int*)(ws + o_cnt);
    int*   offs = (int*)(ws + o_off);
    int*   bsum = (int*)(ws + o_bsum);
    int*   csrc = (int*)(ws + o_csrc);
    float* ebuf = (float*)(ws + o_ebuf);

    float* outp = (float*)d_out;                 // [N,2]
    float* emb  = (float*)d_out + (size_t)N * 2; // [N,128]

    // ---- CSR build ----
    hipMemsetAsync(cnt, 0, (size_t)N * 4, stream);
    int eb = (E + 255) / 256;
    int nbs = (N + 255) / 256;   // 40
    hipLaunchKernelGGL(hist_kernel, dim3(eb), dim3(256), 0, stream, dst, cnt, E);
    hipLaunchKernelGGL(scan1_kernel, dim3(nbs), dim3(256), 0, stream, cnt, bsum, N);
    hipLaunchKernelGGL(scan2_kernel, dim3(1), dim3(64), 0, stream, bsum, offs, nbs, N);
    hipLaunchKernelGGL(scan3_kernel, dim3(nbs), dim3(256), 0, stream, cnt, bsum, offs, N);
    hipLaunchKernelGGL(scatter_kernel, dim3(eb), dim3(256), 0, stream, src, dst, cnt, csrc, E);

    // ---- splits ----
    hipLaunchKernelGGL(split_kernel, dim3((N * 256 + 255) / 256), dim3(256), 0, stream,
                       x, x_hi, x_lo, N * 256);
    hipLaunchKernelGGL(wsplit_kernel, dim3((256 * 512 + 255) / 256), dim3(256), 0, stream,
                       W1, w1h, w1l, 256, 512);
    hipLaunchKernelGGL(wsplit_kernel, dim3((512 * 512 + 255) / 256), dim3(256), 0, stream,
                       W2, w2h, w2l, 512, 512);
    hipLaunchKernelGGL(wsplit_kernel, dim3((512 * 128 + 255) / 256), dim3(256), 0, stream,
                       W3, w3h, w3l, 512, 128);

    int nb4 = (N + 3) / 4;
    int gy128 = (N + 127) / 128;  // 79
    int gy64  = (N + 63) / 64;    // 157

    // ---- layer 1 ----
    hipLaunchKernelGGL(mfma_gemm128_kernel, dim3(512 / 128, gy128), dim3(256), 0, stream,
                       x_hi, x_lo, w1h, w1l, bufG, N, 512, 256);
    hipLaunchKernelGGL(al_h4_kernel, dim3(nb4), dim3(256), 0, stream, bufG, a1s, a1d, als, ald, N);
    hipLaunchKernelGGL(stats_h4_kernel, dim3(nb4), dim3(256), 0, stream,
                       csrc, offs, als, ald, ebuf, psf, rden, N, E);
    hipLaunchKernelGGL((gat_agg_hh_kernel<true>), dim3(N * 8), dim3(64), 0, stream,
                       bufG, ebuf, psf, rden, csrc, offs, b1, act_hi, act_lo, N, E);

    // ---- layer 2 ----
    hipLaunchKernelGGL(mfma_gemm128_kernel, dim3(512 / 128, gy128), dim3(256), 0, stream,
                       act_hi, act_lo, w2h, w2l, bufG, N, 512, 512);
    hipLaunchKernelGGL(al_h4_kernel, dim3(nb4), dim3(256), 0, stream, bufG, a2s, a2d, als, ald, N);
    hipLaunchKernelGGL(stats_h4_kernel, dim3(nb4), dim3(256), 0, stream,
                       csrc, offs, als, ald, ebuf, psf, rden, N, E);
    hipLaunchKernelGGL((gat_agg_hh_kernel<true>), dim3(N * 8), dim3(64), 0, stream,
                       bufG, ebuf, psf, rden, csrc, offs, b2, act_hi, act_lo, N, E);

    // ---- layer 3 + classifier ----
    hipLaunchKernelGGL(mfma_gemm64_kernel, dim3(128 / 128, gy64), dim3(256), 0, stream,
                       act_hi, act_lo, w3h, w3l, bufG, N, 128, 512);
    hipLaunchKernelGGL(al_h1_kernel, dim3(nb4), dim3(256), 0, stream, bufG, a3s, a3d, als, ald, N);
    hipLaunchKernelGGL(stats_h1_kernel, dim3(nb4), dim3(256), 0, stream,
                       csrc, offs, als, ald, ebuf, psf, rden, N);
    hipLaunchKernelGGL(gat_agg_h1_cls_kernel, dim3(N), dim3(64), 0, stream,
                       bufG, ebuf, psf, rden, csrc, offs, b3, Wc1, bc1, Wc2, bc2, emb, outp, N);
}

// Round 10
// 363.228 us; speedup vs baseline: 1.4714x; 1.0559x over previous
//
#include <hip/hip_runtime.h>
#include <cstddef>

#define LEAKY 0.2f
#define EPS_DEN 1e-16f

typedef short bf8_t __attribute__((ext_vector_type(8)));   // 8 bf16 in 4 VGPRs
typedef float f4_t __attribute__((ext_vector_type(4)));
typedef unsigned short us4_t __attribute__((ext_vector_type(4)));
typedef unsigned short us8_t __attribute__((ext_vector_type(8)));

__device__ __forceinline__ unsigned short f2bf(float f) {   // RNE
    unsigned u = __float_as_uint(f);
    unsigned r = (u + 0x7fffu + ((u >> 16) & 1u)) >> 16;
    return (unsigned short)r;
}
__device__ __forceinline__ float bf2f(unsigned short h) {
    return __uint_as_float(((unsigned)h) << 16);
}

// ---------------------------------------------------------------------------
// CSR build: histogram -> scan1 -> scan3b (fused block-sum scan) -> scatter
// ---------------------------------------------------------------------------
__global__ void hist_kernel(const int* __restrict__ dst, int* __restrict__ counts, int E) {
    int i = blockIdx.x * blockDim.x + threadIdx.x;
    if (i < E) atomicAdd(&counts[dst[i]], 1);
}

__global__ void scan1_kernel(int* __restrict__ cnt, int* __restrict__ bsum, int N) {
    __shared__ int s[256];
    int t = threadIdx.x;
    int i = blockIdx.x * 256 + t;
    int v = (i < N) ? cnt[i] : 0;
    s[t] = v;
    __syncthreads();
#pragma unroll
    for (int st = 1; st < 256; st <<= 1) {
        int add = (t >= st) ? s[t - st] : 0;
        __syncthreads();
        s[t] += add;
        __syncthreads();
    }
    if (i < N) cnt[i] = s[t] - v;           // exclusive within block
    if (t == 255) bsum[blockIdx.x] = s[255];
}

// fused scan2+scan3: every block scans the <=64 block sums in wave 0, applies.
__global__ void scan3b_kernel(int* __restrict__ cnt, const int* __restrict__ bsum,
                              int* __restrict__ offs, int N, int NB) {
    __shared__ int sPre[64];
    __shared__ int sTot;
    int t = threadIdx.x;   // 256
    if (t < 64) {
        int v = (t < NB) ? bsum[t] : 0;
        int inc = v;
#pragma unroll
        for (int off = 1; off < 64; off <<= 1) {
            int u = __shfl_up(inc, off);
            if (t >= off) inc += u;
        }
        sPre[t] = inc - v;     // exclusive
        if (t == 63) sTot = inc;
    }
    __syncthreads();
    int i = blockIdx.x * 256 + t;
    if (i < N) {
        int o = cnt[i] + sPre[blockIdx.x];
        offs[i] = o;
        cnt[i] = o;
    }
    if (blockIdx.x == 0 && t == 0) offs[N] = sTot;
}

__global__ void scatter_kernel(const int* __restrict__ src, const int* __restrict__ dst,
                               int* __restrict__ cursor, int* __restrict__ csrc, int E) {
    int i = blockIdx.x * blockDim.x + threadIdx.x;
    if (i < E) {
        int d = dst[i];
        int pos = atomicAdd(&cursor[d], 1);
        csrc[pos] = src[i];
    }
}

// ---------------------------------------------------------------------------
// Merged split kernel: x (straight) + W1/W2/W3 (transpose) fp32 -> bf16 hi/lo.
// Block segmentation: [0,NBX) x, [NBX,+512) W1T, [+1024) W2T, [+256) W3T.
// ---------------------------------------------------------------------------
__global__ void split_all_kernel(
    const float* __restrict__ x, unsigned short* __restrict__ xh, unsigned short* __restrict__ xl,
    int NBX,
    const float* __restrict__ W1, unsigned short* __restrict__ w1h, unsigned short* __restrict__ w1l,
    const float* __restrict__ W2, unsigned short* __restrict__ w2h, unsigned short* __restrict__ w2l,
    const float* __restrict__ W3, unsigned short* __restrict__ w3h, unsigned short* __restrict__ w3l) {
    int b = blockIdx.x, t = threadIdx.x;
    float v;
    unsigned short* ph;
    unsigned short* pl;
    int idx;
    if (b < NBX) {
        idx = b * 256 + t;
        v = x[idx];
        ph = xh; pl = xl;
    } else if (b < NBX + 512) {                 // W1^T [512,256], W1 [256,512]
        idx = (b - NBX) * 256 + t;
        int n = idx >> 8, k = idx & 255;
        v = W1[(size_t)k * 512 + n];
        ph = w1h; pl = w1l;
    } else if (b < NBX + 512 + 1024) {          // W2^T [512,512]
        idx = (b - NBX - 512) * 256 + t;
        int n = idx >> 9, k = idx & 511;
        v = W2[(size_t)k * 512 + n];
        ph = w2h; pl = w2l;
    } else {                                    // W3^T [128,512], W3 [512,128]
        idx = (b - NBX - 1536) * 256 + t;
        int n = idx >> 9, k = idx & 511;
        v = W3[(size_t)k * 128 + n];
        ph = w3h; pl = w3l;
    }
    unsigned short hv = f2bf(v);
    ph[idx] = hv;
    pl[idx] = f2bf(v - bf2f(hv));
}

// ---------------------------------------------------------------------------
// MFMA GEMM (split-bf16, single-staged: 48 MFMAs between 2 barriers), 128x128.
// EPILOGUE: computes als/ald for its 128 rows (block cols == one head).
// ---------------------------------------------------------------------------
__global__ __launch_bounds__(256) void mfma_gemm128_kernel(
    const unsigned short* __restrict__ Ahi, const unsigned short* __restrict__ Alo,
    const unsigned short* __restrict__ BThi, const unsigned short* __restrict__ BTlo,
    const float* __restrict__ a_src, const float* __restrict__ a_dst,
    float* __restrict__ C, float* __restrict__ als, float* __restrict__ ald,
    int M, int N, int K) {
    constexpr int BK = 32;
    __shared__ __align__(16) unsigned short sAh[128 * BK];
    __shared__ __align__(16) unsigned short sAl[128 * BK];
    __shared__ __align__(16) unsigned short sBh[128 * BK];
    __shared__ __align__(16) unsigned short sBl[128 * BK];
    __shared__ float sAls[128][2];
    __shared__ float sAld[128][2];
    int t = threadIdx.x;
    int w = t >> 6, lane = t & 63;
    int quad = lane >> 4, low = lane & 15;
    int m0 = blockIdx.y * 128, n0 = blockIdx.x * 128;
    int wm = (w & 1) * 64, wn = (w >> 1) * 64;

    f4_t acc[4][4];
#pragma unroll
    for (int i = 0; i < 4; i++)
#pragma unroll
        for (int j = 0; j < 4; j++) acc[i][j] = (f4_t){0.f, 0.f, 0.f, 0.f};

    int srow = lane >> 2;
    int schunk = lane & 3;

    for (int k0 = 0; k0 < K; k0 += BK) {
        __syncthreads();
#pragma unroll
        for (int inst = 0; inst < 2; inst++) {
            int r = w * 32 + inst * 16 + srow;
            int gm = m0 + r;
            if (gm >= M) gm = M - 1;
            size_t goff = (size_t)gm * K + k0 + schunk * 8;
            size_t loff = (size_t)(w * 2048 + inst * 1024);
            __builtin_amdgcn_global_load_lds(
                (const __attribute__((address_space(1))) void*)(Ahi + goff),
                (__attribute__((address_space(3))) void*)((char*)sAh + loff), 16, 0, 0);
            __builtin_amdgcn_global_load_lds(
                (const __attribute__((address_space(1))) void*)(Alo + goff),
                (__attribute__((address_space(3))) void*)((char*)sAl + loff), 16, 0, 0);
        }
#pragma unroll
        for (int inst = 0; inst < 2; inst++) {
            int r = w * 32 + inst * 16 + srow;
            int gn = n0 + r;
            size_t goff = (size_t)gn * K + k0 + schunk * 8;
            size_t loff = (size_t)(w * 2048 + inst * 1024);
            __builtin_amdgcn_global_load_lds(
                (const __attribute__((address_space(1))) void*)(BThi + goff),
                (__attribute__((address_space(3))) void*)((char*)sBh + loff), 16, 0, 0);
            __builtin_amdgcn_global_load_lds(
                (const __attribute__((address_space(1))) void*)(BTlo + goff),
                (__attribute__((address_space(3))) void*)((char*)sBl + loff), 16, 0, 0);
        }
        __syncthreads();

        bf8_t afh[4], bfh[4], xx[4];
#pragma unroll
        for (int i = 0; i < 4; i++) {
            int row = wm + i * 16 + low;
            afh[i] = *(const bf8_t*)&sAh[row * BK + quad * 8];
        }
#pragma unroll
        for (int j = 0; j < 4; j++) {
            int row = wn + j * 16 + low;
            bfh[j] = *(const bf8_t*)&sBh[row * BK + quad * 8];
        }
#pragma unroll
        for (int i = 0; i < 4; i++)
#pragma unroll
            for (int j = 0; j < 4; j++)
                acc[i][j] = __builtin_amdgcn_mfma_f32_16x16x32_bf16(afh[i], bfh[j], acc[i][j], 0, 0, 0);
#pragma unroll
        for (int j = 0; j < 4; j++) {
            int row = wn + j * 16 + low;
            xx[j] = *(const bf8_t*)&sBl[row * BK + quad * 8];
        }
#pragma unroll
        for (int i = 0; i < 4; i++)
#pragma unroll
            for (int j = 0; j < 4; j++)
                acc[i][j] = __builtin_amdgcn_mfma_f32_16x16x32_bf16(afh[i], xx[j], acc[i][j], 0, 0, 0);
#pragma unroll
        for (int i = 0; i < 4; i++) {
            int row = wm + i * 16 + low;
            xx[i] = *(const bf8_t*)&sAl[row * BK + quad * 8];
        }
#pragma unroll
        for (int i = 0; i < 4; i++)
#pragma unroll
            for (int j = 0; j < 4; j++)
                acc[i][j] = __builtin_amdgcn_mfma_f32_16x16x32_bf16(xx[i], bfh[j], acc[i][j], 0, 0, 0);
    }

    // C store
#pragma unroll
    for (int i = 0; i < 4; i++) {
#pragma unroll
        for (int r = 0; r < 4; r++) {
            int gm = m0 + wm + i * 16 + quad * 4 + r;
            if (gm >= M) continue;
#pragma unroll
            for (int j = 0; j < 4; j++) {
                int gn = n0 + wn + j * 16 + low;
                C[(size_t)gm * N + gn] = acc[i][j][r];
            }
        }
    }

    // epilogue: als/ald for this block's rows; head = n0>>7 (128 cols == head)
    int hd = n0 >> 7;
    float as_[4], ad_[4];
#pragma unroll
    for (int j = 0; j < 4; j++) {
        int c = wn + j * 16 + low;
        as_[j] = a_src[hd * 128 + c];
        ad_[j] = a_dst[hd * 128 + c];
    }
    int chh = wn >> 6;
#pragma unroll
    for (int i = 0; i < 4; i++) {
#pragma unroll
        for (int r = 0; r < 4; r++) {
            float v = acc[i][0][r] * as_[0] + acc[i][1][r] * as_[1] +
                      acc[i][2][r] * as_[2] + acc[i][3][r] * as_[3];
            float vd = acc[i][0][r] * ad_[0] + acc[i][1][r] * ad_[1] +
                       acc[i][2][r] * ad_[2] + acc[i][3][r] * ad_[3];
#pragma unroll
            for (int off = 1; off < 16; off <<= 1) {
                v += __shfl_xor(v, off);
                vd += __shfl_xor(vd, off);
            }
            if (low == 0) {
                int row = wm + i * 16 + quad * 4 + r;
                sAls[row][chh] = v;
                sAld[row][chh] = vd;
            }
        }
    }
    __syncthreads();
    if (t < 128) {
        int gm = m0 + t;
        if (gm < M) {
            als[gm * 4 + hd] = sAls[t][0] + sAls[t][1];
            ald[gm * 4 + hd] = sAld[t][0] + sAld[t][1];
        }
    }
}

// 64x128 variant for layer 3 (N=128 == full feature dim, H=1) + als epilogue.
__global__ __launch_bounds__(256) void mfma_gemm64_kernel(
    const unsigned short* __restrict__ Ahi, const unsigned short* __restrict__ Alo,
    const unsigned short* __restrict__ BThi, const unsigned short* __restrict__ BTlo,
    const float* __restrict__ a_src, const float* __restrict__ a_dst,
    float* __restrict__ C, float* __restrict__ als, float* __restrict__ ald,
    int M, int N, int K) {
    constexpr int BK = 32;
    __shared__ __align__(16) unsigned short sAh[64 * BK];
    __shared__ __align__(16) unsigned short sAl[64 * BK];
    __shared__ __align__(16) unsigned short sBh[128 * BK];
    __shared__ __align__(16) unsigned short sBl[128 * BK];
    __shared__ float sAls[64][2];
    __shared__ float sAld[64][2];
    int t = threadIdx.x;
    int w = t >> 6, lane = t & 63;
    int quad = lane >> 4, low = lane & 15;
    int m0 = blockIdx.y * 64, n0 = blockIdx.x * 128;
    int wm = (w & 1) * 32, wn = (w >> 1) * 64;

    f4_t acc[2][4];
#pragma unroll
    for (int i = 0; i < 2; i++)
#pragma unroll
        for (int j = 0; j < 4; j++) acc[i][j] = (f4_t){0.f, 0.f, 0.f, 0.f};

    int srow = lane >> 2;
    int schunk = lane & 3;

    for (int k0 = 0; k0 < K; k0 += BK) {
        __syncthreads();
        {
            int gm = m0 + w * 16 + srow;
            if (gm >= M) gm = M - 1;
            size_t goff = (size_t)gm * K + k0 + schunk * 8;
            size_t loff = (size_t)(w * 1024);
            __builtin_amdgcn_global_load_lds(
                (const __attribute__((address_space(1))) void*)(Ahi + goff),
                (__attribute__((address_space(3))) void*)((char*)sAh + loff), 16, 0, 0);
            __builtin_amdgcn_global_load_lds(
                (const __attribute__((address_space(1))) void*)(Alo + goff),
                (__attribute__((address_space(3))) void*)((char*)sAl + loff), 16, 0, 0);
        }
#pragma unroll
        for (int inst = 0; inst < 2; inst++) {
            int gn = n0 + w * 32 + inst * 16 + srow;
            size_t goff = (size_t)gn * K + k0 + schunk * 8;
            size_t loff = (size_t)(w * 2048 + inst * 1024);
            __builtin_amdgcn_global_load_lds(
                (const __attribute__((address_space(1))) void*)(BThi + goff),
                (__attribute__((address_space(3))) void*)((char*)sBh + loff), 16, 0, 0);
            __builtin_amdgcn_global_load_lds(
                (const __attribute__((address_space(1))) void*)(BTlo + goff),
                (__attribute__((address_space(3))) void*)((char*)sBl + loff), 16, 0, 0);
        }
        __syncthreads();

        bf8_t afh[2], bfh[4], xx[4];
#pragma unroll
        for (int i = 0; i < 2; i++) {
            int row = wm + i * 16 + low;
            afh[i] = *(const bf8_t*)&sAh[row * BK + quad * 8];
        }
#pragma unroll
        for (int j = 0; j < 4; j++) {
            int row = wn + j * 16 + low;
            bfh[j] = *(const bf8_t*)&sBh[row * BK + quad * 8];
        }
#pragma unroll
        for (int i = 0; i < 2; i++)
#pragma unroll
            for (int j = 0; j < 4; j++)
                acc[i][j] = __builtin_amdgcn_mfma_f32_16x16x32_bf16(afh[i], bfh[j], acc[i][j], 0, 0, 0);
#pragma unroll
        for (int j = 0; j < 4; j++) {
            int row = wn + j * 16 + low;
            xx[j] = *(const bf8_t*)&sBl[row * BK + quad * 8];
        }
#pragma unroll
        for (int i = 0; i < 2; i++)
#pragma unroll
            for (int j = 0; j < 4; j++)
                acc[i][j] = __builtin_amdgcn_mfma_f32_16x16x32_bf16(afh[i], xx[j], acc[i][j], 0, 0, 0);
#pragma unroll
        for (int i = 0; i < 2; i++) {
            int row = wm + i * 16 + low;
            xx[i] = *(const bf8_t*)&sAl[row * BK + quad * 8];
        }
#pragma unroll
        for (int i = 0; i < 2; i++)
#pragma unroll
            for (int j = 0; j < 4; j++)
                acc[i][j] = __builtin_amdgcn_mfma_f32_16x16x32_bf16(xx[i], bfh[j], acc[i][j], 0, 0, 0);
    }

#pragma unroll
    for (int i = 0; i < 2; i++) {
#pragma unroll
        for (int r = 0; r < 4; r++) {
            int gm = m0 + wm + i * 16 + quad * 4 + r;
            if (gm >= M) continue;
#pragma unroll
            for (int j = 0; j < 4; j++) {
                int gn = n0 + wn + j * 16 + low;
                C[(size_t)gm * N + gn] = acc[i][j][r];
            }
        }
    }

    // epilogue: H=1, block cols cover all 128 features
    float as_[4], ad_[4];
#pragma unroll
    for (int j = 0; j < 4; j++) {
        int c = wn + j * 16 + low;
        as_[j] = a_src[c];
        ad_[j] = a_dst[c];
    }
    int chh = wn >> 6;
#pragma unroll
    for (int i = 0; i < 2; i++) {
#pragma unroll
        for (int r = 0; r < 4; r++) {
            float v = acc[i][0][r] * as_[0] + acc[i][1][r] * as_[1] +
                      acc[i][2][r] * as_[2] + acc[i][3][r] * as_[3];
            float vd = acc[i][0][r] * ad_[0] + acc[i][1][r] * ad_[1] +
                       acc[i][2][r] * ad_[2] + acc[i][3][r] * ad_[3];
#pragma unroll
            for (int off = 1; off < 16; off <<= 1) {
                v += __shfl_xor(v, off);
                vd += __shfl_xor(vd, off);
            }
            if (low == 0) {
                int row = wm + i * 16 + quad * 4 + r;
                sAls[row][chh] = v;
                sAld[row][chh] = vd;
            }
        }
    }
    __syncthreads();
    if (t < 64) {
        int gm = m0 + t;
        if (gm < M) {
            als[gm] = sAls[t][0] + sAls[t][1];
            ald[gm] = sAld[t][0] + sAld[t][1];
        }
    }
}

// ---------------------------------------------------------------------------
// Softmax stats per dst node -> UNNORMALIZED p in head-major pbuf[hd*E+slot];
// psf = unnorm self weight; rden = 1/(sum+eps).
// ---------------------------------------------------------------------------
__global__ void stats_h4_kernel(const int* __restrict__ csrc, const int* __restrict__ offs,
                                const float* __restrict__ als, const float* __restrict__ ald,
                                float* __restrict__ pbuf, float* __restrict__ psf,
                                float* __restrict__ rden, int N, int E) {
    int wave = threadIdx.x >> 6, lane = threadIdx.x & 63;
    int n = blockIdx.x * 4 + wave;
    if (n >= N) return;
    int hd = lane & 3, es = lane >> 2;   // head, edge slot 0..15
    float aldn = ald[n * 4 + hd];
    float selfe = als[n * 4 + hd] + aldn;
    selfe = selfe > 0.f ? selfe : LEAKY * selfe;
    int beg = offs[n], end = offs[n + 1];
    float* pb = pbuf + (size_t)hd * E;
    float m = selfe;
    for (int base = beg; base + es < end; base += 16) {
        int idx = base + es;
        int s = csrc[idx];
        float e = als[s * 4 + hd] + aldn;
        e = e > 0.f ? e : LEAKY * e;
        pb[idx] = e;
        m = fmaxf(m, e);
    }
#pragma unroll
    for (int off = 4; off < 64; off <<= 1) m = fmaxf(m, __shfl_xor(m, off));
    float d = 0.f;
    for (int base = beg; base + es < end; base += 16) {
        int idx = base + es;
        float p = __expf(pb[idx] - m);
        pb[idx] = p;
        d += p;
    }
#pragma unroll
    for (int off = 4; off < 64; off <<= 1) d += __shfl_xor(d, off);
    float pself = __expf(selfe - m);
    float r = 1.0f / (d + pself + EPS_DEN);
    if (es == 0) {
        psf[n * 4 + hd] = pself;
        rden[n * 4 + hd] = r;
    }
}

__global__ void stats_h1_kernel(const int* __restrict__ csrc, const int* __restrict__ offs,
                                const float* __restrict__ als, const float* __restrict__ ald,
                                float* __restrict__ pbuf, float* __restrict__ psf,
                                float* __restrict__ rden, int N) {
    int wave = threadIdx.x >> 6, lane = threadIdx.x & 63;
    int n = blockIdx.x * 4 + wave;
    if (n >= N) return;
    float aldn = ald[n];
    float selfe = als[n] + aldn;
    selfe = selfe > 0.f ? selfe : LEAKY * selfe;
    int beg = offs[n], end = offs[n + 1];
    float m = selfe;
    for (int base = beg; base + lane < end; base += 64) {
        int idx = base + lane;
        int s = csrc[idx];
        float e = als[s] + aldn;
        e = e > 0.f ? e : LEAKY * e;
        pbuf[idx] = e;
        m = fmaxf(m, e);
    }
#pragma unroll
    for (int off = 1; off < 64; off <<= 1) m = fmaxf(m, __shfl_xor(m, off));
    float d = 0.f;
    for (int base = beg; base + lane < end; base += 64) {
        int idx = base + lane;
        float p = __expf(pbuf[idx] - m);
        pbuf[idx] = p;
        d += p;
    }
#pragma unroll
    for (int off = 1; off < 64; off <<= 1) d += __shfl_xor(d, off);
    float pself = __expf(selfe - m);
    float r = 1.0f / (d + pself + EPS_DEN);
    if (lane == 0) { psf[n] = pself; rden[n] = r; }
}

// ---------------------------------------------------------------------------
// HALF-HEAD aggregate, double-buffered staging (1 barrier/chunk):
// one 64-thread block per (node, half-head); hh = blockIdx&7 -> L2-resident
// 2.6MB slice per XCD. sSrc holds pre-scaled row offsets (s*512).
// ---------------------------------------------------------------------------
template <bool DO_ELU>
__global__ __launch_bounds__(64) void gat_agg_hh_kernel(
    const float* __restrict__ h, const float* __restrict__ pbuf,
    const float* __restrict__ psf, const float* __restrict__ rden,
    const int* __restrict__ csrc, const int* __restrict__ offs,
    const float* __restrict__ bias, unsigned short* __restrict__ ohi,
    unsigned short* __restrict__ olo, int N, int E) {
    int gid = blockIdx.x;
    int hh = gid & 7;
    int n = gid >> 3;
    int head = hh >> 1;
    int lane = threadIdx.x;
    int eg = lane >> 4;                  // 0..3 edge groups
    int f0 = hh * 64 + (lane & 15) * 4;
    const float* pb = pbuf + (size_t)head * E;

    __shared__ int   sSrc[2][64];
    __shared__ float sP[2][64];
    int beg = offs[n], end = offs[n + 1];
    int nchunks = (end - beg + 63) >> 6;

    f4_t acc = (f4_t){0.f, 0.f, 0.f, 0.f};
    if (beg + lane < end) {
        sSrc[0][lane] = csrc[beg + lane] << 9;   // s*512 (row offset in floats)
        sP[0][lane] = pb[beg + lane];
    }
    for (int ch = 0; ch < nchunks; ch++) {
        int base = beg + ch * 64;
        int len = min(64, end - base);
        int buf = ch & 1;
        __syncthreads();
        int nbase = base + 64;
        if (ch + 1 < nchunks && nbase + lane < end) {
            sSrc[buf ^ 1][lane] = csrc[nbase + lane] << 9;
            sP[buf ^ 1][lane] = pb[nbase + lane];
        }
#pragma unroll 8
        for (int c = eg; c < len; c += 4) {
            const float* srow = h + (size_t)(unsigned)sSrc[buf][c] + f0;
            acc += sP[buf][c] * *(const f4_t*)srow;
        }
    }
    if (eg == 0) {
        f4_t x = *(const f4_t*)(h + (size_t)n * 512 + f0);
        acc += psf[n * 4 + head] * x;
    }
#pragma unroll
    for (int j = 0; j < 4; j++) {
        acc[j] += __shfl_xor(acc[j], 16);
        acc[j] += __shfl_xor(acc[j], 32);
    }
    if (lane < 16) {
        float r = rden[n * 4 + head];
        f4_t b = *(const f4_t*)(bias + f0);
        us4_t hs, ls;
#pragma unroll
        for (int j = 0; j < 4; j++) {
            float o = acc[j] * r + b[j];
            if (DO_ELU) o = o > 0.f ? o : (__expf(o) - 1.0f);
            unsigned short hv = f2bf(o);
            hs[j] = hv;
            ls[j] = f2bf(o - bf2f(hv));
        }
        size_t idx = (size_t)n * 512 + f0;
        *(us4_t*)&ohi[idx] = hs;
        *(us4_t*)&olo[idx] = ls;
    }
}

// Layer-3: dbuf-staged aggregate + classifier fused. One 64-thread block/node.
__global__ __launch_bounds__(64) void gat_agg_h1_cls_kernel(
    const float* __restrict__ h, const float* __restrict__ pbuf,
    const float* __restrict__ psf, const float* __restrict__ rden,
    const int* __restrict__ csrc, const int* __restrict__ offs,
    const float* __restrict__ bias, const float* __restrict__ Wc1,
    const float* __restrict__ bc1, const float* __restrict__ Wc2,
    const float* __restrict__ bc2, float* __restrict__ emb,
    float* __restrict__ outp, int N) {
    int n = blockIdx.x;
    int lane = threadIdx.x;
    int eg = lane >> 4;                  // 0..3
    int fl = (lane & 15) * 8;            // 8 floats/lane (128 total)
    __shared__ int   sSrc[2][64];
    __shared__ float sP[2][64];
    __shared__ float semb[128];
    int beg = offs[n], end = offs[n + 1];
    int nchunks = (end - beg + 63) >> 6;

    f4_t a0 = (f4_t){0.f, 0.f, 0.f, 0.f};
    f4_t a1 = (f4_t){0.f, 0.f, 0.f, 0.f};
    if (beg + lane < end) {
        sSrc[0][lane] = csrc[beg + lane] << 7;   // s*128
        sP[0][lane] = pbuf[beg + lane];
    }
    for (int ch = 0; ch < nchunks; ch++) {
        int base = beg + ch * 64;
        int len = min(64, end - base);
        int buf = ch & 1;
        __syncthreads();
        int nbase = base + 64;
        if (ch + 1 < nchunks && nbase + lane < end) {
            sSrc[buf ^ 1][lane] = csrc[nbase + lane] << 7;
            sP[buf ^ 1][lane] = pbuf[nbase + lane];
        }
#pragma unroll 8
        for (int c = eg; c < len; c += 4) {
            const float* srow = h + (size_t)(unsigned)sSrc[buf][c] + fl;
            float p = sP[buf][c];
            a0 += p * *(const f4_t*)(srow);
            a1 += p * *(const f4_t*)(srow + 4);
        }
    }
    if (eg == 0) {
        float p = psf[n];
        const float* srow = h + (size_t)n * 128 + fl;
        a0 += p * *(const f4_t*)(srow);
        a1 += p * *(const f4_t*)(srow + 4);
    }
#pragma unroll
    for (int j = 0; j < 4; j++) {
        a0[j] += __shfl_xor(a0[j], 16);
        a0[j] += __shfl_xor(a0[j], 32);
        a1[j] += __shfl_xor(a1[j], 16);
        a1[j] += __shfl_xor(a1[j], 32);
    }
    __syncthreads();
    if (lane < 16) {
        int fo = lane * 8;
        float r = rden[n];
        f4_t b0 = *(const f4_t*)(bias + fo);
        f4_t b1 = *(const f4_t*)(bias + fo + 4);
        f4_t o0, o1;
#pragma unroll
        for (int j = 0; j < 4; j++) {
            o0[j] = a0[j] * r + b0[j];
            o1[j] = a1[j] * r + b1[j];
        }
        *(f4_t*)&semb[fo] = o0;
        *(f4_t*)&semb[fo + 4] = o1;
        *(f4_t*)&emb[(size_t)n * 128 + fo] = o0;
        *(f4_t*)&emb[(size_t)n * 128 + fo + 4] = o1;
    }
    __syncthreads();

    float cacc = bc1[lane];
#pragma unroll 4
    for (int k = 0; k < 128; k++) cacc += semb[k] * Wc1[k * 64 + lane];
    cacc = fmaxf(cacc, 0.f);
    float o0 = cacc * Wc2[lane * 2 + 0];
    float o1 = cacc * Wc2[lane * 2 + 1];
#pragma unroll
    for (int off = 32; off; off >>= 1) {
        o0 += __shfl_down(o0, off);
        o1 += __shfl_down(o1, off);
    }
    if (lane == 0) {
        outp[n * 2 + 0] = o0 + bc2[0];
        outp[n * 2 + 1] = o1 + bc2[1];
    }
}

// ---------------------------------------------------------------------------
extern "C" void kernel_launch(void* const* d_in, const int* in_sizes, int n_in,
                              void* d_out, int out_size, void* d_ws, size_t ws_size,
                              hipStream_t stream) {
    const float* x      = (const float*)d_in[0];
    const int*   ei     = (const int*)d_in[1];
    const float* W1     = (const float*)d_in[2];
    const float* a1s    = (const float*)d_in[3];
    const float* a1d    = (const float*)d_in[4];
    const float* b1     = (const float*)d_in[5];
    const float* W2     = (const float*)d_in[6];
    const float* a2s    = (const float*)d_in[7];
    const float* a2d    = (const float*)d_in[8];
    const float* b2     = (const float*)d_in[9];
    const float* W3     = (const float*)d_in[10];
    const float* a3s    = (const float*)d_in[11];
    const float* a3d    = (const float*)d_in[12];
    const float* b3     = (const float*)d_in[13];
    const float* Wc1    = (const float*)d_in[14];
    const float* bc1    = (const float*)d_in[15];
    const float* Wc2    = (const float*)d_in[16];
    const float* bc2    = (const float*)d_in[17];

    const int N = in_sizes[0] / 256;       // 10000
    const int E = in_sizes[1] / 2;         // 320000
    const int F = 512;

    const int* src = ei;
    const int* dst = ei + E;

    auto align = [](size_t o) { return (o + 255) & ~(size_t)255; };
    size_t o = 0;
    size_t o_G     = o; o = align(o + (size_t)N * F * 4);        // GEMM output h (fp32)
    size_t o_ahi   = o; o = align(o + (size_t)N * F * 2);
    size_t o_alo   = o; o = align(o + (size_t)N * F * 2);
    size_t o_xhi   = o; o = align(o + (size_t)N * 256 * 2);
    size_t o_xlo   = o; o = align(o + (size_t)N * 256 * 2);
    size_t o_w1h   = o; o = align(o + (size_t)512 * 256 * 2);
    size_t o_w1l   = o; o = align(o + (size_t)512 * 256 * 2);
    size_t o_w2h   = o; o = align(o + (size_t)512 * 512 * 2);
    size_t o_w2l   = o; o = align(o + (size_t)512 * 512 * 2);
    size_t o_w3h   = o; o = align(o + (size_t)128 * 512 * 2);
    size_t o_w3l   = o; o = align(o + (size_t)128 * 512 * 2);
    size_t o_als   = o; o = align(o + (size_t)N * 4 * 4);
    size_t o_ald   = o; o = align(o + (size_t)N * 4 * 4);
    size_t o_psf   = o; o = align(o + (size_t)N * 4 * 4);
    size_t o_rden  = o; o = align(o + (size_t)N * 4 * 4);
    size_t o_cnt   = o; o = align(o + (size_t)N * 4);
    size_t o_off   = o; o = align(o + (size_t)(N + 1) * 4);
    size_t o_bsum  = o; o = align(o + (size_t)64 * 4);
    size_t o_csrc  = o; o = align(o + (size_t)E * 4);
    size_t o_ebuf  = o; o = align(o + (size_t)E * 4 * 4);
    (void)ws_size;

    char* ws = (char*)d_ws;
    float* bufG  = (float*)(ws + o_G);
    unsigned short* act_hi = (unsigned short*)(ws + o_ahi);
    unsigned short* act_lo = (unsigned short*)(ws + o_alo);
    unsigned short* x_hi   = (unsigned short*)(ws + o_xhi);
    unsigned short* x_lo   = (unsigned short*)(ws + o_xlo);
    unsigned short* w1h = (unsigned short*)(ws + o_w1h);
    unsigned short* w1l = (unsigned short*)(ws + o_w1l);
    unsigned short* w2h = (unsigned short*)(ws + o_w2h);
    unsigned short* w2l = (unsigned short*)(ws + o_w2l);
    unsigned short* w3h = (unsigned short*)(ws + o_w3h);
    unsigned short* w3l = (unsigned short*)(ws + o_w3l);
    float* als  = (float*)(ws + o_als);
    float* ald  = (float*)(ws + o_ald);
    float* psf  = (float*)(ws + o_psf);
    float* rden = (float*)(ws + o_rden);
    int*   cnt  = (int*)(ws + o_cnt);
    int*   offs = (int*)(ws + o_off);
    int*   bsum = (int*)(ws + o_bsum);
    int*   csrc = (int*)(ws + o_csrc);
    float* ebuf = (float*)(ws + o_ebuf);

    float* outp = (float*)d_out;                 // [N,2]
    float* emb  = (float*)d_out + (size_t)N * 2; // [N,128]

    // ---- CSR build (5 dispatches) ----
    hipMemsetAsync(cnt, 0, (size_t)N * 4, stream);
    int eb = (E + 255) / 256;
    int nbs = (N + 255) / 256;   // 40
    hipLaunchKernelGGL(hist_kernel, dim3(eb), dim3(256), 0, stream, dst, cnt, E);
    hipLaunchKernelGGL(scan1_kernel, dim3(nbs), dim3(256), 0, stream, cnt, bsum, N);
    hipLaunchKernelGGL(scan3b_kernel, dim3(nbs), dim3(256), 0, stream, cnt, bsum, offs, N, nbs);
    hipLaunchKernelGGL(scatter_kernel, dim3(eb), dim3(256), 0, stream, src, dst, cnt, csrc, E);

    // ---- merged splits (1 dispatch) ----
    int NBX = N;   // N*256/256
    hipLaunchKernelGGL(split_all_kernel, dim3(NBX + 512 + 1024 + 256), dim3(256), 0, stream,
                       x, x_hi, x_lo, NBX, W1, w1h, w1l, W2, w2h, w2l, W3, w3h, w3l);

    int nb4 = (N + 3) / 4;
    int gy128 = (N + 127) / 128;  // 79
    int gy64  = (N + 63) / 64;    // 157

    // ---- layer 1 ----
    hipLaunchKernelGGL(mfma_gemm128_kernel, dim3(512 / 128, gy128), dim3(256), 0, stream,
                       x_hi, x_lo, w1h, w1l, a1s, a1d, bufG, als, ald, N, 512, 256);
    hipLaunchKernelGGL(stats_h4_kernel, dim3(nb4), dim3(256), 0, stream,
                       csrc, offs, als, ald, ebuf, psf, rden, N, E);
    hipLaunchKernelGGL((gat_agg_hh_kernel<true>), dim3(N * 8), dim3(64), 0, stream,
                       bufG, ebuf, psf, rden, csrc, offs, b1, act_hi, act_lo, N, E);

    // ---- layer 2 ----
    hipLaunchKernelGGL(mfma_gemm128_kernel, dim3(512 / 128, gy128), dim3(256), 0, stream,
                       act_hi, act_lo, w2h, w2l, a2s, a2d, bufG, als, ald, N, 512, 512);
    hipLaunchKernelGGL(stats_h4_kernel, dim3(nb4), dim3(256), 0, stream,
                       csrc, offs, als, ald, ebuf, psf, rden, N, E);
    hipLaunchKernelGGL((gat_agg_hh_kernel<true>), dim3(N * 8), dim3(64), 0, stream,
                       bufG, ebuf, psf, rden, csrc, offs, b2, act_hi, act_lo, N, E);

    // ---- layer 3 + classifier ----
    hipLaunchKernelGGL(mfma_gemm64_kernel, dim3(128 / 128, gy64), dim3(256), 0, stream,
                       act_hi, act_lo, w3h, w3l, a3s, a3d, bufG, als, ald, N, 128, 512);
    hipLaunchKernelGGL(stats_h1_kernel, dim3(nb4), dim3(256), 0, stream,
                       csrc, offs, als, ald, ebuf, psf, rden, N);
    hipLaunchKernelGGL(gat_agg_h1_cls_kernel, dim3(N), dim3(64), 0, stream,
                       bufG, ebuf, psf, rden, csrc, offs, b3, Wc1, bc1, Wc2, bc2, emb, outp, N);
}